// Round 1
// baseline (2848.943 us; speedup 1.0000x reference)
//
#include <hip/hip_runtime.h>
#include <math.h>

// Problem constants
constexpr int cB = 2, cS = 4096, cHID = 1024, cNH = 16, cHD = 64, cNL = 128, cSEG = 32, cD = 1024, cBH = 32;
constexpr float cSCALE = 0.35355339059327373f;   // 1/sqrt(sqrt(64))

// ---------------------------------------------------------------------------
// GEMM: Y = (X @ W + b) * (mask*scale if q/k), scattered to (B,NH,S,HD)
// grid (D/64, B*S/64, 3), block 256, 64x64 tile, TK=16, 4x4 micro
// ---------------------------------------------------------------------------
__global__ __launch_bounds__(256) void qkv_gemm(
    const float* __restrict__ X, const float* __restrict__ mask,
    const float* __restrict__ Wq, const float* __restrict__ bq,
    const float* __restrict__ Wk, const float* __restrict__ bk,
    const float* __restrict__ Wv, const float* __restrict__ bv,
    float* __restrict__ Qo, float* __restrict__ Ko, float* __restrict__ Vo)
{
    __shared__ __align__(16) float As[16][68];
    __shared__ __align__(16) float Bs[16][68];
    const int tid = threadIdx.x;
    const int wsel = blockIdx.z;
    const float* W    = (wsel == 0) ? Wq : (wsel == 1 ? Wk : Wv);
    const float* bias = (wsel == 0) ? bq : (wsel == 1 ? bk : bv);
    float* Y          = (wsel == 0) ? Qo : (wsel == 1 ? Ko : Vo);
    const int c0 = blockIdx.x * 64, r0 = blockIdx.y * 64;
    const int tx = tid & 15, ty = tid >> 4;
    const int am = tid >> 2, ak = (tid & 3) * 4;
    const int bkk = tid >> 4, bn = (tid & 15) * 4;

    float acc[4][4] = {};
    for (int k0 = 0; k0 < cHID; k0 += 16) {
        float4 a4 = *reinterpret_cast<const float4*>(X + (r0 + am) * cHID + k0 + ak);
        As[ak + 0][am] = a4.x; As[ak + 1][am] = a4.y; As[ak + 2][am] = a4.z; As[ak + 3][am] = a4.w;
        float4 b4 = *reinterpret_cast<const float4*>(W + (k0 + bkk) * cD + c0 + bn);
        *reinterpret_cast<float4*>(&Bs[bkk][bn]) = b4;
        __syncthreads();
#pragma unroll
        for (int kk = 0; kk < 16; ++kk) {
            float4 av  = *reinterpret_cast<const float4*>(&As[kk][ty * 4]);
            float4 bv4 = *reinterpret_cast<const float4*>(&Bs[kk][tx * 4]);
            float a_[4] = {av.x, av.y, av.z, av.w};
            float b_[4] = {bv4.x, bv4.y, bv4.z, bv4.w};
#pragma unroll
            for (int i = 0; i < 4; ++i)
#pragma unroll
                for (int j = 0; j < 4; ++j) acc[i][j] += a_[i] * b_[j];
        }
        __syncthreads();
    }
#pragma unroll
    for (int i = 0; i < 4; ++i) {
        int r = r0 + ty * 4 + i;
        int b = r >> 12, s = r & (cS - 1);
        float msc = (wsel < 2) ? mask[b * cS + s] * cSCALE : 1.0f;
#pragma unroll
        for (int j = 0; j < 4; ++j) {
            int c = c0 + tx * 4 + j;
            int h = c >> 6, d = c & 63;
            Y[((b * cNH + h) * cS + s) * cHD + d] = (acc[i][j] + bias[c]) * msc;
        }
    }
}

// ---------------------------------------------------------------------------
// out = ctx @ Wo + bo ; ctx row-major (B*S, D); out row-major
// ---------------------------------------------------------------------------
__global__ __launch_bounds__(256) void out_gemm(
    const float* __restrict__ Xc, const float* __restrict__ W,
    const float* __restrict__ bias, float* __restrict__ Y)
{
    __shared__ __align__(16) float As[16][68];
    __shared__ __align__(16) float Bs[16][68];
    const int tid = threadIdx.x;
    const int c0 = blockIdx.x * 64, r0 = blockIdx.y * 64;
    const int tx = tid & 15, ty = tid >> 4;
    const int am = tid >> 2, ak = (tid & 3) * 4;
    const int bkk = tid >> 4, bn = (tid & 15) * 4;

    float acc[4][4] = {};
    for (int k0 = 0; k0 < cD; k0 += 16) {
        float4 a4 = *reinterpret_cast<const float4*>(Xc + (r0 + am) * cD + k0 + ak);
        As[ak + 0][am] = a4.x; As[ak + 1][am] = a4.y; As[ak + 2][am] = a4.z; As[ak + 3][am] = a4.w;
        float4 b4 = *reinterpret_cast<const float4*>(W + (k0 + bkk) * cHID + c0 + bn);
        *reinterpret_cast<float4*>(&Bs[bkk][bn]) = b4;
        __syncthreads();
#pragma unroll
        for (int kk = 0; kk < 16; ++kk) {
            float4 av  = *reinterpret_cast<const float4*>(&As[kk][ty * 4]);
            float4 bv4 = *reinterpret_cast<const float4*>(&Bs[kk][tx * 4]);
            float a_[4] = {av.x, av.y, av.z, av.w};
            float b_[4] = {bv4.x, bv4.y, bv4.z, bv4.w};
#pragma unroll
            for (int i = 0; i < 4; ++i)
#pragma unroll
                for (int j = 0; j < 4; ++j) acc[i][j] += a_[i] * b_[j];
        }
        __syncthreads();
    }
#pragma unroll
    for (int i = 0; i < 4; ++i) {
        int r = r0 + ty * 4 + i;
#pragma unroll
        for (int j = 0; j < 4; ++j) {
            int c = c0 + tx * 4 + j;
            Y[r * cHID + c] = acc[i][j] + bias[c];
        }
    }
}

// ---------------------------------------------------------------------------
// Landmark means: Ql/Kl[bh][l][d] = mean_{j<32} Q/K[bh][l*32+j][d]
// ---------------------------------------------------------------------------
__global__ __launch_bounds__(256) void lmeans(
    const float* __restrict__ Q, const float* __restrict__ K,
    float* __restrict__ Ql, float* __restrict__ Kl)
{
    int idx = blockIdx.x * 256 + threadIdx.x;       // < 2*262144
    int sel = idx >> 18;
    int t = idx & 262143;
    int d = t & 63, l = (t >> 6) & 127, bh = t >> 13;
    const float* src = sel ? K : Q;
    float s = 0.f;
    int base = (bh * cS + l * cSEG) * cHD + d;
#pragma unroll 8
    for (int j = 0; j < cSEG; ++j) s += src[base + j * cHD];
    (sel ? Kl : Ql)[t] = s * (1.0f / cSEG);
}

// ---------------------------------------------------------------------------
// k2[bh][i][j] = softmax_j( Ql[bh][i] . Kl[bh][j] )  (128 threads per (bh,i))
// ---------------------------------------------------------------------------
__global__ __launch_bounds__(128) void k2_softmax(
    const float* __restrict__ Ql, const float* __restrict__ Kl, float* __restrict__ k2)
{
    __shared__ __align__(16) float qrow[64];
    __shared__ float red[128];
    int bh = blockIdx.x >> 7, i = blockIdx.x & 127;
    int j = threadIdx.x;
    if (j < 64) qrow[j] = Ql[(bh * cNL + i) * cHD + j];
    __syncthreads();
    const float4* q4  = reinterpret_cast<const float4*>(qrow);
    const float4* kl4 = reinterpret_cast<const float4*>(Kl + (bh * cNL + j) * cHD);
    float dot = 0.f;
#pragma unroll
    for (int u = 0; u < 16; ++u) {
        float4 a = q4[u], b = kl4[u];
        dot += a.x * b.x + a.y * b.y + a.z * b.z + a.w * b.w;
    }
    red[j] = dot; __syncthreads();
    for (int off = 64; off > 0; off >>= 1) { if (j < off) red[j] = fmaxf(red[j], red[j + off]); __syncthreads(); }
    float m = red[0]; __syncthreads();
    float e = expf(dot - m);
    red[j] = e; __syncthreads();
    for (int off = 64; off > 0; off >>= 1) { if (j < off) red[j] += red[j + off]; __syncthreads(); }
    k2[(bh * cNL + i) * cNL + j] = e / red[0];
}

// ---------------------------------------------------------------------------
// Global max over (bh, j) of column sums of k2 -> cmax (positive-float atomicMax)
// ---------------------------------------------------------------------------
__global__ __launch_bounds__(128) void colsum_max(const float* __restrict__ k2, int* __restrict__ cmax)
{
    __shared__ float red[128];
    int bh = blockIdx.x, j = threadIdx.x;
    float s = 0.f;
    for (int i = 0; i < cNL; ++i) s += k2[(bh * cNL + i) * cNL + j];
    red[j] = s; __syncthreads();
    for (int off = 64; off > 0; off >>= 1) { if (j < off) red[j] = fmaxf(red[j], red[j + off]); __syncthreads(); }
    if (j == 0) atomicMax(cmax, __float_as_int(red[0]));
}

// V0[bh][i][j] = k2[bh][j][i] / cmax
__global__ __launch_bounds__(128) void v0_kernel(
    const float* __restrict__ k2, const int* __restrict__ cmax, float* __restrict__ V0)
{
    int bh = blockIdx.x >> 7, i = blockIdx.x & 127, j = threadIdx.x;
    float c = __int_as_float(*cmax);
    V0[(bh * cNL + i) * cNL + j] = k2[(bh * cNL + j) * cNL + i] / c;
}

// ---------------------------------------------------------------------------
// Batched 128x128: C = ds * (cs*A - A@B)  (grid (2,2,32), block 256)
// ---------------------------------------------------------------------------
__global__ __launch_bounds__(256) void nys_matmul(
    const float* __restrict__ A, const float* __restrict__ Bm, float* __restrict__ C,
    float cs, float ds)
{
    __shared__ __align__(16) float As[16][68];
    __shared__ __align__(16) float Bs[16][68];
    const int tid = threadIdx.x;
    const int c0 = blockIdx.x * 64, r0 = blockIdx.y * 64;
    const int base = blockIdx.z * cNL * cNL;
    const int tx = tid & 15, ty = tid >> 4;
    const int am = tid >> 2, ak = (tid & 3) * 4;
    const int bkk = tid >> 4, bn = (tid & 15) * 4;

    float acc[4][4] = {};
    for (int k0 = 0; k0 < cNL; k0 += 16) {
        float4 a4 = *reinterpret_cast<const float4*>(A + base + (r0 + am) * cNL + k0 + ak);
        As[ak + 0][am] = a4.x; As[ak + 1][am] = a4.y; As[ak + 2][am] = a4.z; As[ak + 3][am] = a4.w;
        float4 b4 = *reinterpret_cast<const float4*>(Bm + base + (k0 + bkk) * cNL + c0 + bn);
        *reinterpret_cast<float4*>(&Bs[bkk][bn]) = b4;
        __syncthreads();
#pragma unroll
        for (int kk = 0; kk < 16; ++kk) {
            float4 av  = *reinterpret_cast<const float4*>(&As[kk][ty * 4]);
            float4 bv4 = *reinterpret_cast<const float4*>(&Bs[kk][tx * 4]);
            float a_[4] = {av.x, av.y, av.z, av.w};
            float b_[4] = {bv4.x, bv4.y, bv4.z, bv4.w};
#pragma unroll
            for (int i = 0; i < 4; ++i)
#pragma unroll
                for (int j = 0; j < 4; ++j) acc[i][j] += a_[i] * b_[j];
        }
        __syncthreads();
    }
#pragma unroll
    for (int i = 0; i < 4; ++i) {
        int r = r0 + ty * 4 + i;
#pragma unroll
        for (int j = 0; j < 4; ++j) {
            int c = c0 + tx * 4 + j;
            float av = A[base + r * cNL + c];
            C[base + r * cNL + c] = ds * (cs * av - acc[i][j]);
        }
    }
}

// ---------------------------------------------------------------------------
// CV[bh][l][:] = softmax_s(Ql[bh][l].K[bh][s] - 1e9*(1-mask)) @ V[bh]
// one block (256 thr) per (bh, l); full 4096 logits staged in LDS
// ---------------------------------------------------------------------------
__global__ __launch_bounds__(256) void k3v_fused(
    const float* __restrict__ Ql, const float* __restrict__ K, const float* __restrict__ V,
    const float* __restrict__ mask, float* __restrict__ CV)
{
    __shared__ __align__(16) float qlrow[64];
    __shared__ float sl[4096];
    __shared__ float red[256];
    const int l = blockIdx.x, bh = blockIdx.y;
    const int b = bh >> 4;
    const int t = threadIdx.x;
    if (t < 64) qlrow[t] = Ql[(bh * cNL + l) * cHD + t];
    __syncthreads();
    const float4* q4 = reinterpret_cast<const float4*>(qlrow);
    float tmax = -1e30f;
    for (int k = 0; k < 16; ++k) {
        int s = t + k * 256;
        const float4* kv4 = reinterpret_cast<const float4*>(K + (bh * cS + s) * cHD);
        float dot = 0.f;
#pragma unroll
        for (int u = 0; u < 16; ++u) {
            float4 a = q4[u], b4 = kv4[u];
            dot += a.x * b4.x + a.y * b4.y + a.z * b4.z + a.w * b4.w;
        }
        dot -= 1e9f * (1.0f - mask[b * cS + s]);
        sl[s] = dot; tmax = fmaxf(tmax, dot);
    }
    red[t] = tmax; __syncthreads();
    for (int off = 128; off > 0; off >>= 1) { if (t < off) red[t] = fmaxf(red[t], red[t + off]); __syncthreads(); }
    float gmax = red[0]; __syncthreads();
    float tsum = 0.f;
    for (int k = 0; k < 16; ++k) {
        int s = t + k * 256;
        float e = expf(sl[s] - gmax);
        sl[s] = e; tsum += e;
    }
    red[t] = tsum; __syncthreads();
    for (int off = 128; off > 0; off >>= 1) { if (t < off) red[t] += red[t + off]; __syncthreads(); }
    float ssum = red[0]; __syncthreads();
    const int d = t & 63, ch = t >> 6;
    float acc = 0.f;
    int sbase = ch * 1024;
    for (int s = sbase; s < sbase + 1024; ++s) acc += sl[s] * V[(bh * cS + s) * cHD + d];
    red[t] = acc; __syncthreads();
    if (t < 64) {
        float tot = red[t] + red[t + 64] + red[t + 128] + red[t + 192];
        CV[(bh * cNL + l) * cHD + t] = tot / ssum;
    }
}

// W2[bh] = V6[bh] @ CV[bh]   (128x128)@(128x64); one block per bh
__global__ __launch_bounds__(256) void w2_matmul(
    const float* __restrict__ V6, const float* __restrict__ CV, float* __restrict__ W2)
{
    __shared__ __align__(16) float CVs[128][64];
    const int bh = blockIdx.x, t = threadIdx.x;
    for (int k = 0; k < 32; ++k) { int idx = t + k * 256; CVs[idx >> 6][idx & 63] = CV[bh * 8192 + idx]; }
    __syncthreads();
    const int tx = t & 15, ty = t >> 4;
    float acc[8][4] = {};
    for (int k = 0; k < 128; ++k) {
        float4 b4 = *reinterpret_cast<const float4*>(&CVs[k][tx * 4]);
#pragma unroll
        for (int i = 0; i < 8; ++i) {
            float a = V6[(bh * cNL + ty * 8 + i) * cNL + k];
            acc[i][0] += a * b4.x; acc[i][1] += a * b4.y; acc[i][2] += a * b4.z; acc[i][3] += a * b4.w;
        }
    }
#pragma unroll
    for (int i = 0; i < 8; ++i)
#pragma unroll
        for (int j = 0; j < 4; ++j)
            W2[(bh * cNL + ty * 8 + i) * cHD + tx * 4 + j] = acc[i][j];
}

// ---------------------------------------------------------------------------
// ctx[b][s][h*64+d] = softmax_l(Q[bh][s].Kl[bh][l]) @ W2[bh]
// one block per (bh, 16 s-rows); Kl then W2 share one padded LDS buffer
// ---------------------------------------------------------------------------
__global__ __launch_bounds__(256) void k1_fused(
    const float* __restrict__ Q, const float* __restrict__ Kl, const float* __restrict__ W2,
    float* __restrict__ ctx)
{
    __shared__ __align__(16) float buf[128 * 68];
    __shared__ float pbuf[16 * 128];
    __shared__ __align__(16) float qbuf[16 * 64];
    __shared__ float rowred[16 * 16];
    __shared__ float rowmax[16];
    __shared__ float rowsum[16];
    const int bh = blockIdx.y, s0 = blockIdx.x * 16;
    const int b = bh >> 4, h = bh & 15;
    const int t = threadIdx.x;
    for (int k = 0; k < 32; ++k) { int idx = t + k * 256; buf[(idx >> 6) * 68 + (idx & 63)] = Kl[bh * 8192 + idx]; }
    for (int k = 0; k < 4; ++k)  { int idx = t + k * 256; qbuf[idx] = Q[(bh * cS + s0 + (idx >> 6)) * cHD + (idx & 63)]; }
    __syncthreads();
    const int i = t >> 4, lo = t & 15;
    const float4* qv = reinterpret_cast<const float4*>(&qbuf[i * 64]);
    float tmax = -1e30f;
    float dots[8];
#pragma unroll
    for (int k = 0; k < 8; ++k) {
        int l = lo + k * 16;
        const float4* kl4 = reinterpret_cast<const float4*>(&buf[l * 68]);
        float dot = 0.f;
#pragma unroll
        for (int u = 0; u < 16; ++u) {
            float4 a = qv[u], b4 = kl4[u];
            dot += a.x * b4.x + a.y * b4.y + a.z * b4.z + a.w * b4.w;
        }
        dots[k] = dot; tmax = fmaxf(tmax, dot);
    }
    rowred[i * 16 + lo] = tmax; __syncthreads();
    if (t < 16) { float m = rowred[t * 16]; for (int u = 1; u < 16; ++u) m = fmaxf(m, rowred[t * 16 + u]); rowmax[t] = m; }
    __syncthreads();
    float m = rowmax[i];
    float psum = 0.f;
#pragma unroll
    for (int k = 0; k < 8; ++k) {
        int l = lo + k * 16;
        float e = expf(dots[k] - m);
        pbuf[i * 128 + l] = e; psum += e;
    }
    rowred[i * 16 + lo] = psum; __syncthreads();
    if (t < 16) { float s_ = 0.f; for (int u = 0; u < 16; ++u) s_ += rowred[t * 16 + u]; rowsum[t] = s_; }
    __syncthreads();
    // phase 2: overwrite buf with W2
    for (int k = 0; k < 32; ++k) { int idx = t + k * 256; buf[(idx >> 6) * 68 + (idx & 63)] = W2[bh * 8192 + idx]; }
    __syncthreads();
    const int d = t & 63, ig = t >> 6;
    float acc[4] = {};
    for (int l = 0; l < 128; ++l) {
        float w = buf[l * 68 + d];
#pragma unroll
        for (int k = 0; k < 4; ++k) acc[k] += pbuf[(ig * 4 + k) * 128 + l] * w;
    }
#pragma unroll
    for (int k = 0; k < 4; ++k) {
        int i2 = ig * 4 + k;
        ctx[(b * cS + s0 + i2) * cD + h * cHD + d] = acc[k] / rowsum[i2];
    }
}

// ---------------------------------------------------------------------------
extern "C" void kernel_launch(void* const* d_in, const int* in_sizes, int n_in,
                              void* d_out, int out_size, void* d_ws, size_t ws_size,
                              hipStream_t stream)
{
    const float* X    = (const float*)d_in[0];
    const float* mask = (const float*)d_in[1];
    const float* Wq   = (const float*)d_in[2];
    const float* bq   = (const float*)d_in[3];
    const float* Wk   = (const float*)d_in[4];
    const float* bk   = (const float*)d_in[5];
    const float* Wv   = (const float*)d_in[6];
    const float* bv   = (const float*)d_in[7];
    const float* Wo   = (const float*)d_in[8];
    const float* bo   = (const float*)d_in[9];
    float* out = (float*)d_out;

    float* ws = (float*)d_ws;
    size_t off = 0;
    const size_t szQKV = (size_t)cBH * cS * cHD;      // 8388608
    const size_t szL   = (size_t)cBH * cNL * cHD;     // 262144
    const size_t szM   = (size_t)cBH * cNL * cNL;     // 524288
    float* Q   = ws + off; off += szQKV;
    float* K   = ws + off; off += szQKV;
    float* V   = ws + off; off += szQKV;
    float* Ql  = ws + off; off += szL;
    float* Kl  = ws + off; off += szL;
    float* k2  = ws + off; off += szM;
    float* Vb0 = ws + off; off += szM;
    float* Vb1 = ws + off; off += szM;
    float* Zb  = ws + off; off += szM;
    float* T2b = ws + off; off += szM;
    float* T3b = ws + off; off += szM;
    float* CV  = ws + off; off += szL;
    float* W2  = ws + off; off += szL;
    int*   cmax = (int*)(ws + off); off += 16;
    float* ctx = K;   // K is dead after k3v_fused; reuse its 32 MB for ctx

    hipMemsetAsync(cmax, 0, sizeof(int), stream);

    qkv_gemm<<<dim3(cD / 64, (cB * cS) / 64, 3), 256, 0, stream>>>(
        X, mask, Wq, bq, Wk, bk, Wv, bv, Q, K, V);
    lmeans<<<2048, 256, 0, stream>>>(Q, K, Ql, Kl);
    k2_softmax<<<cBH * cNL, 128, 0, stream>>>(Ql, Kl, k2);
    colsum_max<<<cBH, 128, 0, stream>>>(k2, cmax);
    v0_kernel<<<cBH * cNL, 128, 0, stream>>>(k2, cmax, Vb0);

    float* Vc = Vb0; float* Vn = Vb1;
    for (int it = 0; it < 6; ++it) {
        nys_matmul<<<dim3(2, 2, cBH), 256, 0, stream>>>(k2, Vc, Zb, 0.f, -1.f);   // Z = k2@V
        nys_matmul<<<dim3(2, 2, cBH), 256, 0, stream>>>(Zb, Zb, T2b, 7.f, 1.f);   // T2 = 7Z - Z@Z
        nys_matmul<<<dim3(2, 2, cBH), 256, 0, stream>>>(Zb, T2b, T3b, 15.f, 1.f); // T3 = 15Z - Z@T2
        nys_matmul<<<dim3(2, 2, cBH), 256, 0, stream>>>(Vc, T3b, Vn, 13.f, 0.25f);// V' = .25(13V - V@T3)
        float* tmp = Vc; Vc = Vn; Vn = tmp;
    }

    k3v_fused<<<dim3(cNL, cBH), 256, 0, stream>>>(Ql, K, V, mask, CV);
    w2_matmul<<<cBH, 256, 0, stream>>>(Vc, CV, W2);
    k1_fused<<<dim3(cS / 16, cBH), 256, 0, stream>>>(Q, Kl, W2, ctx);
    out_gemm<<<dim3(cD / 64, (cB * cS) / 64), 256, 0, stream>>>(ctx, Wo, bo, out);
}

// Round 2
// 1602.275 us; speedup vs baseline: 1.7781x; 1.7781x over previous
//
#include <hip/hip_runtime.h>
#include <math.h>

// Problem constants
constexpr int cB = 2, cS = 4096, cHID = 1024, cNH = 16, cHD = 64, cNL = 128, cSEG = 32, cD = 1024, cBH = 32;
constexpr float cSCALE = 0.35355339059327373f;   // 1/sqrt(sqrt(64))

// ---------------------------------------------------------------------------
// GEMM: Y = (X @ W + b) * (mask*scale if q/k), scattered to (B,NH,S,HD)
// ---------------------------------------------------------------------------
__global__ __launch_bounds__(256) void qkv_gemm(
    const float* __restrict__ X, const float* __restrict__ mask,
    const float* __restrict__ Wq, const float* __restrict__ bq,
    const float* __restrict__ Wk, const float* __restrict__ bk,
    const float* __restrict__ Wv, const float* __restrict__ bv,
    float* __restrict__ Qo, float* __restrict__ Ko, float* __restrict__ Vo)
{
    __shared__ __align__(16) float As[16][68];
    __shared__ __align__(16) float Bs[16][68];
    const int tid = threadIdx.x;
    const int wsel = blockIdx.z;
    const float* W    = (wsel == 0) ? Wq : (wsel == 1 ? Wk : Wv);
    const float* bias = (wsel == 0) ? bq : (wsel == 1 ? bk : bv);
    float* Y          = (wsel == 0) ? Qo : (wsel == 1 ? Ko : Vo);
    const int c0 = blockIdx.x * 64, r0 = blockIdx.y * 64;
    const int tx = tid & 15, ty = tid >> 4;
    const int am = tid >> 2, ak = (tid & 3) * 4;
    const int bkk = tid >> 4, bn = (tid & 15) * 4;

    float acc[4][4] = {};
    for (int k0 = 0; k0 < cHID; k0 += 16) {
        float4 a4 = *reinterpret_cast<const float4*>(X + (r0 + am) * cHID + k0 + ak);
        As[ak + 0][am] = a4.x; As[ak + 1][am] = a4.y; As[ak + 2][am] = a4.z; As[ak + 3][am] = a4.w;
        float4 b4 = *reinterpret_cast<const float4*>(W + (k0 + bkk) * cD + c0 + bn);
        *reinterpret_cast<float4*>(&Bs[bkk][bn]) = b4;
        __syncthreads();
#pragma unroll
        for (int kk = 0; kk < 16; ++kk) {
            float4 av  = *reinterpret_cast<const float4*>(&As[kk][ty * 4]);
            float4 bv4 = *reinterpret_cast<const float4*>(&Bs[kk][tx * 4]);
            float a_[4] = {av.x, av.y, av.z, av.w};
            float b_[4] = {bv4.x, bv4.y, bv4.z, bv4.w};
#pragma unroll
            for (int i = 0; i < 4; ++i)
#pragma unroll
                for (int j = 0; j < 4; ++j) acc[i][j] += a_[i] * b_[j];
        }
        __syncthreads();
    }
#pragma unroll
    for (int i = 0; i < 4; ++i) {
        int r = r0 + ty * 4 + i;
        int b = r >> 12, s = r & (cS - 1);
        float msc = (wsel < 2) ? mask[b * cS + s] * cSCALE : 1.0f;
#pragma unroll
        for (int j = 0; j < 4; ++j) {
            int c = c0 + tx * 4 + j;
            int h = c >> 6, d = c & 63;
            Y[((b * cNH + h) * cS + s) * cHD + d] = (acc[i][j] + bias[c]) * msc;
        }
    }
}

// ---------------------------------------------------------------------------
// out = ctx @ Wo + bo
// ---------------------------------------------------------------------------
__global__ __launch_bounds__(256) void out_gemm(
    const float* __restrict__ Xc, const float* __restrict__ W,
    const float* __restrict__ bias, float* __restrict__ Y)
{
    __shared__ __align__(16) float As[16][68];
    __shared__ __align__(16) float Bs[16][68];
    const int tid = threadIdx.x;
    const int c0 = blockIdx.x * 64, r0 = blockIdx.y * 64;
    const int tx = tid & 15, ty = tid >> 4;
    const int am = tid >> 2, ak = (tid & 3) * 4;
    const int bkk = tid >> 4, bn = (tid & 15) * 4;

    float acc[4][4] = {};
    for (int k0 = 0; k0 < cD; k0 += 16) {
        float4 a4 = *reinterpret_cast<const float4*>(Xc + (r0 + am) * cD + k0 + ak);
        As[ak + 0][am] = a4.x; As[ak + 1][am] = a4.y; As[ak + 2][am] = a4.z; As[ak + 3][am] = a4.w;
        float4 b4 = *reinterpret_cast<const float4*>(W + (k0 + bkk) * cHID + c0 + bn);
        *reinterpret_cast<float4*>(&Bs[bkk][bn]) = b4;
        __syncthreads();
#pragma unroll
        for (int kk = 0; kk < 16; ++kk) {
            float4 av  = *reinterpret_cast<const float4*>(&As[kk][ty * 4]);
            float4 bv4 = *reinterpret_cast<const float4*>(&Bs[kk][tx * 4]);
            float a_[4] = {av.x, av.y, av.z, av.w};
            float b_[4] = {bv4.x, bv4.y, bv4.z, bv4.w};
#pragma unroll
            for (int i = 0; i < 4; ++i)
#pragma unroll
                for (int j = 0; j < 4; ++j) acc[i][j] += a_[i] * b_[j];
        }
        __syncthreads();
    }
#pragma unroll
    for (int i = 0; i < 4; ++i) {
        int r = r0 + ty * 4 + i;
#pragma unroll
        for (int j = 0; j < 4; ++j) {
            int c = c0 + tx * 4 + j;
            Y[r * cHID + c] = acc[i][j] + bias[c];
        }
    }
}

// ---------------------------------------------------------------------------
// Landmark means
// ---------------------------------------------------------------------------
__global__ __launch_bounds__(256) void lmeans(
    const float* __restrict__ Q, const float* __restrict__ K,
    float* __restrict__ Ql, float* __restrict__ Kl)
{
    int idx = blockIdx.x * 256 + threadIdx.x;
    int sel = idx >> 18;
    int t = idx & 262143;
    int d = t & 63, l = (t >> 6) & 127, bh = t >> 13;
    const float* src = sel ? K : Q;
    float s = 0.f;
    int base = (bh * cS + l * cSEG) * cHD + d;
#pragma unroll 8
    for (int j = 0; j < cSEG; ++j) s += src[base + j * cHD];
    (sel ? Kl : Ql)[t] = s * (1.0f / cSEG);
}

// ---------------------------------------------------------------------------
// k2 softmax
// ---------------------------------------------------------------------------
__global__ __launch_bounds__(128) void k2_softmax(
    const float* __restrict__ Ql, const float* __restrict__ Kl, float* __restrict__ k2)
{
    __shared__ __align__(16) float qrow[64];
    __shared__ float red[128];
    int bh = blockIdx.x >> 7, i = blockIdx.x & 127;
    int j = threadIdx.x;
    if (j < 64) qrow[j] = Ql[(bh * cNL + i) * cHD + j];
    __syncthreads();
    const float4* q4  = reinterpret_cast<const float4*>(qrow);
    const float4* kl4 = reinterpret_cast<const float4*>(Kl + (bh * cNL + j) * cHD);
    float dot = 0.f;
#pragma unroll
    for (int u = 0; u < 16; ++u) {
        float4 a = q4[u], b = kl4[u];
        dot += a.x * b.x + a.y * b.y + a.z * b.z + a.w * b.w;
    }
    red[j] = dot; __syncthreads();
    for (int off = 64; off > 0; off >>= 1) { if (j < off) red[j] = fmaxf(red[j], red[j + off]); __syncthreads(); }
    float m = red[0]; __syncthreads();
    float e = expf(dot - m);
    red[j] = e; __syncthreads();
    for (int off = 64; off > 0; off >>= 1) { if (j < off) red[j] += red[j + off]; __syncthreads(); }
    k2[(bh * cNL + i) * cNL + j] = e / red[0];
}

__global__ __launch_bounds__(128) void colsum_max(const float* __restrict__ k2, int* __restrict__ cmax)
{
    __shared__ float red[128];
    int bh = blockIdx.x, j = threadIdx.x;
    float s = 0.f;
    for (int i = 0; i < cNL; ++i) s += k2[(bh * cNL + i) * cNL + j];
    red[j] = s; __syncthreads();
    for (int off = 64; off > 0; off >>= 1) { if (j < off) red[j] = fmaxf(red[j], red[j + off]); __syncthreads(); }
    if (j == 0) atomicMax(cmax, __float_as_int(red[0]));
}

__global__ __launch_bounds__(128) void v0_kernel(
    const float* __restrict__ k2, const int* __restrict__ cmax, float* __restrict__ V0)
{
    int bh = blockIdx.x >> 7, i = blockIdx.x & 127, j = threadIdx.x;
    float c = __int_as_float(*cmax);
    V0[(bh * cNL + i) * cNL + j] = k2[(bh * cNL + j) * cNL + i] / c;
}

// ---------------------------------------------------------------------------
// Batched 128x128: C = ds * (cs*A - A@B)
// ---------------------------------------------------------------------------
__global__ __launch_bounds__(256) void nys_matmul(
    const float* __restrict__ A, const float* __restrict__ Bm, float* __restrict__ C,
    float cs, float ds)
{
    __shared__ __align__(16) float As[16][68];
    __shared__ __align__(16) float Bs[16][68];
    const int tid = threadIdx.x;
    const int c0 = blockIdx.x * 64, r0 = blockIdx.y * 64;
    const int base = blockIdx.z * cNL * cNL;
    const int tx = tid & 15, ty = tid >> 4;
    const int am = tid >> 2, ak = (tid & 3) * 4;
    const int bkk = tid >> 4, bn = (tid & 15) * 4;

    float acc[4][4] = {};
    for (int k0 = 0; k0 < cNL; k0 += 16) {
        float4 a4 = *reinterpret_cast<const float4*>(A + base + (r0 + am) * cNL + k0 + ak);
        As[ak + 0][am] = a4.x; As[ak + 1][am] = a4.y; As[ak + 2][am] = a4.z; As[ak + 3][am] = a4.w;
        float4 b4 = *reinterpret_cast<const float4*>(Bm + base + (k0 + bkk) * cNL + c0 + bn);
        *reinterpret_cast<float4*>(&Bs[bkk][bn]) = b4;
        __syncthreads();
#pragma unroll
        for (int kk = 0; kk < 16; ++kk) {
            float4 av  = *reinterpret_cast<const float4*>(&As[kk][ty * 4]);
            float4 bv4 = *reinterpret_cast<const float4*>(&Bs[kk][tx * 4]);
            float a_[4] = {av.x, av.y, av.z, av.w};
            float b_[4] = {bv4.x, bv4.y, bv4.z, bv4.w};
#pragma unroll
            for (int i = 0; i < 4; ++i)
#pragma unroll
                for (int j = 0; j < 4; ++j) acc[i][j] += a_[i] * b_[j];
        }
        __syncthreads();
    }
#pragma unroll
    for (int i = 0; i < 4; ++i) {
        int r = r0 + ty * 4 + i;
#pragma unroll
        for (int j = 0; j < 4; ++j) {
            int c = c0 + tx * 4 + j;
            float av = A[base + r * cNL + c];
            C[base + r * cNL + c] = ds * (cs * av - acc[i][j]);
        }
    }
}

// ---------------------------------------------------------------------------
// k3v flash-style: CV[bh][l][:] = softmax_s(Ql[bh][l].K[bh][s] - 1e9(1-mask)) @ V[bh]
// grid (NL/16, BH), block 256. Per block: 16 l-rows, stream s in tiles of 64.
// Thread t: lg = t>>4 (l-row), sq = t&15 (s-quad in dots; d-quad in PV).
// Ql row register-resident (64 VGPR); K tile transposed in LDS (pad 68);
// online softmax state (m, l) replicated across each 16-lane group via shfl_xor.
// Next tile prefetched into registers to hide global latency behind compute.
// ---------------------------------------------------------------------------
__global__ __launch_bounds__(256) void k3v_fused2(
    const float* __restrict__ Ql, const float* __restrict__ K, const float* __restrict__ V,
    const float* __restrict__ mask, float* __restrict__ CV)
{
    __shared__ __align__(16) float Kt[64][68];   // [d][s] transposed
    __shared__ __align__(16) float Vs[64][68];   // [s][d]
    __shared__ __align__(16) float Ps[16][68];   // pad 68: PV reads Ps[lg][s], lg stride 68 -> 4 distinct banks
    __shared__ __align__(16) float msk[64];
    const int bh = blockIdx.y, l0 = blockIdx.x * 16;
    const int b = bh >> 4;
    const int t = threadIdx.x;
    const int lg = t >> 4, sq = t & 15;

    // Ql row -> registers (broadcast across the 16 lanes of each group)
    float qreg[64];
    {
        const float4* qp = reinterpret_cast<const float4*>(Ql + (size_t)(bh * cNL + l0 + lg) * cHD);
#pragma unroll
        for (int u4 = 0; u4 < 16; ++u4) {
            float4 q = qp[u4];
            qreg[u4 * 4 + 0] = q.x; qreg[u4 * 4 + 1] = q.y; qreg[u4 * 4 + 2] = q.z; qreg[u4 * 4 + 3] = q.w;
        }
    }

    float O0 = 0.f, O1 = 0.f, O2 = 0.f, O3 = 0.f;
    float mrun = -1e30f, srun = 0.f;

    const size_t kvbase = (size_t)bh * cS * cHD;
    // prefetch tile 0
    float4 kx[4], vx[4];
    float mv = 0.f;
#pragma unroll
    for (int j = 0; j < 4; ++j) {
        int idx4 = t + j * 256;             // 0..1023 float4s of the 64x64 tile
        int row = idx4 >> 4, c4 = idx4 & 15;
        kx[j] = *reinterpret_cast<const float4*>(K + kvbase + (size_t)row * cHD + c4 * 4);
        vx[j] = *reinterpret_cast<const float4*>(V + kvbase + (size_t)row * cHD + c4 * 4);
    }
    if (t < 64) mv = mask[b * cS + t];

    for (int tile = 0; tile < 64; ++tile) {
        __syncthreads();    // previous PV done reading Vs/Ps
        // regs -> LDS (K transposed)
#pragma unroll
        for (int j = 0; j < 4; ++j) {
            int idx4 = t + j * 256;
            int row = idx4 >> 4, c4 = idx4 & 15;
            Kt[c4 * 4 + 0][row] = kx[j].x; Kt[c4 * 4 + 1][row] = kx[j].y;
            Kt[c4 * 4 + 2][row] = kx[j].z; Kt[c4 * 4 + 3][row] = kx[j].w;
            *reinterpret_cast<float4*>(&Vs[row][c4 * 4]) = vx[j];
        }
        if (t < 64) msk[t] = mv;
        // prefetch next tile
        if (tile < 63) {
            int s1 = (tile + 1) * 64;
#pragma unroll
            for (int j = 0; j < 4; ++j) {
                int idx4 = t + j * 256;
                int row = idx4 >> 4, c4 = idx4 & 15;
                kx[j] = *reinterpret_cast<const float4*>(K + kvbase + (size_t)(s1 + row) * cHD + c4 * 4);
                vx[j] = *reinterpret_cast<const float4*>(V + kvbase + (size_t)(s1 + row) * cHD + c4 * 4);
            }
            if (t < 64) mv = mask[b * cS + s1 + t];
        }
        __syncthreads();
        // dots: 4 logits per thread (row lg, cols sq*4..+3)
        float a0 = 0.f, a1 = 0.f, a2 = 0.f, a3 = 0.f;
#pragma unroll
        for (int u = 0; u < 64; ++u) {
            float4 k4 = *reinterpret_cast<const float4*>(&Kt[u][sq * 4]);
            float q = qreg[u];
            a0 += q * k4.x; a1 += q * k4.y; a2 += q * k4.z; a3 += q * k4.w;
        }
        float4 m4 = *reinterpret_cast<const float4*>(&msk[sq * 4]);
        a0 -= 1e9f * (1.0f - m4.x); a1 -= 1e9f * (1.0f - m4.y);
        a2 -= 1e9f * (1.0f - m4.z); a3 -= 1e9f * (1.0f - m4.w);
        // tile max across the 16-lane group
        float tmax = fmaxf(fmaxf(a0, a1), fmaxf(a2, a3));
#pragma unroll
        for (int w = 1; w < 16; w <<= 1) tmax = fmaxf(tmax, __shfl_xor(tmax, w, 16));
        float mnew = fmaxf(mrun, tmax);
        float alpha = __expf(mrun - mnew);
        float e0 = __expf(a0 - mnew), e1 = __expf(a1 - mnew);
        float e2 = __expf(a2 - mnew), e3 = __expf(a3 - mnew);
        float ts = e0 + e1 + e2 + e3;
#pragma unroll
        for (int w = 1; w < 16; w <<= 1) ts += __shfl_xor(ts, w, 16);
        srun = srun * alpha + ts;
        mrun = mnew;
        O0 *= alpha; O1 *= alpha; O2 *= alpha; O3 *= alpha;
        *reinterpret_cast<float4*>(&Ps[lg][sq * 4]) = make_float4(e0, e1, e2, e3);
        __syncthreads();
        // PV: thread (lg, dq=sq) accumulates O[lg][dq*4..+3]
#pragma unroll
        for (int s = 0; s < 64; ++s) {
            float p = Ps[lg][s];
            float4 v4 = *reinterpret_cast<const float4*>(&Vs[s][sq * 4]);
            O0 += p * v4.x; O1 += p * v4.y; O2 += p * v4.z; O3 += p * v4.w;
        }
    }
    float inv = 1.0f / srun;
    *reinterpret_cast<float4*>(CV + (size_t)(bh * cNL + l0 + lg) * cHD + sq * 4) =
        make_float4(O0 * inv, O1 * inv, O2 * inv, O3 * inv);
}

// W2[bh] = V6[bh] @ CV[bh]
__global__ __launch_bounds__(256) void w2_matmul(
    const float* __restrict__ V6, const float* __restrict__ CV, float* __restrict__ W2)
{
    __shared__ __align__(16) float CVs[128][64];
    const int bh = blockIdx.x, t = threadIdx.x;
    for (int k = 0; k < 32; ++k) { int idx = t + k * 256; CVs[idx >> 6][idx & 63] = CV[bh * 8192 + idx]; }
    __syncthreads();
    const int tx = t & 15, ty = t >> 4;
    float acc[8][4] = {};
    for (int k = 0; k < 128; ++k) {
        float4 b4 = *reinterpret_cast<const float4*>(&CVs[k][tx * 4]);
#pragma unroll
        for (int i = 0; i < 8; ++i) {
            float a = V6[(bh * cNL + ty * 8 + i) * cNL + k];
            acc[i][0] += a * b4.x; acc[i][1] += a * b4.y; acc[i][2] += a * b4.z; acc[i][3] += a * b4.w;
        }
    }
#pragma unroll
    for (int i = 0; i < 8; ++i)
#pragma unroll
        for (int j = 0; j < 4; ++j)
            W2[(bh * cNL + ty * 8 + i) * cHD + tx * 4 + j] = acc[i][j];
}

// ---------------------------------------------------------------------------
// k1_fused
// ---------------------------------------------------------------------------
__global__ __launch_bounds__(256) void k1_fused(
    const float* __restrict__ Q, const float* __restrict__ Kl, const float* __restrict__ W2,
    float* __restrict__ ctx)
{
    __shared__ __align__(16) float buf[128 * 68];
    __shared__ float pbuf[16 * 128];
    __shared__ __align__(16) float qbuf[16 * 64];
    __shared__ float rowred[16 * 16];
    __shared__ float rowmax[16];
    __shared__ float rowsum[16];
    const int bh = blockIdx.y, s0 = blockIdx.x * 16;
    const int b = bh >> 4, h = bh & 15;
    const int t = threadIdx.x;
    for (int k = 0; k < 32; ++k) { int idx = t + k * 256; buf[(idx >> 6) * 68 + (idx & 63)] = Kl[bh * 8192 + idx]; }
    for (int k = 0; k < 4; ++k)  { int idx = t + k * 256; qbuf[idx] = Q[(bh * cS + s0 + (idx >> 6)) * cHD + (idx & 63)]; }
    __syncthreads();
    const int i = t >> 4, lo = t & 15;
    const float4* qv = reinterpret_cast<const float4*>(&qbuf[i * 64]);
    float tmax = -1e30f;
    float dots[8];
#pragma unroll
    for (int k = 0; k < 8; ++k) {
        int l = lo + k * 16;
        const float4* kl4 = reinterpret_cast<const float4*>(&buf[l * 68]);
        float dot = 0.f;
#pragma unroll
        for (int u = 0; u < 16; ++u) {
            float4 a = qv[u], b4 = kl4[u];
            dot += a.x * b4.x + a.y * b4.y + a.z * b4.z + a.w * b4.w;
        }
        dots[k] = dot; tmax = fmaxf(tmax, dot);
    }
    rowred[i * 16 + lo] = tmax; __syncthreads();
    if (t < 16) { float m = rowred[t * 16]; for (int u = 1; u < 16; ++u) m = fmaxf(m, rowred[t * 16 + u]); rowmax[t] = m; }
    __syncthreads();
    float m = rowmax[i];
    float psum = 0.f;
#pragma unroll
    for (int k = 0; k < 8; ++k) {
        int l = lo + k * 16;
        float e = expf(dots[k] - m);
        pbuf[i * 128 + l] = e; psum += e;
    }
    rowred[i * 16 + lo] = psum; __syncthreads();
    if (t < 16) { float s_ = 0.f; for (int u = 0; u < 16; ++u) s_ += rowred[t * 16 + u]; rowsum[t] = s_; }
    __syncthreads();
    for (int k = 0; k < 32; ++k) { int idx = t + k * 256; buf[(idx >> 6) * 68 + (idx & 63)] = W2[bh * 8192 + idx]; }
    __syncthreads();
    const int d = t & 63, ig = t >> 6;
    float acc[4] = {};
    for (int l = 0; l < 128; ++l) {
        float w = buf[l * 68 + d];
#pragma unroll
        for (int k = 0; k < 4; ++k) acc[k] += pbuf[(ig * 4 + k) * 128 + l] * w;
    }
#pragma unroll
    for (int k = 0; k < 4; ++k) {
        int i2 = ig * 4 + k;
        ctx[(b * cS + s0 + i2) * cD + h * cHD + d] = acc[k] / rowsum[i2];
    }
}

// ---------------------------------------------------------------------------
extern "C" void kernel_launch(void* const* d_in, const int* in_sizes, int n_in,
                              void* d_out, int out_size, void* d_ws, size_t ws_size,
                              hipStream_t stream)
{
    const float* X    = (const float*)d_in[0];
    const float* mask = (const float*)d_in[1];
    const float* Wq   = (const float*)d_in[2];
    const float* bq   = (const float*)d_in[3];
    const float* Wk   = (const float*)d_in[4];
    const float* bk   = (const float*)d_in[5];
    const float* Wv   = (const float*)d_in[6];
    const float* bv   = (const float*)d_in[7];
    const float* Wo   = (const float*)d_in[8];
    const float* bo   = (const float*)d_in[9];
    float* out = (float*)d_out;

    float* ws = (float*)d_ws;
    size_t off = 0;
    const size_t szQKV = (size_t)cBH * cS * cHD;
    const size_t szL   = (size_t)cBH * cNL * cHD;
    const size_t szM   = (size_t)cBH * cNL * cNL;
    float* Q   = ws + off; off += szQKV;
    float* K   = ws + off; off += szQKV;
    float* V   = ws + off; off += szQKV;
    float* Ql  = ws + off; off += szL;
    float* Kl  = ws + off; off += szL;
    float* k2  = ws + off; off += szM;
    float* Vb0 = ws + off; off += szM;
    float* Vb1 = ws + off; off += szM;
    float* Zb  = ws + off; off += szM;
    float* T2b = ws + off; off += szM;
    float* T3b = ws + off; off += szM;
    float* CV  = ws + off; off += szL;
    float* W2  = ws + off; off += szL;
    int*   cmax = (int*)(ws + off); off += 16;
    float* ctx = K;   // K dead after k3v_fused2

    hipMemsetAsync(cmax, 0, sizeof(int), stream);

    qkv_gemm<<<dim3(cD / 64, (cB * cS) / 64, 3), 256, 0, stream>>>(
        X, mask, Wq, bq, Wk, bk, Wv, bv, Q, K, V);
    lmeans<<<2048, 256, 0, stream>>>(Q, K, Ql, Kl);
    k2_softmax<<<cBH * cNL, 128, 0, stream>>>(Ql, Kl, k2);
    colsum_max<<<cBH, 128, 0, stream>>>(k2, cmax);
    v0_kernel<<<cBH * cNL, 128, 0, stream>>>(k2, cmax, Vb0);

    float* Vc = Vb0; float* Vn = Vb1;
    for (int it = 0; it < 6; ++it) {
        nys_matmul<<<dim3(2, 2, cBH), 256, 0, stream>>>(k2, Vc, Zb, 0.f, -1.f);
        nys_matmul<<<dim3(2, 2, cBH), 256, 0, stream>>>(Zb, Zb, T2b, 7.f, 1.f);
        nys_matmul<<<dim3(2, 2, cBH), 256, 0, stream>>>(Zb, T2b, T3b, 15.f, 1.f);
        nys_matmul<<<dim3(2, 2, cBH), 256, 0, stream>>>(Vc, T3b, Vn, 13.f, 0.25f);
        float* tmp = Vc; Vc = Vn; Vn = tmp;
    }

    k3v_fused2<<<dim3(cNL / 16, cBH), 256, 0, stream>>>(Ql, K, V, mask, CV);
    w2_matmul<<<cBH, 256, 0, stream>>>(Vc, CV, W2);
    k1_fused<<<dim3(cS / 16, cBH), 256, 0, stream>>>(Q, Kl, W2, ctx);
    out_gemm<<<dim3(cD / 64, (cB * cS) / 64), 256, 0, stream>>>(ctx, Wo, bo, out);
}

// Round 3
// 929.074 us; speedup vs baseline: 3.0664x; 1.7246x over previous
//
#include <hip/hip_runtime.h>
#include <math.h>

// Problem constants
constexpr int cB = 2, cS = 4096, cHID = 1024, cNH = 16, cHD = 64, cNL = 128, cSEG = 32, cD = 1024, cBH = 32;
constexpr float cSCALE = 0.35355339059327373f;   // 1/sqrt(sqrt(64))

typedef _Float16 f16x8 __attribute__((ext_vector_type(8)));
typedef float f32x4 __attribute__((ext_vector_type(4)));

__device__ inline void gload_lds16(const void* g, void* l) {
    __builtin_amdgcn_global_load_lds(
        (const __attribute__((address_space(1))) void*)g,
        (__attribute__((address_space(3))) void*)l, 16, 0, 0);
}

// ---------------------------------------------------------------------------
// cast X fp32 -> fp16
// ---------------------------------------------------------------------------
__global__ __launch_bounds__(256) void cast_x(const float* __restrict__ X, _Float16* __restrict__ Xh)
{
    int i = (blockIdx.x * 256 + threadIdx.x) * 4;
    float4 v = *reinterpret_cast<const float4*>(X + i);
    union { _Float16 h[4]; ushort4 u; } p;
    p.h[0] = (_Float16)v.x; p.h[1] = (_Float16)v.y; p.h[2] = (_Float16)v.z; p.h[3] = (_Float16)v.w;
    *reinterpret_cast<ushort4*>(Xh + i) = p.u;
}

// ---------------------------------------------------------------------------
// transpose+cast W (K x N fp32) -> WT (N x K fp16), z selects which weight
// ---------------------------------------------------------------------------
__global__ __launch_bounds__(256) void wcast_t(
    const float* __restrict__ Wq, const float* __restrict__ Wk,
    const float* __restrict__ Wv, const float* __restrict__ Wo,
    _Float16* __restrict__ WqT, _Float16* __restrict__ WkT,
    _Float16* __restrict__ WvT, _Float16* __restrict__ WoT)
{
    __shared__ float tile[32][33];
    const int wsel = blockIdx.z;
    const float* W = (wsel == 0) ? Wq : (wsel == 1 ? Wk : (wsel == 2 ? Wv : Wo));
    _Float16* WT   = (wsel == 0) ? WqT : (wsel == 1 ? WkT : (wsel == 2 ? WvT : WoT));
    const int n0 = blockIdx.x * 32, k0 = blockIdx.y * 32;
    const int t = threadIdx.x;
    const int r = t >> 3, c = (t & 7) * 4;
    float4 v = *reinterpret_cast<const float4*>(W + (size_t)(k0 + r) * cD + n0 + c);
    tile[r][c] = v.x; tile[r][c + 1] = v.y; tile[r][c + 2] = v.z; tile[r][c + 3] = v.w;
    __syncthreads();
    union { _Float16 h[4]; ushort4 u; } p;
    p.h[0] = (_Float16)tile[c + 0][r]; p.h[1] = (_Float16)tile[c + 1][r];
    p.h[2] = (_Float16)tile[c + 2][r]; p.h[3] = (_Float16)tile[c + 3][r];
    *reinterpret_cast<ushort4*>(WT + (size_t)(n0 + r) * cHID + k0 + c) = p.u;
}

// ---------------------------------------------------------------------------
// Xm[b*128+l][:] = (1/32) sum_j mask*X ; mbar = mean mask  (fp32 landmark input)
// ---------------------------------------------------------------------------
__global__ __launch_bounds__(256) void xm_kernel(
    const float* __restrict__ X, const float* __restrict__ mask,
    float* __restrict__ Xm, float* __restrict__ mbar)
{
    const int bl = blockIdx.x;          // b*128 + l
    const int b = bl >> 7, l = bl & 127;
    const int c = threadIdx.x * 4;
    float4 a = {0.f, 0.f, 0.f, 0.f};
    float msum = 0.f;
    for (int j = 0; j < cSEG; ++j) {
        float m = mask[b * cS + l * cSEG + j];
        float4 x = *reinterpret_cast<const float4*>(X + ((size_t)(b * cS + l * cSEG + j)) * cHID + c);
        a.x += m * x.x; a.y += m * x.y; a.z += m * x.z; a.w += m * x.w;
        msum += m;
    }
    const float inv = 1.0f / cSEG;
    a.x *= inv; a.y *= inv; a.z *= inv; a.w *= inv;
    *reinterpret_cast<float4*>(Xm + (size_t)bl * cHID + c) = a;
    if (threadIdx.x == 0) mbar[bl] = msum * inv;
}

// ---------------------------------------------------------------------------
// f16 MFMA GEMM: QKV.  A = Xh [8192][1024], B = WT [1024][1024] (N-major),
// 128x128 tile, BK=32, m97 structure. Epilogue: +bias, *mask*scale (q/k),
// scatter to (B,NH,S,HD) fp32.
// ---------------------------------------------------------------------------
__global__ __launch_bounds__(256) void qkv_gemm_f16(
    const _Float16* __restrict__ Xh, const float* __restrict__ mask,
    const _Float16* __restrict__ WqT, const _Float16* __restrict__ WkT, const _Float16* __restrict__ WvT,
    const float* __restrict__ bq, const float* __restrict__ bk, const float* __restrict__ bv,
    float* __restrict__ Qo, float* __restrict__ Ko, float* __restrict__ Vo)
{
    __shared__ __align__(16) _Float16 As[128 * 32];
    __shared__ __align__(16) _Float16 Bs[128 * 32];
    const int wsel = blockIdx.z;
    const _Float16* WT = (wsel == 0) ? WqT : (wsel == 1 ? WkT : WvT);
    const float* bias  = (wsel == 0) ? bq  : (wsel == 1 ? bk  : bv);
    float* Y           = (wsel == 0) ? Qo  : (wsel == 1 ? Ko  : Vo);
    const int n0 = blockIdx.x * 128, m0 = blockIdx.y * 128;
    const int t = threadIdx.x;
    const int wave = t >> 6, lane = t & 63;
    const int wm = (wave >> 1) * 64, wn = (wave & 1) * 64;
    const int quad = lane >> 4, l15 = lane & 15;
    const int srow = wave * 32 + (lane >> 2);       // staging row within 128-tile
    const int scol = (lane & 3) * 8;                // halfs within 32-half k-row

    f32x4 acc[4][4];
#pragma unroll
    for (int i = 0; i < 4; ++i)
#pragma unroll
        for (int j = 0; j < 4; ++j) acc[i][j] = (f32x4){0.f, 0.f, 0.f, 0.f};

    for (int k0 = 0; k0 < cHID; k0 += 32) {
        const _Float16* aSrc = Xh + (size_t)(m0 + srow) * cHID + k0 + scol;
        const _Float16* bSrc = WT + (size_t)(n0 + srow) * cHID + k0 + scol;
        gload_lds16(aSrc,              &As[(wave * 32) * 32]);
        gload_lds16(aSrc + 16 * cHID,  &As[(wave * 32 + 16) * 32]);
        gload_lds16(bSrc,              &Bs[(wave * 32) * 32]);
        gload_lds16(bSrc + 16 * cHID,  &Bs[(wave * 32 + 16) * 32]);
        __syncthreads();
        f16x8 af[4], bf[4];
#pragma unroll
        for (int mt = 0; mt < 4; ++mt)
            af[mt] = *reinterpret_cast<const f16x8*>(&As[(wm + mt * 16 + l15) * 32 + quad * 8]);
#pragma unroll
        for (int nt = 0; nt < 4; ++nt)
            bf[nt] = *reinterpret_cast<const f16x8*>(&Bs[(wn + nt * 16 + l15) * 32 + quad * 8]);
#pragma unroll
        for (int mt = 0; mt < 4; ++mt)
#pragma unroll
            for (int nt = 0; nt < 4; ++nt)
                acc[mt][nt] = __builtin_amdgcn_mfma_f32_16x16x32_f16(af[mt], bf[nt], acc[mt][nt], 0, 0, 0);
        __syncthreads();
    }
#pragma unroll
    for (int mt = 0; mt < 4; ++mt) {
#pragma unroll
        for (int r = 0; r < 4; ++r) {
            int R = m0 + wm + mt * 16 + quad * 4 + r;
            int b = R >> 12, s = R & (cS - 1);
            float msc = (wsel < 2) ? mask[b * cS + s] * cSCALE : 1.0f;
#pragma unroll
            for (int nt = 0; nt < 4; ++nt) {
                int Cc = n0 + wn + nt * 16 + l15;
                int h = Cc >> 6, d = Cc & 63;
                float val = acc[mt][nt][r] + bias[Cc];
                Y[((size_t)(b * cNH + h) * cS + s) * cHD + d] = val * msc;
            }
        }
    }
}

// ---------------------------------------------------------------------------
// f16 MFMA GEMM: out = ctxh @ Wo + bo.  A = ctxh [8192][1024], B = WoT [1024][1024]
// ---------------------------------------------------------------------------
__global__ __launch_bounds__(256) void out_gemm_f16(
    const _Float16* __restrict__ Ah, const _Float16* __restrict__ WT,
    const float* __restrict__ bias, float* __restrict__ Y)
{
    __shared__ __align__(16) _Float16 As[128 * 32];
    __shared__ __align__(16) _Float16 Bs[128 * 32];
    const int n0 = blockIdx.x * 128, m0 = blockIdx.y * 128;
    const int t = threadIdx.x;
    const int wave = t >> 6, lane = t & 63;
    const int wm = (wave >> 1) * 64, wn = (wave & 1) * 64;
    const int quad = lane >> 4, l15 = lane & 15;
    const int srow = wave * 32 + (lane >> 2);
    const int scol = (lane & 3) * 8;

    f32x4 acc[4][4];
#pragma unroll
    for (int i = 0; i < 4; ++i)
#pragma unroll
        for (int j = 0; j < 4; ++j) acc[i][j] = (f32x4){0.f, 0.f, 0.f, 0.f};

    for (int k0 = 0; k0 < cD; k0 += 32) {
        const _Float16* aSrc = Ah + (size_t)(m0 + srow) * cD + k0 + scol;
        const _Float16* bSrc = WT + (size_t)(n0 + srow) * cD + k0 + scol;
        gload_lds16(aSrc,             &As[(wave * 32) * 32]);
        gload_lds16(aSrc + 16 * cD,   &As[(wave * 32 + 16) * 32]);
        gload_lds16(bSrc,             &Bs[(wave * 32) * 32]);
        gload_lds16(bSrc + 16 * cD,   &Bs[(wave * 32 + 16) * 32]);
        __syncthreads();
        f16x8 af[4], bf[4];
#pragma unroll
        for (int mt = 0; mt < 4; ++mt)
            af[mt] = *reinterpret_cast<const f16x8*>(&As[(wm + mt * 16 + l15) * 32 + quad * 8]);
#pragma unroll
        for (int nt = 0; nt < 4; ++nt)
            bf[nt] = *reinterpret_cast<const f16x8*>(&Bs[(wn + nt * 16 + l15) * 32 + quad * 8]);
#pragma unroll
        for (int mt = 0; mt < 4; ++mt)
#pragma unroll
            for (int nt = 0; nt < 4; ++nt)
                acc[mt][nt] = __builtin_amdgcn_mfma_f32_16x16x32_f16(af[mt], bf[nt], acc[mt][nt], 0, 0, 0);
        __syncthreads();
    }
#pragma unroll
    for (int mt = 0; mt < 4; ++mt) {
#pragma unroll
        for (int r = 0; r < 4; ++r) {
            int R = m0 + wm + mt * 16 + quad * 4 + r;
#pragma unroll
            for (int nt = 0; nt < 4; ++nt) {
                int Cc = n0 + wn + nt * 16 + l15;
                Y[(size_t)R * cHID + Cc] = acc[mt][nt][r] + bias[Cc];
            }
        }
    }
}

// ---------------------------------------------------------------------------
// Landmark GEMM (fp32, exact path for the ill-conditioned inverse chain):
// Ql/Kl[((b*16+h)*128+l)*64+d] = scale * (Xm[b*128+l] @ W + mbar*bias)
// ---------------------------------------------------------------------------
__global__ __launch_bounds__(256) void lgemm(
    const float* __restrict__ Xm, const float* __restrict__ mbar,
    const float* __restrict__ Wq, const float* __restrict__ bq,
    const float* __restrict__ Wk, const float* __restrict__ bk,
    float* __restrict__ Ql, float* __restrict__ Kl)
{
    __shared__ __align__(16) float As[16][68];
    __shared__ __align__(16) float Bs[16][68];
    const int tid = threadIdx.x;
    const int wsel = blockIdx.z;
    const float* W    = wsel ? Wk : Wq;
    const float* bias = wsel ? bk : bq;
    float* Yl         = wsel ? Kl : Ql;
    const int c0 = blockIdx.x * 64, r0 = blockIdx.y * 64;
    const int tx = tid & 15, ty = tid >> 4;
    const int am = tid >> 2, ak = (tid & 3) * 4;
    const int bkk = tid >> 4, bn = (tid & 15) * 4;

    float acc[4][4] = {};
    for (int k0 = 0; k0 < cHID; k0 += 16) {
        float4 a4 = *reinterpret_cast<const float4*>(Xm + (size_t)(r0 + am) * cHID + k0 + ak);
        As[ak + 0][am] = a4.x; As[ak + 1][am] = a4.y; As[ak + 2][am] = a4.z; As[ak + 3][am] = a4.w;
        float4 b4 = *reinterpret_cast<const float4*>(W + (size_t)(k0 + bkk) * cD + c0 + bn);
        *reinterpret_cast<float4*>(&Bs[bkk][bn]) = b4;
        __syncthreads();
#pragma unroll
        for (int kk = 0; kk < 16; ++kk) {
            float4 av  = *reinterpret_cast<const float4*>(&As[kk][ty * 4]);
            float4 bv4 = *reinterpret_cast<const float4*>(&Bs[kk][tx * 4]);
            float a_[4] = {av.x, av.y, av.z, av.w};
            float b_[4] = {bv4.x, bv4.y, bv4.z, bv4.w};
#pragma unroll
            for (int i = 0; i < 4; ++i)
#pragma unroll
                for (int j = 0; j < 4; ++j) acc[i][j] += a_[i] * b_[j];
        }
        __syncthreads();
    }
#pragma unroll
    for (int i = 0; i < 4; ++i) {
        int r = r0 + ty * 4 + i;          // b*128 + l
        int b = r >> 7, l = r & 127;
        float mb = mbar[r];
#pragma unroll
        for (int j = 0; j < 4; ++j) {
            int c = c0 + tx * 4 + j;
            int h = c >> 6, d = c & 63;
            Yl[((size_t)(b * cNH + h) * cNL + l) * cHD + d] = (acc[i][j] + mb * bias[c]) * cSCALE;
        }
    }
}

// ---------------------------------------------------------------------------
// k2 softmax (fp32-clean path)
// ---------------------------------------------------------------------------
__global__ __launch_bounds__(128) void k2_softmax(
    const float* __restrict__ Ql, const float* __restrict__ Kl, float* __restrict__ k2)
{
    __shared__ __align__(16) float qrow[64];
    __shared__ float red[128];
    int bh = blockIdx.x >> 7, i = blockIdx.x & 127;
    int j = threadIdx.x;
    if (j < 64) qrow[j] = Ql[(bh * cNL + i) * cHD + j];
    __syncthreads();
    const float4* q4  = reinterpret_cast<const float4*>(qrow);
    const float4* kl4 = reinterpret_cast<const float4*>(Kl + (bh * cNL + j) * cHD);
    float dot = 0.f;
#pragma unroll
    for (int u = 0; u < 16; ++u) {
        float4 a = q4[u], b = kl4[u];
        dot += a.x * b.x + a.y * b.y + a.z * b.z + a.w * b.w;
    }
    red[j] = dot; __syncthreads();
    for (int off = 64; off > 0; off >>= 1) { if (j < off) red[j] = fmaxf(red[j], red[j + off]); __syncthreads(); }
    float m = red[0]; __syncthreads();
    float e = expf(dot - m);
    red[j] = e; __syncthreads();
    for (int off = 64; off > 0; off >>= 1) { if (j < off) red[j] += red[j + off]; __syncthreads(); }
    k2[(bh * cNL + i) * cNL + j] = e / red[0];
}

__global__ __launch_bounds__(128) void colsum_max(const float* __restrict__ k2, int* __restrict__ cmax)
{
    __shared__ float red[128];
    int bh = blockIdx.x, j = threadIdx.x;
    float s = 0.f;
    for (int i = 0; i < cNL; ++i) s += k2[(bh * cNL + i) * cNL + j];
    red[j] = s; __syncthreads();
    for (int off = 64; off > 0; off >>= 1) { if (j < off) red[j] = fmaxf(red[j], red[j + off]); __syncthreads(); }
    if (j == 0) atomicMax(cmax, __float_as_int(red[0]));
}

__global__ __launch_bounds__(128) void v0_kernel(
    const float* __restrict__ k2, const int* __restrict__ cmax, float* __restrict__ V0)
{
    int bh = blockIdx.x >> 7, i = blockIdx.x & 127, j = threadIdx.x;
    float c = __int_as_float(*cmax);
    V0[(bh * cNL + i) * cNL + j] = k2[(bh * cNL + j) * cNL + i] / c;
}

// ---------------------------------------------------------------------------
// Batched 128x128: C = ds * (cs*A - A@B)
// ---------------------------------------------------------------------------
__global__ __launch_bounds__(256) void nys_matmul(
    const float* __restrict__ A, const float* __restrict__ Bm, float* __restrict__ C,
    float cs, float ds)
{
    __shared__ __align__(16) float As[16][68];
    __shared__ __align__(16) float Bs[16][68];
    const int tid = threadIdx.x;
    const int c0 = blockIdx.x * 64, r0 = blockIdx.y * 64;
    const int base = blockIdx.z * cNL * cNL;
    const int tx = tid & 15, ty = tid >> 4;
    const int am = tid >> 2, ak = (tid & 3) * 4;
    const int bkk = tid >> 4, bn = (tid & 15) * 4;

    float acc[4][4] = {};
    for (int k0 = 0; k0 < cNL; k0 += 16) {
        float4 a4 = *reinterpret_cast<const float4*>(A + base + (r0 + am) * cNL + k0 + ak);
        As[ak + 0][am] = a4.x; As[ak + 1][am] = a4.y; As[ak + 2][am] = a4.z; As[ak + 3][am] = a4.w;
        float4 b4 = *reinterpret_cast<const float4*>(Bm + base + (k0 + bkk) * cNL + c0 + bn);
        *reinterpret_cast<float4*>(&Bs[bkk][bn]) = b4;
        __syncthreads();
#pragma unroll
        for (int kk = 0; kk < 16; ++kk) {
            float4 av  = *reinterpret_cast<const float4*>(&As[kk][ty * 4]);
            float4 bv4 = *reinterpret_cast<const float4*>(&Bs[kk][tx * 4]);
            float a_[4] = {av.x, av.y, av.z, av.w};
            float b_[4] = {bv4.x, bv4.y, bv4.z, bv4.w};
#pragma unroll
            for (int i = 0; i < 4; ++i)
#pragma unroll
                for (int j = 0; j < 4; ++j) acc[i][j] += a_[i] * b_[j];
        }
        __syncthreads();
    }
#pragma unroll
    for (int i = 0; i < 4; ++i) {
        int r = r0 + ty * 4 + i;
#pragma unroll
        for (int j = 0; j < 4; ++j) {
            int c = c0 + tx * 4 + j;
            float av = A[base + r * cNL + c];
            C[base + r * cNL + c] = ds * (cs * av - acc[i][j]);
        }
    }
}

// ---------------------------------------------------------------------------
// k3v flash-style (unchanged from R2)
// ---------------------------------------------------------------------------
__global__ __launch_bounds__(256) void k3v_fused2(
    const float* __restrict__ Ql, const float* __restrict__ K, const float* __restrict__ V,
    const float* __restrict__ mask, float* __restrict__ CV)
{
    __shared__ __align__(16) float Kt[64][68];
    __shared__ __align__(16) float Vs[64][68];
    __shared__ __align__(16) float Ps[16][68];
    __shared__ __align__(16) float msk[64];
    const int bh = blockIdx.y, l0 = blockIdx.x * 16;
    const int b = bh >> 4;
    const int t = threadIdx.x;
    const int lg = t >> 4, sq = t & 15;

    float qreg[64];
    {
        const float4* qp = reinterpret_cast<const float4*>(Ql + (size_t)(bh * cNL + l0 + lg) * cHD);
#pragma unroll
        for (int u4 = 0; u4 < 16; ++u4) {
            float4 q = qp[u4];
            qreg[u4 * 4 + 0] = q.x; qreg[u4 * 4 + 1] = q.y; qreg[u4 * 4 + 2] = q.z; qreg[u4 * 4 + 3] = q.w;
        }
    }

    float O0 = 0.f, O1 = 0.f, O2 = 0.f, O3 = 0.f;
    float mrun = -1e30f, srun = 0.f;

    const size_t kvbase = (size_t)bh * cS * cHD;
    float4 kx[4], vx[4];
    float mv = 0.f;
#pragma unroll
    for (int j = 0; j < 4; ++j) {
        int idx4 = t + j * 256;
        int row = idx4 >> 4, c4 = idx4 & 15;
        kx[j] = *reinterpret_cast<const float4*>(K + kvbase + (size_t)row * cHD + c4 * 4);
        vx[j] = *reinterpret_cast<const float4*>(V + kvbase + (size_t)row * cHD + c4 * 4);
    }
    if (t < 64) mv = mask[b * cS + t];

    for (int tile = 0; tile < 64; ++tile) {
        __syncthreads();
#pragma unroll
        for (int j = 0; j < 4; ++j) {
            int idx4 = t + j * 256;
            int row = idx4 >> 4, c4 = idx4 & 15;
            Kt[c4 * 4 + 0][row] = kx[j].x; Kt[c4 * 4 + 1][row] = kx[j].y;
            Kt[c4 * 4 + 2][row] = kx[j].z; Kt[c4 * 4 + 3][row] = kx[j].w;
            *reinterpret_cast<float4*>(&Vs[row][c4 * 4]) = vx[j];
        }
        if (t < 64) msk[t] = mv;
        if (tile < 63) {
            int s1 = (tile + 1) * 64;
#pragma unroll
            for (int j = 0; j < 4; ++j) {
                int idx4 = t + j * 256;
                int row = idx4 >> 4, c4 = idx4 & 15;
                kx[j] = *reinterpret_cast<const float4*>(K + kvbase + (size_t)(s1 + row) * cHD + c4 * 4);
                vx[j] = *reinterpret_cast<const float4*>(V + kvbase + (size_t)(s1 + row) * cHD + c4 * 4);
            }
            if (t < 64) mv = mask[b * cS + s1 + t];
        }
        __syncthreads();
        float a0 = 0.f, a1 = 0.f, a2 = 0.f, a3 = 0.f;
#pragma unroll
        for (int u = 0; u < 64; ++u) {
            float4 k4 = *reinterpret_cast<const float4*>(&Kt[u][sq * 4]);
            float q = qreg[u];
            a0 += q * k4.x; a1 += q * k4.y; a2 += q * k4.z; a3 += q * k4.w;
        }
        float4 m4 = *reinterpret_cast<const float4*>(&msk[sq * 4]);
        a0 -= 1e9f * (1.0f - m4.x); a1 -= 1e9f * (1.0f - m4.y);
        a2 -= 1e9f * (1.0f - m4.z); a3 -= 1e9f * (1.0f - m4.w);
        float tmax = fmaxf(fmaxf(a0, a1), fmaxf(a2, a3));
#pragma unroll
        for (int w = 1; w < 16; w <<= 1) tmax = fmaxf(tmax, __shfl_xor(tmax, w, 16));
        float mnew = fmaxf(mrun, tmax);
        float alpha = __expf(mrun - mnew);
        float e0 = __expf(a0 - mnew), e1 = __expf(a1 - mnew);
        float e2 = __expf(a2 - mnew), e3 = __expf(a3 - mnew);
        float ts = e0 + e1 + e2 + e3;
#pragma unroll
        for (int w = 1; w < 16; w <<= 1) ts += __shfl_xor(ts, w, 16);
        srun = srun * alpha + ts;
        mrun = mnew;
        O0 *= alpha; O1 *= alpha; O2 *= alpha; O3 *= alpha;
        *reinterpret_cast<float4*>(&Ps[lg][sq * 4]) = make_float4(e0, e1, e2, e3);
        __syncthreads();
#pragma unroll
        for (int s = 0; s < 64; ++s) {
            float p = Ps[lg][s];
            float4 v4 = *reinterpret_cast<const float4*>(&Vs[s][sq * 4]);
            O0 += p * v4.x; O1 += p * v4.y; O2 += p * v4.z; O3 += p * v4.w;
        }
    }
    float inv = 1.0f / srun;
    *reinterpret_cast<float4*>(CV + (size_t)(bh * cNL + l0 + lg) * cHD + sq * 4) =
        make_float4(O0 * inv, O1 * inv, O2 * inv, O3 * inv);
}

// W2[bh] = V6[bh] @ CV[bh]
__global__ __launch_bounds__(256) void w2_matmul(
    const float* __restrict__ V6, const float* __restrict__ CV, float* __restrict__ W2)
{
    __shared__ __align__(16) float CVs[128][64];
    const int bh = blockIdx.x, t = threadIdx.x;
    for (int k = 0; k < 32; ++k) { int idx = t + k * 256; CVs[idx >> 6][idx & 63] = CV[bh * 8192 + idx]; }
    __syncthreads();
    const int tx = t & 15, ty = t >> 4;
    float acc[8][4] = {};
    for (int k = 0; k < 128; ++k) {
        float4 b4 = *reinterpret_cast<const float4*>(&CVs[k][tx * 4]);
#pragma unroll
        for (int i = 0; i < 8; ++i) {
            float a = V6[(bh * cNL + ty * 8 + i) * cNL + k];
            acc[i][0] += a * b4.x; acc[i][1] += a * b4.y; acc[i][2] += a * b4.z; acc[i][3] += a * b4.w;
        }
    }
#pragma unroll
    for (int i = 0; i < 8; ++i)
#pragma unroll
        for (int j = 0; j < 4; ++j)
            W2[(bh * cNL + ty * 8 + i) * cHD + tx * 4 + j] = acc[i][j];
}

// ---------------------------------------------------------------------------
// k1_fused — now writes fp16 ctx for the MFMA output GEMM
// ---------------------------------------------------------------------------
__global__ __launch_bounds__(256) void k1_fused(
    const float* __restrict__ Q, const float* __restrict__ Kl, const float* __restrict__ W2,
    _Float16* __restrict__ ctxh)
{
    __shared__ __align__(16) float buf[128 * 68];
    __shared__ float pbuf[16 * 128];
    __shared__ __align__(16) float qbuf[16 * 64];
    __shared__ float rowred[16 * 16];
    __shared__ float rowmax[16];
    __shared__ float rowsum[16];
    const int bh = blockIdx.y, s0 = blockIdx.x * 16;
    const int b = bh >> 4, h = bh & 15;
    const int t = threadIdx.x;
    for (int k = 0; k < 32; ++k) { int idx = t + k * 256; buf[(idx >> 6) * 68 + (idx & 63)] = Kl[bh * 8192 + idx]; }
    for (int k = 0; k < 4; ++k)  { int idx = t + k * 256; qbuf[idx] = Q[(size_t)(bh * cS + s0 + (idx >> 6)) * cHD + (idx & 63)]; }
    __syncthreads();
    const int i = t >> 4, lo = t & 15;
    const float4* qv = reinterpret_cast<const float4*>(&qbuf[i * 64]);
    float tmax = -1e30f;
    float dots[8];
#pragma unroll
    for (int k = 0; k < 8; ++k) {
        int l = lo + k * 16;
        const float4* kl4 = reinterpret_cast<const float4*>(&buf[l * 68]);
        float dot = 0.f;
#pragma unroll
        for (int u = 0; u < 16; ++u) {
            float4 a = qv[u], b4 = kl4[u];
            dot += a.x * b4.x + a.y * b4.y + a.z * b4.z + a.w * b4.w;
        }
        dots[k] = dot; tmax = fmaxf(tmax, dot);
    }
    rowred[i * 16 + lo] = tmax; __syncthreads();
    if (t < 16) { float m = rowred[t * 16]; for (int u = 1; u < 16; ++u) m = fmaxf(m, rowred[t * 16 + u]); rowmax[t] = m; }
    __syncthreads();
    float m = rowmax[i];
    float psum = 0.f;
#pragma unroll
    for (int k = 0; k < 8; ++k) {
        int l = lo + k * 16;
        float e = expf(dots[k] - m);
        pbuf[i * 128 + l] = e; psum += e;
    }
    rowred[i * 16 + lo] = psum; __syncthreads();
    if (t < 16) { float s_ = 0.f; for (int u = 0; u < 16; ++u) s_ += rowred[t * 16 + u]; rowsum[t] = s_; }
    __syncthreads();
    for (int k = 0; k < 32; ++k) { int idx = t + k * 256; buf[(idx >> 6) * 68 + (idx & 63)] = W2[bh * 8192 + idx]; }
    __syncthreads();
    const int d = t & 63, ig = t >> 6;
    float acc[4] = {};
    for (int l = 0; l < 128; ++l) {
        float w = buf[l * 68 + d];
#pragma unroll
        for (int k = 0; k < 4; ++k) acc[k] += pbuf[(ig * 4 + k) * 128 + l] * w;
    }
#pragma unroll
    for (int k = 0; k < 4; ++k) {
        int i2 = ig * 4 + k;
        ctxh[(size_t)(b * cS + s0 + i2) * cD + h * cHD + d] = (_Float16)(acc[k] / rowsum[i2]);
    }
}

// ---------------------------------------------------------------------------
extern "C" void kernel_launch(void* const* d_in, const int* in_sizes, int n_in,
                              void* d_out, int out_size, void* d_ws, size_t ws_size,
                              hipStream_t stream)
{
    const float* X    = (const float*)d_in[0];
    const float* mask = (const float*)d_in[1];
    const float* Wq   = (const float*)d_in[2];
    const float* bq   = (const float*)d_in[3];
    const float* Wk   = (const float*)d_in[4];
    const float* bk   = (const float*)d_in[5];
    const float* Wv   = (const float*)d_in[6];
    const float* bv   = (const float*)d_in[7];
    const float* Wo   = (const float*)d_in[8];
    const float* bo   = (const float*)d_in[9];
    float* out = (float*)d_out;

    float* ws = (float*)d_ws;
    size_t off = 0;
    const size_t szQKV = (size_t)cBH * cS * cHD;      // 8388608 floats
    const size_t szL   = (size_t)cBH * cNL * cHD;     // 262144
    const size_t szM   = (size_t)cBH * cNL * cNL;     // 524288
    float* Q    = ws + off; off += szQKV;
    float* K    = ws + off; off += szQKV;
    float* V    = ws + off; off += szQKV;
    _Float16* Xh  = (_Float16*)(ws + off); off += szQKV / 2;      // 8.4M halfs
    _Float16* WqT = (_Float16*)(ws + off); off += 524288;         // 1M halfs
    _Float16* WkT = (_Float16*)(ws + off); off += 524288;
    _Float16* WvT = (_Float16*)(ws + off); off += 524288;
    _Float16* WoT = (_Float16*)(ws + off); off += 524288;
    float* Xm   = ws + off; off += (size_t)cB * cNL * cHID;       // 262144
    float* mbar = ws + off; off += 256;
    float* Ql  = ws + off; off += szL;
    float* Kl  = ws + off; off += szL;
    float* k2  = ws + off; off += szM;
    float* Vb0 = ws + off; off += szM;
    float* Vb1 = ws + off; off += szM;
    float* Zb  = ws + off; off += szM;
    float* T2b = ws + off; off += szM;
    float* T3b = ws + off; off += szM;
    float* CV  = ws + off; off += szL;
    float* W2  = ws + off; off += szL;
    int*   cmax = (int*)(ws + off); off += 16;
    _Float16* ctxh = (_Float16*)K;   // K dead after k3v_fused2; 16 MB fp16 fits in its 32 MB

    hipMemsetAsync(cmax, 0, sizeof(int), stream);

    cast_x<<<(int)(szQKV / 1024), 256, 0, stream>>>(X, Xh);
    wcast_t<<<dim3(32, 32, 4), 256, 0, stream>>>(Wq, Wk, Wv, Wo, WqT, WkT, WvT, WoT);
    xm_kernel<<<cB * cNL, 256, 0, stream>>>(X, mask, Xm, mbar);

    qkv_gemm_f16<<<dim3(cD / 128, (cB * cS) / 128, 3), 256, 0, stream>>>(
        Xh, mask, WqT, WkT, WvT, bq, bk, bv, Q, K, V);
    lgemm<<<dim3(cD / 64, (cB * cNL) / 64, 2), 256, 0, stream>>>(Xm, mbar, Wq, bq, Wk, bk, Ql, Kl);

    k2_softmax<<<cBH * cNL, 128, 0, stream>>>(Ql, Kl, k2);
    colsum_max<<<cBH, 128, 0, stream>>>(k2, cmax);
    v0_kernel<<<cBH * cNL, 128, 0, stream>>>(k2, cmax, Vb0);

    float* Vc = Vb0; float* Vn = Vb1;
    for (int it = 0; it < 6; ++it) {
        nys_matmul<<<dim3(2, 2, cBH), 256, 0, stream>>>(k2, Vc, Zb, 0.f, -1.f);
        nys_matmul<<<dim3(2, 2, cBH), 256, 0, stream>>>(Zb, Zb, T2b, 7.f, 1.f);
        nys_matmul<<<dim3(2, 2, cBH), 256, 0, stream>>>(Zb, T2b, T3b, 15.f, 1.f);
        nys_matmul<<<dim3(2, 2, cBH), 256, 0, stream>>>(Vc, T3b, Vn, 13.f, 0.25f);
        float* tmp = Vc; Vc = Vn; Vn = tmp;
    }

    k3v_fused2<<<dim3(cNL / 16, cBH), 256, 0, stream>>>(Ql, K, V, mask, CV);
    w2_matmul<<<cBH, 256, 0, stream>>>(Vc, CV, W2);
    k1_fused<<<dim3(cS / 16, cBH), 256, 0, stream>>>(Q, Kl, W2, ctxh);
    out_gemm_f16<<<dim3(cHID / 128, (cB * cS) / 128), 256, 0, stream>>>(ctxh, WoT, bo, out);
}

// Round 4
// 851.681 us; speedup vs baseline: 3.3451x; 1.0909x over previous
//
#include <hip/hip_runtime.h>
#include <math.h>

// Problem constants
constexpr int cB = 2, cS = 4096, cHID = 1024, cNH = 16, cHD = 64, cNL = 128, cSEG = 32, cD = 1024, cBH = 32;
constexpr float cSCALE = 0.35355339059327373f;   // 1/sqrt(sqrt(64))

typedef _Float16 f16x8 __attribute__((ext_vector_type(8)));
typedef float f32x4 __attribute__((ext_vector_type(4)));

__device__ inline void gload_lds16(const void* g, void* l) {
    __builtin_amdgcn_global_load_lds(
        (const __attribute__((address_space(1))) void*)g,
        (__attribute__((address_space(3))) void*)l, 16, 0, 0);
}

// ---------------------------------------------------------------------------
// cast X fp32 -> fp16
// ---------------------------------------------------------------------------
__global__ __launch_bounds__(256) void cast_x(const float* __restrict__ X, _Float16* __restrict__ Xh)
{
    int i = (blockIdx.x * 256 + threadIdx.x) * 4;
    float4 v = *reinterpret_cast<const float4*>(X + i);
    union { _Float16 h[4]; ushort4 u; } p;
    p.h[0] = (_Float16)v.x; p.h[1] = (_Float16)v.y; p.h[2] = (_Float16)v.z; p.h[3] = (_Float16)v.w;
    *reinterpret_cast<ushort4*>(Xh + i) = p.u;
}

// ---------------------------------------------------------------------------
// transpose+cast W (K x N fp32) -> WT (N x K fp16), z selects which weight
// ---------------------------------------------------------------------------
__global__ __launch_bounds__(256) void wcast_t(
    const float* __restrict__ Wq, const float* __restrict__ Wk,
    const float* __restrict__ Wv, const float* __restrict__ Wo,
    _Float16* __restrict__ WqT, _Float16* __restrict__ WkT,
    _Float16* __restrict__ WvT, _Float16* __restrict__ WoT)
{
    __shared__ float tile[32][33];
    const int wsel = blockIdx.z;
    const float* W = (wsel == 0) ? Wq : (wsel == 1 ? Wk : (wsel == 2 ? Wv : Wo));
    _Float16* WT   = (wsel == 0) ? WqT : (wsel == 1 ? WkT : (wsel == 2 ? WvT : WoT));
    const int n0 = blockIdx.x * 32, k0 = blockIdx.y * 32;
    const int t = threadIdx.x;
    const int r = t >> 3, c = (t & 7) * 4;
    float4 v = *reinterpret_cast<const float4*>(W + (size_t)(k0 + r) * cD + n0 + c);
    tile[r][c] = v.x; tile[r][c + 1] = v.y; tile[r][c + 2] = v.z; tile[r][c + 3] = v.w;
    __syncthreads();
    union { _Float16 h[4]; ushort4 u; } p;
    p.h[0] = (_Float16)tile[c + 0][r]; p.h[1] = (_Float16)tile[c + 1][r];
    p.h[2] = (_Float16)tile[c + 2][r]; p.h[3] = (_Float16)tile[c + 3][r];
    *reinterpret_cast<ushort4*>(WT + (size_t)(n0 + r) * cHID + k0 + c) = p.u;
}

// ---------------------------------------------------------------------------
// Xm[b*128+l][:] = (1/32) sum_j mask*X ; mbar = mean mask  (fp32 landmark input)
// ---------------------------------------------------------------------------
__global__ __launch_bounds__(256) void xm_kernel(
    const float* __restrict__ X, const float* __restrict__ mask,
    float* __restrict__ Xm, float* __restrict__ mbar)
{
    const int bl = blockIdx.x;          // b*128 + l
    const int b = bl >> 7, l = bl & 127;
    const int c = threadIdx.x * 4;
    float4 a = {0.f, 0.f, 0.f, 0.f};
    float msum = 0.f;
    for (int j = 0; j < cSEG; ++j) {
        float m = mask[b * cS + l * cSEG + j];
        float4 x = *reinterpret_cast<const float4*>(X + ((size_t)(b * cS + l * cSEG + j)) * cHID + c);
        a.x += m * x.x; a.y += m * x.y; a.z += m * x.z; a.w += m * x.w;
        msum += m;
    }
    const float inv = 1.0f / cSEG;
    a.x *= inv; a.y *= inv; a.z *= inv; a.w *= inv;
    *reinterpret_cast<float4*>(Xm + (size_t)bl * cHID + c) = a;
    if (threadIdx.x == 0) mbar[bl] = msum * inv;
}

// ---------------------------------------------------------------------------
// f16 MFMA GEMM: QKV
// ---------------------------------------------------------------------------
__global__ __launch_bounds__(256) void qkv_gemm_f16(
    const _Float16* __restrict__ Xh, const float* __restrict__ mask,
    const _Float16* __restrict__ WqT, const _Float16* __restrict__ WkT, const _Float16* __restrict__ WvT,
    const float* __restrict__ bq, const float* __restrict__ bk, const float* __restrict__ bv,
    float* __restrict__ Qo, float* __restrict__ Ko, float* __restrict__ Vo)
{
    __shared__ __align__(16) _Float16 As[128 * 32];
    __shared__ __align__(16) _Float16 Bs[128 * 32];
    const int wsel = blockIdx.z;
    const _Float16* WT = (wsel == 0) ? WqT : (wsel == 1 ? WkT : WvT);
    const float* bias  = (wsel == 0) ? bq  : (wsel == 1 ? bk  : bv);
    float* Y           = (wsel == 0) ? Qo  : (wsel == 1 ? Ko  : Vo);
    const int n0 = blockIdx.x * 128, m0 = blockIdx.y * 128;
    const int t = threadIdx.x;
    const int wave = t >> 6, lane = t & 63;
    const int wm = (wave >> 1) * 64, wn = (wave & 1) * 64;
    const int quad = lane >> 4, l15 = lane & 15;
    const int srow = wave * 32 + (lane >> 2);
    const int scol = (lane & 3) * 8;

    f32x4 acc[4][4];
#pragma unroll
    for (int i = 0; i < 4; ++i)
#pragma unroll
        for (int j = 0; j < 4; ++j) acc[i][j] = (f32x4){0.f, 0.f, 0.f, 0.f};

    for (int k0 = 0; k0 < cHID; k0 += 32) {
        const _Float16* aSrc = Xh + (size_t)(m0 + srow) * cHID + k0 + scol;
        const _Float16* bSrc = WT + (size_t)(n0 + srow) * cHID + k0 + scol;
        gload_lds16(aSrc,              &As[(wave * 32) * 32]);
        gload_lds16(aSrc + 16 * cHID,  &As[(wave * 32 + 16) * 32]);
        gload_lds16(bSrc,              &Bs[(wave * 32) * 32]);
        gload_lds16(bSrc + 16 * cHID,  &Bs[(wave * 32 + 16) * 32]);
        __syncthreads();
        f16x8 af[4], bf[4];
#pragma unroll
        for (int mt = 0; mt < 4; ++mt)
            af[mt] = *reinterpret_cast<const f16x8*>(&As[(wm + mt * 16 + l15) * 32 + quad * 8]);
#pragma unroll
        for (int nt = 0; nt < 4; ++nt)
            bf[nt] = *reinterpret_cast<const f16x8*>(&Bs[(wn + nt * 16 + l15) * 32 + quad * 8]);
#pragma unroll
        for (int mt = 0; mt < 4; ++mt)
#pragma unroll
            for (int nt = 0; nt < 4; ++nt)
                acc[mt][nt] = __builtin_amdgcn_mfma_f32_16x16x32_f16(af[mt], bf[nt], acc[mt][nt], 0, 0, 0);
        __syncthreads();
    }
#pragma unroll
    for (int mt = 0; mt < 4; ++mt) {
#pragma unroll
        for (int r = 0; r < 4; ++r) {
            int R = m0 + wm + mt * 16 + quad * 4 + r;
            int b = R >> 12, s = R & (cS - 1);
            float msc = (wsel < 2) ? mask[b * cS + s] * cSCALE : 1.0f;
#pragma unroll
            for (int nt = 0; nt < 4; ++nt) {
                int Cc = n0 + wn + nt * 16 + l15;
                int h = Cc >> 6, d = Cc & 63;
                float val = acc[mt][nt][r] + bias[Cc];
                Y[((size_t)(b * cNH + h) * cS + s) * cHD + d] = val * msc;
            }
        }
    }
}

// ---------------------------------------------------------------------------
// f16 MFMA GEMM: out = ctxh @ Wo + bo
// ---------------------------------------------------------------------------
__global__ __launch_bounds__(256) void out_gemm_f16(
    const _Float16* __restrict__ Ah, const _Float16* __restrict__ WT,
    const float* __restrict__ bias, float* __restrict__ Y)
{
    __shared__ __align__(16) _Float16 As[128 * 32];
    __shared__ __align__(16) _Float16 Bs[128 * 32];
    const int n0 = blockIdx.x * 128, m0 = blockIdx.y * 128;
    const int t = threadIdx.x;
    const int wave = t >> 6, lane = t & 63;
    const int wm = (wave >> 1) * 64, wn = (wave & 1) * 64;
    const int quad = lane >> 4, l15 = lane & 15;
    const int srow = wave * 32 + (lane >> 2);
    const int scol = (lane & 3) * 8;

    f32x4 acc[4][4];
#pragma unroll
    for (int i = 0; i < 4; ++i)
#pragma unroll
        for (int j = 0; j < 4; ++j) acc[i][j] = (f32x4){0.f, 0.f, 0.f, 0.f};

    for (int k0 = 0; k0 < cD; k0 += 32) {
        const _Float16* aSrc = Ah + (size_t)(m0 + srow) * cD + k0 + scol;
        const _Float16* bSrc = WT + (size_t)(n0 + srow) * cD + k0 + scol;
        gload_lds16(aSrc,             &As[(wave * 32) * 32]);
        gload_lds16(aSrc + 16 * cD,   &As[(wave * 32 + 16) * 32]);
        gload_lds16(bSrc,             &Bs[(wave * 32) * 32]);
        gload_lds16(bSrc + 16 * cD,   &Bs[(wave * 32 + 16) * 32]);
        __syncthreads();
        f16x8 af[4], bf[4];
#pragma unroll
        for (int mt = 0; mt < 4; ++mt)
            af[mt] = *reinterpret_cast<const f16x8*>(&As[(wm + mt * 16 + l15) * 32 + quad * 8]);
#pragma unroll
        for (int nt = 0; nt < 4; ++nt)
            bf[nt] = *reinterpret_cast<const f16x8*>(&Bs[(wn + nt * 16 + l15) * 32 + quad * 8]);
#pragma unroll
        for (int mt = 0; mt < 4; ++mt)
#pragma unroll
            for (int nt = 0; nt < 4; ++nt)
                acc[mt][nt] = __builtin_amdgcn_mfma_f32_16x16x32_f16(af[mt], bf[nt], acc[mt][nt], 0, 0, 0);
        __syncthreads();
    }
#pragma unroll
    for (int mt = 0; mt < 4; ++mt) {
#pragma unroll
        for (int r = 0; r < 4; ++r) {
            int R = m0 + wm + mt * 16 + quad * 4 + r;
#pragma unroll
            for (int nt = 0; nt < 4; ++nt) {
                int Cc = n0 + wn + nt * 16 + l15;
                Y[(size_t)R * cHID + Cc] = acc[mt][nt][r] + bias[Cc];
            }
        }
    }
}

// ---------------------------------------------------------------------------
// Landmark GEMM (fp32, exact path for the ill-conditioned inverse chain)
// ---------------------------------------------------------------------------
__global__ __launch_bounds__(256) void lgemm(
    const float* __restrict__ Xm, const float* __restrict__ mbar,
    const float* __restrict__ Wq, const float* __restrict__ bq,
    const float* __restrict__ Wk, const float* __restrict__ bk,
    float* __restrict__ Ql, float* __restrict__ Kl)
{
    __shared__ __align__(16) float As[16][68];
    __shared__ __align__(16) float Bs[16][68];
    const int tid = threadIdx.x;
    const int wsel = blockIdx.z;
    const float* W    = wsel ? Wk : Wq;
    const float* bias = wsel ? bk : bq;
    float* Yl         = wsel ? Kl : Ql;
    const int c0 = blockIdx.x * 64, r0 = blockIdx.y * 64;
    const int tx = tid & 15, ty = tid >> 4;
    const int am = tid >> 2, ak = (tid & 3) * 4;
    const int bkk = tid >> 4, bn = (tid & 15) * 4;

    float acc[4][4] = {};
    for (int k0 = 0; k0 < cHID; k0 += 16) {
        float4 a4 = *reinterpret_cast<const float4*>(Xm + (size_t)(r0 + am) * cHID + k0 + ak);
        As[ak + 0][am] = a4.x; As[ak + 1][am] = a4.y; As[ak + 2][am] = a4.z; As[ak + 3][am] = a4.w;
        float4 b4 = *reinterpret_cast<const float4*>(W + (size_t)(k0 + bkk) * cD + c0 + bn);
        *reinterpret_cast<float4*>(&Bs[bkk][bn]) = b4;
        __syncthreads();
#pragma unroll
        for (int kk = 0; kk < 16; ++kk) {
            float4 av  = *reinterpret_cast<const float4*>(&As[kk][ty * 4]);
            float4 bv4 = *reinterpret_cast<const float4*>(&Bs[kk][tx * 4]);
            float a_[4] = {av.x, av.y, av.z, av.w};
            float b_[4] = {bv4.x, bv4.y, bv4.z, bv4.w};
#pragma unroll
            for (int i = 0; i < 4; ++i)
#pragma unroll
                for (int j = 0; j < 4; ++j) acc[i][j] += a_[i] * b_[j];
        }
        __syncthreads();
    }
#pragma unroll
    for (int i = 0; i < 4; ++i) {
        int r = r0 + ty * 4 + i;          // b*128 + l
        int b = r >> 7, l = r & 127;
        float mb = mbar[r];
#pragma unroll
        for (int j = 0; j < 4; ++j) {
            int c = c0 + tx * 4 + j;
            int h = c >> 6, d = c & 63;
            Yl[((size_t)(b * cNH + h) * cNL + l) * cHD + d] = (acc[i][j] + mb * bias[c]) * cSCALE;
        }
    }
}

// ---------------------------------------------------------------------------
// k2 softmax chain (fp32-clean path)
// ---------------------------------------------------------------------------
__global__ __launch_bounds__(128) void k2_softmax(
    const float* __restrict__ Ql, const float* __restrict__ Kl, float* __restrict__ k2)
{
    __shared__ __align__(16) float qrow[64];
    __shared__ float red[128];
    int bh = blockIdx.x >> 7, i = blockIdx.x & 127;
    int j = threadIdx.x;
    if (j < 64) qrow[j] = Ql[(bh * cNL + i) * cHD + j];
    __syncthreads();
    const float4* q4  = reinterpret_cast<const float4*>(qrow);
    const float4* kl4 = reinterpret_cast<const float4*>(Kl + (bh * cNL + j) * cHD);
    float dot = 0.f;
#pragma unroll
    for (int u = 0; u < 16; ++u) {
        float4 a = q4[u], b = kl4[u];
        dot += a.x * b.x + a.y * b.y + a.z * b.z + a.w * b.w;
    }
    red[j] = dot; __syncthreads();
    for (int off = 64; off > 0; off >>= 1) { if (j < off) red[j] = fmaxf(red[j], red[j + off]); __syncthreads(); }
    float m = red[0]; __syncthreads();
    float e = expf(dot - m);
    red[j] = e; __syncthreads();
    for (int off = 64; off > 0; off >>= 1) { if (j < off) red[j] += red[j + off]; __syncthreads(); }
    k2[(bh * cNL + i) * cNL + j] = e / red[0];
}

__global__ __launch_bounds__(128) void colsum_max(const float* __restrict__ k2, int* __restrict__ cmax)
{
    __shared__ float red[128];
    int bh = blockIdx.x, j = threadIdx.x;
    float s = 0.f;
    for (int i = 0; i < cNL; ++i) s += k2[(bh * cNL + i) * cNL + j];
    red[j] = s; __syncthreads();
    for (int off = 64; off > 0; off >>= 1) { if (j < off) red[j] = fmaxf(red[j], red[j + off]); __syncthreads(); }
    if (j == 0) atomicMax(cmax, __float_as_int(red[0]));
}

__global__ __launch_bounds__(128) void v0_kernel(
    const float* __restrict__ k2, const int* __restrict__ cmax, float* __restrict__ V0)
{
    int bh = blockIdx.x >> 7, i = blockIdx.x & 127, j = threadIdx.x;
    float c = __int_as_float(*cmax);
    V0[(bh * cNL + i) * cNL + j] = k2[(bh * cNL + j) * cNL + i] / c;
}

// ---------------------------------------------------------------------------
// Batched 128x128: C = ds * (cs*A - A@B)
// ---------------------------------------------------------------------------
__global__ __launch_bounds__(256) void nys_matmul(
    const float* __restrict__ A, const float* __restrict__ Bm, float* __restrict__ C,
    float cs, float ds)
{
    __shared__ __align__(16) float As[16][68];
    __shared__ __align__(16) float Bs[16][68];
    const int tid = threadIdx.x;
    const int c0 = blockIdx.x * 64, r0 = blockIdx.y * 64;
    const int base = blockIdx.z * cNL * cNL;
    const int tx = tid & 15, ty = tid >> 4;
    const int am = tid >> 2, ak = (tid & 3) * 4;
    const int bkk = tid >> 4, bn = (tid & 15) * 4;

    float acc[4][4] = {};
    for (int k0 = 0; k0 < cNL; k0 += 16) {
        float4 a4 = *reinterpret_cast<const float4*>(A + base + (r0 + am) * cNL + k0 + ak);
        As[ak + 0][am] = a4.x; As[ak + 1][am] = a4.y; As[ak + 2][am] = a4.z; As[ak + 3][am] = a4.w;
        float4 b4 = *reinterpret_cast<const float4*>(Bm + base + (k0 + bkk) * cNL + c0 + bn);
        *reinterpret_cast<float4*>(&Bs[bkk][bn]) = b4;
        __syncthreads();
#pragma unroll
        for (int kk = 0; kk < 16; ++kk) {
            float4 av  = *reinterpret_cast<const float4*>(&As[kk][ty * 4]);
            float4 bv4 = *reinterpret_cast<const float4*>(&Bs[kk][tx * 4]);
            float a_[4] = {av.x, av.y, av.z, av.w};
            float b_[4] = {bv4.x, bv4.y, bv4.z, bv4.w};
#pragma unroll
            for (int i = 0; i < 4; ++i)
#pragma unroll
                for (int j = 0; j < 4; ++j) acc[i][j] += a_[i] * b_[j];
        }
        __syncthreads();
    }
#pragma unroll
    for (int i = 0; i < 4; ++i) {
        int r = r0 + ty * 4 + i;
#pragma unroll
        for (int j = 0; j < 4; ++j) {
            int c = c0 + tx * 4 + j;
            float av = A[base + r * cNL + c];
            C[base + r * cNL + c] = ds * (cs * av - acc[i][j]);
        }
    }
}

// ---------------------------------------------------------------------------
// ktrans: K[bh][s][d] fp32 -> KT[bh][d][s] fp16. LDS 65-pad scalar transpose
// (all LDS ops 2-way conflicts = free). grid (64 s-tiles, 32 bh).
// ---------------------------------------------------------------------------
__global__ __launch_bounds__(256) void ktrans(const float* __restrict__ K, _Float16* __restrict__ KT)
{
    __shared__ float T[64 * 65];
    const int s0 = blockIdx.x * 64, bh = blockIdx.y;
    const int t = threadIdx.x;
    const float* kb = K + (size_t)bh * cS * cHD;
#pragma unroll
    for (int j = 0; j < 4; ++j) {
        int idx4 = t + j * 256;
        int row = idx4 >> 4, c4 = idx4 & 15;
        float4 v = *reinterpret_cast<const float4*>(kb + (size_t)(s0 + row) * cHD + c4 * 4);
        T[(c4 * 4 + 0) * 65 + row] = v.x; T[(c4 * 4 + 1) * 65 + row] = v.y;
        T[(c4 * 4 + 2) * 65 + row] = v.z; T[(c4 * 4 + 3) * 65 + row] = v.w;
    }
    __syncthreads();
    _Float16* kt = KT + (size_t)bh * cHD * cS;
#pragma unroll
    for (int j = 0; j < 4; ++j) {
        int idx4 = t + j * 256;
        int d = idx4 >> 4, s4 = idx4 & 15;
        union { _Float16 h[4]; ushort4 u; } p;
        p.h[0] = (_Float16)T[d * 65 + s4 * 4 + 0];
        p.h[1] = (_Float16)T[d * 65 + s4 * 4 + 1];
        p.h[2] = (_Float16)T[d * 65 + s4 * 4 + 2];
        p.h[3] = (_Float16)T[d * 65 + s4 * 4 + 3];
        *reinterpret_cast<ushort4*>(kt + (size_t)d * cS + s0 + s4 * 4) = p.u;
    }
}

// ---------------------------------------------------------------------------
// k3v split-S flash: grid (lgroup 8, bh 32, chunk 8), 256 thr.
// Each block: 16 l-rows x 512 s (8 tiles of 64). Partials (O unnorm, m, s).
// KT fp16 [bh][d][s] staged -> fp32 Kt LDS (cvt at stage; conflict-free b128 in loop).
// ---------------------------------------------------------------------------
__global__ __launch_bounds__(256) void k3v_split(
    const float* __restrict__ Ql, const _Float16* __restrict__ KT, const float* __restrict__ V,
    const float* __restrict__ mask,
    float* __restrict__ Opart, float* __restrict__ mpart, float* __restrict__ spart)
{
    __shared__ __align__(16) float Kt[64][68];   // [d][s]
    __shared__ __align__(16) float Vs[64][68];   // [s][d]
    __shared__ __align__(16) float Ps[16][68];
    __shared__ __align__(16) float msk[64];
    const int l0 = blockIdx.x * 16, bh = blockIdx.y, z = blockIdx.z;
    const int s_base = z * 512;
    const int b = bh >> 4;
    const int t = threadIdx.x;
    const int lg = t >> 4, sq = t & 15;

    float qreg[64];
    {
        const float4* qp = reinterpret_cast<const float4*>(Ql + (size_t)(bh * cNL + l0 + lg) * cHD);
#pragma unroll
        for (int u4 = 0; u4 < 16; ++u4) {
            float4 q = qp[u4];
            qreg[u4 * 4 + 0] = q.x; qreg[u4 * 4 + 1] = q.y; qreg[u4 * 4 + 2] = q.z; qreg[u4 * 4 + 3] = q.w;
        }
    }

    float O0 = 0.f, O1 = 0.f, O2 = 0.f, O3 = 0.f;
    float mrun = -1e30f, srun = 0.f;

    const _Float16* ktg = KT + (size_t)bh * cHD * cS;
    const float* vbase = V + (size_t)bh * cS * cHD;

    // prefetch tile 0
    f16x8 kh[2]; float4 vx[4]; float mv = 0.f;
#pragma unroll
    for (int j = 0; j < 2; ++j) {
        int idx8 = t + j * 256;                  // 0..511 : 64d x 8 groups of 8s
        int d = idx8 >> 3, s8 = idx8 & 7;
        kh[j] = *reinterpret_cast<const f16x8*>(ktg + (size_t)d * cS + s_base + s8 * 8);
    }
#pragma unroll
    for (int j = 0; j < 4; ++j) {
        int idx4 = t + j * 256;
        int row = idx4 >> 4, c4 = idx4 & 15;
        vx[j] = *reinterpret_cast<const float4*>(vbase + (size_t)(s_base + row) * cHD + c4 * 4);
    }
    if (t < 64) mv = mask[b * cS + s_base + t];

    for (int tile = 0; tile < 8; ++tile) {
        __syncthreads();
#pragma unroll
        for (int j = 0; j < 2; ++j) {
            int idx8 = t + j * 256;
            int d = idx8 >> 3, s8 = idx8 & 7;
            float4 lo = make_float4((float)kh[j][0], (float)kh[j][1], (float)kh[j][2], (float)kh[j][3]);
            float4 hi = make_float4((float)kh[j][4], (float)kh[j][5], (float)kh[j][6], (float)kh[j][7]);
            *reinterpret_cast<float4*>(&Kt[d][s8 * 8])     = lo;
            *reinterpret_cast<float4*>(&Kt[d][s8 * 8 + 4]) = hi;
        }
#pragma unroll
        for (int j = 0; j < 4; ++j) {
            int idx4 = t + j * 256;
            int row = idx4 >> 4, c4 = idx4 & 15;
            *reinterpret_cast<float4*>(&Vs[row][c4 * 4]) = vx[j];
        }
        if (t < 64) msk[t] = mv;
        if (tile < 7) {
            int s1 = s_base + (tile + 1) * 64;
#pragma unroll
            for (int j = 0; j < 2; ++j) {
                int idx8 = t + j * 256;
                int d = idx8 >> 3, s8 = idx8 & 7;
                kh[j] = *reinterpret_cast<const f16x8*>(ktg + (size_t)d * cS + s1 + s8 * 8);
            }
#pragma unroll
            for (int j = 0; j < 4; ++j) {
                int idx4 = t + j * 256;
                int row = idx4 >> 4, c4 = idx4 & 15;
                vx[j] = *reinterpret_cast<const float4*>(vbase + (size_t)(s1 + row) * cHD + c4 * 4);
            }
            if (t < 64) mv = mask[b * cS + s1 + t];
        }
        __syncthreads();
        float a0 = 0.f, a1 = 0.f, a2 = 0.f, a3 = 0.f;
#pragma unroll
        for (int u = 0; u < 64; ++u) {
            float4 k4 = *reinterpret_cast<const float4*>(&Kt[u][sq * 4]);
            float q = qreg[u];
            a0 += q * k4.x; a1 += q * k4.y; a2 += q * k4.z; a3 += q * k4.w;
        }
        float4 m4 = *reinterpret_cast<const float4*>(&msk[sq * 4]);
        a0 -= 1e9f * (1.0f - m4.x); a1 -= 1e9f * (1.0f - m4.y);
        a2 -= 1e9f * (1.0f - m4.z); a3 -= 1e9f * (1.0f - m4.w);
        float tmax = fmaxf(fmaxf(a0, a1), fmaxf(a2, a3));
#pragma unroll
        for (int w = 1; w < 16; w <<= 1) tmax = fmaxf(tmax, __shfl_xor(tmax, w, 16));
        float mnew = fmaxf(mrun, tmax);
        float alpha = __expf(mrun - mnew);
        float e0 = __expf(a0 - mnew), e1 = __expf(a1 - mnew);
        float e2 = __expf(a2 - mnew), e3 = __expf(a3 - mnew);
        float ts = e0 + e1 + e2 + e3;
#pragma unroll
        for (int w = 1; w < 16; w <<= 1) ts += __shfl_xor(ts, w, 16);
        srun = srun * alpha + ts;
        mrun = mnew;
        O0 *= alpha; O1 *= alpha; O2 *= alpha; O3 *= alpha;
        *reinterpret_cast<float4*>(&Ps[lg][sq * 4]) = make_float4(e0, e1, e2, e3);
        __syncthreads();
#pragma unroll
        for (int s = 0; s < 64; ++s) {
            float p = Ps[lg][s];
            float4 v4 = *reinterpret_cast<const float4*>(&Vs[s][sq * 4]);
            O0 += p * v4.x; O1 += p * v4.y; O2 += p * v4.z; O3 += p * v4.w;
        }
    }
    const int prow = (z * cBH + bh) * cNL + l0 + lg;
    *reinterpret_cast<float4*>(Opart + (size_t)prow * cHD + sq * 4) = make_float4(O0, O1, O2, O3);
    if (sq == 0) { mpart[prow] = mrun; spart[prow] = srun; }
}

// ---------------------------------------------------------------------------
// combine 8 chunk-partials: CV[row][d] = sum_z e^{m_z-m*} O_z / sum_z e^{m_z-m*} s_z
// ---------------------------------------------------------------------------
__global__ __launch_bounds__(256) void k3v_reduce(
    const float* __restrict__ Opart, const float* __restrict__ mpart,
    const float* __restrict__ spart, float* __restrict__ CV)
{
    const int t = threadIdx.x;
    const int row = blockIdx.x * 4 + (t >> 6);   // 0..4095 = bh*128 + l
    const int d = t & 63;
    float mstar = -1e30f;
#pragma unroll
    for (int z = 0; z < 8; ++z) mstar = fmaxf(mstar, mpart[z * 4096 + row]);
    float ssum = 0.f, acc = 0.f;
#pragma unroll
    for (int z = 0; z < 8; ++z) {
        float w = __expf(mpart[z * 4096 + row] - mstar);
        ssum += w * spart[z * 4096 + row];
        acc  += w * Opart[(size_t)(z * 4096 + row) * cHD + d];
    }
    CV[(size_t)row * cHD + d] = acc / ssum;
}

// W2[bh] = V6[bh] @ CV[bh]
__global__ __launch_bounds__(256) void w2_matmul(
    const float* __restrict__ V6, const float* __restrict__ CV, float* __restrict__ W2)
{
    __shared__ __align__(16) float CVs[128][64];
    const int bh = blockIdx.x, t = threadIdx.x;
    for (int k = 0; k < 32; ++k) { int idx = t + k * 256; CVs[idx >> 6][idx & 63] = CV[bh * 8192 + idx]; }
    __syncthreads();
    const int tx = t & 15, ty = t >> 4;
    float acc[8][4] = {};
    for (int k = 0; k < 128; ++k) {
        float4 b4 = *reinterpret_cast<const float4*>(&CVs[k][tx * 4]);
#pragma unroll
        for (int i = 0; i < 8; ++i) {
            float a = V6[(bh * cNL + ty * 8 + i) * cNL + k];
            acc[i][0] += a * b4.x; acc[i][1] += a * b4.y; acc[i][2] += a * b4.z; acc[i][3] += a * b4.w;
        }
    }
#pragma unroll
    for (int i = 0; i < 8; ++i)
#pragma unroll
        for (int j = 0; j < 4; ++j)
            W2[(bh * cNL + ty * 8 + i) * cHD + tx * 4 + j] = acc[i][j];
}

// ---------------------------------------------------------------------------
// k1_fused — writes fp16 ctx for the MFMA output GEMM
// ---------------------------------------------------------------------------
__global__ __launch_bounds__(256) void k1_fused(
    const float* __restrict__ Q, const float* __restrict__ Kl, const float* __restrict__ W2,
    _Float16* __restrict__ ctxh)
{
    __shared__ __align__(16) float buf[128 * 68];
    __shared__ float pbuf[16 * 128];
    __shared__ __align__(16) float qbuf[16 * 64];
    __shared__ float rowred[16 * 16];
    __shared__ float rowmax[16];
    __shared__ float rowsum[16];
    const int bh = blockIdx.y, s0 = blockIdx.x * 16;
    const int b = bh >> 4, h = bh & 15;
    const int t = threadIdx.x;
    for (int k = 0; k < 32; ++k) { int idx = t + k * 256; buf[(idx >> 6) * 68 + (idx & 63)] = Kl[bh * 8192 + idx]; }
    for (int k = 0; k < 4; ++k)  { int idx = t + k * 256; qbuf[idx] = Q[(size_t)(bh * cS + s0 + (idx >> 6)) * cHD + (idx & 63)]; }
    __syncthreads();
    const int i = t >> 4, lo = t & 15;
    const float4* qv = reinterpret_cast<const float4*>(&qbuf[i * 64]);
    float tmax = -1e30f;
    float dots[8];
#pragma unroll
    for (int k = 0; k < 8; ++k) {
        int l = lo + k * 16;
        const float4* kl4 = reinterpret_cast<const float4*>(&buf[l * 68]);
        float dot = 0.f;
#pragma unroll
        for (int u = 0; u < 16; ++u) {
            float4 a = qv[u], b4 = kl4[u];
            dot += a.x * b4.x + a.y * b4.y + a.z * b4.z + a.w * b4.w;
        }
        dots[k] = dot; tmax = fmaxf(tmax, dot);
    }
    rowred[i * 16 + lo] = tmax; __syncthreads();
    if (t < 16) { float m = rowred[t * 16]; for (int u = 1; u < 16; ++u) m = fmaxf(m, rowred[t * 16 + u]); rowmax[t] = m; }
    __syncthreads();
    float m = rowmax[i];
    float psum = 0.f;
#pragma unroll
    for (int k = 0; k < 8; ++k) {
        int l = lo + k * 16;
        float e = expf(dots[k] - m);
        pbuf[i * 128 + l] = e; psum += e;
    }
    rowred[i * 16 + lo] = psum; __syncthreads();
    if (t < 16) { float s_ = 0.f; for (int u = 0; u < 16; ++u) s_ += rowred[t * 16 + u]; rowsum[t] = s_; }
    __syncthreads();
    for (int k = 0; k < 32; ++k) { int idx = t + k * 256; buf[(idx >> 6) * 68 + (idx & 63)] = W2[bh * 8192 + idx]; }
    __syncthreads();
    const int d = t & 63, ig = t >> 6;
    float acc[4] = {};
    for (int l = 0; l < 128; ++l) {
        float w = buf[l * 68 + d];
#pragma unroll
        for (int k = 0; k < 4; ++k) acc[k] += pbuf[(ig * 4 + k) * 128 + l] * w;
    }
#pragma unroll
    for (int k = 0; k < 4; ++k) {
        int i2 = ig * 4 + k;
        ctxh[(size_t)(b * cS + s0 + i2) * cD + h * cHD + d] = (_Float16)(acc[k] / rowsum[i2]);
    }
}

// ---------------------------------------------------------------------------
extern "C" void kernel_launch(void* const* d_in, const int* in_sizes, int n_in,
                              void* d_out, int out_size, void* d_ws, size_t ws_size,
                              hipStream_t stream)
{
    const float* X    = (const float*)d_in[0];
    const float* mask = (const float*)d_in[1];
    const float* Wq   = (const float*)d_in[2];
    const float* bq   = (const float*)d_in[3];
    const float* Wk   = (const float*)d_in[4];
    const float* bk   = (const float*)d_in[5];
    const float* Wv   = (const float*)d_in[6];
    const float* bv   = (const float*)d_in[7];
    const float* Wo   = (const float*)d_in[8];
    const float* bo   = (const float*)d_in[9];
    float* out = (float*)d_out;

    float* ws = (float*)d_ws;
    size_t off = 0;
    const size_t szQKV = (size_t)cBH * cS * cHD;      // 8388608 floats
    const size_t szL   = (size_t)cBH * cNL * cHD;     // 262144
    const size_t szM   = (size_t)cBH * cNL * cNL;     // 524288
    float* Q    = ws + off; off += szQKV;
    float* K    = ws + off; off += szQKV;
    float* V    = ws + off; off += szQKV;
    _Float16* Xh  = (_Float16*)(ws + off); off += szQKV / 2;      // 16 MB
    _Float16* WqT = (_Float16*)(ws + off); off += 524288;
    _Float16* WkT = (_Float16*)(ws + off); off += 524288;
    _Float16* WvT = (_Float16*)(ws + off); off += 524288;
    _Float16* WoT = (_Float16*)(ws + off); off += 524288;
    float* Xm   = ws + off; off += (size_t)cB * cNL * cHID;
    float* mbar = ws + off; off += 256;
    float* Ql  = ws + off; off += szL;
    float* Kl  = ws + off; off += szL;
    float* k2  = ws + off; off += szM;
    float* Vb0 = ws + off; off += szM;
    float* Vb1 = ws + off; off += szM;       // Vb1..T3b (8 MB) double as Opart after nys loop
    float* Zb  = ws + off; off += szM;
    float* T2b = ws + off; off += szM;
    float* T3b = ws + off; off += szM;
    float* CV  = ws + off; off += szL;
    float* W2  = ws + off; off += szL;
    int*   cmax = (int*)(ws + off); off += 16;
    float* mpart = ws + off; off += 4096;    // 8 chunks x 4096 rows? -> 8*4096 = 32768
    off += 28672;                            // (mpart occupies 32768 total)
    float* spart = ws + off; off += 32768;
    _Float16* KT = (_Float16*)Xh;            // Xh dead after qkv_gemm_f16
    float* Opart = Vb1;                      // Vb1..T3b = 4 x 524288 = 2097152 floats = 8 chunks*4096*64
    _Float16* ctxh = (_Float16*)K;           // K dead after ktrans+k3v_split

    hipMemsetAsync(cmax, 0, sizeof(int), stream);

    cast_x<<<(int)(szQKV / 1024), 256, 0, stream>>>(X, Xh);
    wcast_t<<<dim3(32, 32, 4), 256, 0, stream>>>(Wq, Wk, Wv, Wo, WqT, WkT, WvT, WoT);
    xm_kernel<<<cB * cNL, 256, 0, stream>>>(X, mask, Xm, mbar);

    qkv_gemm_f16<<<dim3(cD / 128, (cB * cS) / 128, 3), 256, 0, stream>>>(
        Xh, mask, WqT, WkT, WvT, bq, bk, bv, Q, K, V);
    ktrans<<<dim3(cS / 64, cBH), 256, 0, stream>>>(K, KT);   // overwrites Xh region
    lgemm<<<dim3(cD / 64, (cB * cNL) / 64, 2), 256, 0, stream>>>(Xm, mbar, Wq, bq, Wk, bk, Ql, Kl);

    k2_softmax<<<cBH * cNL, 128, 0, stream>>>(Ql, Kl, k2);
    colsum_max<<<cBH, 128, 0, stream>>>(k2, cmax);
    v0_kernel<<<cBH * cNL, 128, 0, stream>>>(k2, cmax, Vb0);

    float* Vc = Vb0; float* Vn = Vb1;
    for (int it = 0; it < 6; ++it) {
        nys_matmul<<<dim3(2, 2, cBH), 256, 0, stream>>>(k2, Vc, Zb, 0.f, -1.f);
        nys_matmul<<<dim3(2, 2, cBH), 256, 0, stream>>>(Zb, Zb, T2b, 7.f, 1.f);
        nys_matmul<<<dim3(2, 2, cBH), 256, 0, stream>>>(Zb, T2b, T3b, 15.f, 1.f);
        nys_matmul<<<dim3(2, 2, cBH), 256, 0, stream>>>(Vc, T3b, Vn, 13.f, 0.25f);
        float* tmp = Vc; Vc = Vn; Vn = tmp;
    }
    // after 6 iters Vc == Vb0; Vb1/Zb/T2b/T3b are dead -> Opart reuses them

    k3v_split<<<dim3(cNL / 16, cBH, 8), 256, 0, stream>>>(Ql, KT, V, mask, Opart, mpart, spart);
    k3v_reduce<<<1024, 256, 0, stream>>>(Opart, mpart, spart, CV);
    w2_matmul<<<cBH, 256, 0, stream>>>(Vc, CV, W2);
    k1_fused<<<dim3(cS / 16, cBH), 256, 0, stream>>>(Q, Kl, W2, ctxh);
    out_gemm_f16<<<dim3(cHID / 128, (cB * cS) / 128), 256, 0, stream>>>(ctxh, WoT, bo, out);
}

// Round 5
// 727.778 us; speedup vs baseline: 3.9146x; 1.1702x over previous
//
#include <hip/hip_runtime.h>
#include <math.h>

// Problem constants
constexpr int cB = 2, cS = 4096, cHID = 1024, cNH = 16, cHD = 64, cNL = 128, cSEG = 32, cD = 1024, cBH = 32;
constexpr float cSCALE = 0.35355339059327373f;   // 1/sqrt(sqrt(64))

typedef _Float16 f16x8 __attribute__((ext_vector_type(8)));
typedef float f32x4 __attribute__((ext_vector_type(4)));

__device__ inline void gload_lds16(const void* g, void* l) {
    __builtin_amdgcn_global_load_lds(
        (const __attribute__((address_space(1))) void*)g,
        (__attribute__((address_space(3))) void*)l, 16, 0, 0);
}

// ---------------------------------------------------------------------------
// cast X fp32 -> fp16
// ---------------------------------------------------------------------------
__global__ __launch_bounds__(256) void cast_x(const float* __restrict__ X, _Float16* __restrict__ Xh)
{
    int i = (blockIdx.x * 256 + threadIdx.x) * 4;
    float4 v = *reinterpret_cast<const float4*>(X + i);
    union { _Float16 h[4]; ushort4 u; } p;
    p.h[0] = (_Float16)v.x; p.h[1] = (_Float16)v.y; p.h[2] = (_Float16)v.z; p.h[3] = (_Float16)v.w;
    *reinterpret_cast<ushort4*>(Xh + i) = p.u;
}

// ---------------------------------------------------------------------------
// transpose+cast W (K x N fp32) -> WT (N x K fp16)
// ---------------------------------------------------------------------------
__global__ __launch_bounds__(256) void wcast_t(
    const float* __restrict__ Wq, const float* __restrict__ Wk,
    const float* __restrict__ Wv, const float* __restrict__ Wo,
    _Float16* __restrict__ WqT, _Float16* __restrict__ WkT,
    _Float16* __restrict__ WvT, _Float16* __restrict__ WoT)
{
    __shared__ float tile[32][33];
    const int wsel = blockIdx.z;
    const float* W = (wsel == 0) ? Wq : (wsel == 1 ? Wk : (wsel == 2 ? Wv : Wo));
    _Float16* WT   = (wsel == 0) ? WqT : (wsel == 1 ? WkT : (wsel == 2 ? WvT : WoT));
    const int n0 = blockIdx.x * 32, k0 = blockIdx.y * 32;
    const int t = threadIdx.x;
    const int r = t >> 3, c = (t & 7) * 4;
    float4 v = *reinterpret_cast<const float4*>(W + (size_t)(k0 + r) * cD + n0 + c);
    tile[r][c] = v.x; tile[r][c + 1] = v.y; tile[r][c + 2] = v.z; tile[r][c + 3] = v.w;
    __syncthreads();
    union { _Float16 h[4]; ushort4 u; } p;
    p.h[0] = (_Float16)tile[c + 0][r]; p.h[1] = (_Float16)tile[c + 1][r];
    p.h[2] = (_Float16)tile[c + 2][r]; p.h[3] = (_Float16)tile[c + 3][r];
    *reinterpret_cast<ushort4*>(WT + (size_t)(n0 + r) * cHID + k0 + c) = p.u;
}

// ---------------------------------------------------------------------------
// Xm[b*128+l][:] = (1/32) sum_j mask*X ; mbar = mean mask  (fp32 landmark input)
// ---------------------------------------------------------------------------
__global__ __launch_bounds__(256) void xm_kernel(
    const float* __restrict__ X, const float* __restrict__ mask,
    float* __restrict__ Xm, float* __restrict__ mbar)
{
    const int bl = blockIdx.x;          // b*128 + l
    const int b = bl >> 7, l = bl & 127;
    const int c = threadIdx.x * 4;
    float4 a = {0.f, 0.f, 0.f, 0.f};
    float msum = 0.f;
    for (int j = 0; j < cSEG; ++j) {
        float m = mask[b * cS + l * cSEG + j];
        float4 x = *reinterpret_cast<const float4*>(X + ((size_t)(b * cS + l * cSEG + j)) * cHID + c);
        a.x += m * x.x; a.y += m * x.y; a.z += m * x.z; a.w += m * x.w;
        msum += m;
    }
    const float inv = 1.0f / cSEG;
    a.x *= inv; a.y *= inv; a.z *= inv; a.w *= inv;
    *reinterpret_cast<float4*>(Xm + (size_t)bl * cHID + c) = a;
    if (threadIdx.x == 0) mbar[bl] = msum * inv;
}

// ---------------------------------------------------------------------------
// f16 MFMA GEMM: QKV.  Q written as f16 (only consumer k1_mfma); K,V fp32.
// ---------------------------------------------------------------------------
__global__ __launch_bounds__(256) void qkv_gemm_f16(
    const _Float16* __restrict__ Xh, const float* __restrict__ mask,
    const _Float16* __restrict__ WqT, const _Float16* __restrict__ WkT, const _Float16* __restrict__ WvT,
    const float* __restrict__ bq, const float* __restrict__ bk, const float* __restrict__ bv,
    _Float16* __restrict__ Qh, float* __restrict__ Ko, float* __restrict__ Vo)
{
    __shared__ __align__(16) _Float16 As[128 * 32];
    __shared__ __align__(16) _Float16 Bs[128 * 32];
    const int wsel = blockIdx.z;
    const _Float16* WT = (wsel == 0) ? WqT : (wsel == 1 ? WkT : WvT);
    const float* bias  = (wsel == 0) ? bq  : (wsel == 1 ? bk  : bv);
    const int n0 = blockIdx.x * 128, m0 = blockIdx.y * 128;
    const int t = threadIdx.x;
    const int wave = t >> 6, lane = t & 63;
    const int wm = (wave >> 1) * 64, wn = (wave & 1) * 64;
    const int quad = lane >> 4, l15 = lane & 15;
    const int srow = wave * 32 + (lane >> 2);
    const int scol = (lane & 3) * 8;

    f32x4 acc[4][4];
#pragma unroll
    for (int i = 0; i < 4; ++i)
#pragma unroll
        for (int j = 0; j < 4; ++j) acc[i][j] = (f32x4){0.f, 0.f, 0.f, 0.f};

    for (int k0 = 0; k0 < cHID; k0 += 32) {
        const _Float16* aSrc = Xh + (size_t)(m0 + srow) * cHID + k0 + scol;
        const _Float16* bSrc = WT + (size_t)(n0 + srow) * cHID + k0 + scol;
        gload_lds16(aSrc,              &As[(wave * 32) * 32]);
        gload_lds16(aSrc + 16 * cHID,  &As[(wave * 32 + 16) * 32]);
        gload_lds16(bSrc,              &Bs[(wave * 32) * 32]);
        gload_lds16(bSrc + 16 * cHID,  &Bs[(wave * 32 + 16) * 32]);
        __syncthreads();
        f16x8 af[4], bf[4];
#pragma unroll
        for (int mt = 0; mt < 4; ++mt)
            af[mt] = *reinterpret_cast<const f16x8*>(&As[(wm + mt * 16 + l15) * 32 + quad * 8]);
#pragma unroll
        for (int nt = 0; nt < 4; ++nt)
            bf[nt] = *reinterpret_cast<const f16x8*>(&Bs[(wn + nt * 16 + l15) * 32 + quad * 8]);
#pragma unroll
        for (int mt = 0; mt < 4; ++mt)
#pragma unroll
            for (int nt = 0; nt < 4; ++nt)
                acc[mt][nt] = __builtin_amdgcn_mfma_f32_16x16x32_f16(af[mt], bf[nt], acc[mt][nt], 0, 0, 0);
        __syncthreads();
    }
#pragma unroll
    for (int mt = 0; mt < 4; ++mt) {
#pragma unroll
        for (int r = 0; r < 4; ++r) {
            int R = m0 + wm + mt * 16 + quad * 4 + r;
            int b = R >> 12, s = R & (cS - 1);
            float msc = (wsel < 2) ? mask[b * cS + s] * cSCALE : 1.0f;
#pragma unroll
            for (int nt = 0; nt < 4; ++nt) {
                int Cc = n0 + wn + nt * 16 + l15;
                int h = Cc >> 6, d = Cc & 63;
                float val = (acc[mt][nt][r] + bias[Cc]) * msc;
                size_t idx = ((size_t)(b * cNH + h) * cS + s) * cHD + d;
                if (wsel == 0) Qh[idx] = (_Float16)val;
                else if (wsel == 1) Ko[idx] = val;
                else Vo[idx] = val;
            }
        }
    }
}

// ---------------------------------------------------------------------------
// f16 MFMA GEMM: out = ctxh @ Wo + bo
// ---------------------------------------------------------------------------
__global__ __launch_bounds__(256) void out_gemm_f16(
    const _Float16* __restrict__ Ah, const _Float16* __restrict__ WT,
    const float* __restrict__ bias, float* __restrict__ Y)
{
    __shared__ __align__(16) _Float16 As[128 * 32];
    __shared__ __align__(16) _Float16 Bs[128 * 32];
    const int n0 = blockIdx.x * 128, m0 = blockIdx.y * 128;
    const int t = threadIdx.x;
    const int wave = t >> 6, lane = t & 63;
    const int wm = (wave >> 1) * 64, wn = (wave & 1) * 64;
    const int quad = lane >> 4, l15 = lane & 15;
    const int srow = wave * 32 + (lane >> 2);
    const int scol = (lane & 3) * 8;

    f32x4 acc[4][4];
#pragma unroll
    for (int i = 0; i < 4; ++i)
#pragma unroll
        for (int j = 0; j < 4; ++j) acc[i][j] = (f32x4){0.f, 0.f, 0.f, 0.f};

    for (int k0 = 0; k0 < cD; k0 += 32) {
        const _Float16* aSrc = Ah + (size_t)(m0 + srow) * cD + k0 + scol;
        const _Float16* bSrc = WT + (size_t)(n0 + srow) * cD + k0 + scol;
        gload_lds16(aSrc,             &As[(wave * 32) * 32]);
        gload_lds16(aSrc + 16 * cD,   &As[(wave * 32 + 16) * 32]);
        gload_lds16(bSrc,             &Bs[(wave * 32) * 32]);
        gload_lds16(bSrc + 16 * cD,   &Bs[(wave * 32 + 16) * 32]);
        __syncthreads();
        f16x8 af[4], bf[4];
#pragma unroll
        for (int mt = 0; mt < 4; ++mt)
            af[mt] = *reinterpret_cast<const f16x8*>(&As[(wm + mt * 16 + l15) * 32 + quad * 8]);
#pragma unroll
        for (int nt = 0; nt < 4; ++nt)
            bf[nt] = *reinterpret_cast<const f16x8*>(&Bs[(wn + nt * 16 + l15) * 32 + quad * 8]);
#pragma unroll
        for (int mt = 0; mt < 4; ++mt)
#pragma unroll
            for (int nt = 0; nt < 4; ++nt)
                acc[mt][nt] = __builtin_amdgcn_mfma_f32_16x16x32_f16(af[mt], bf[nt], acc[mt][nt], 0, 0, 0);
        __syncthreads();
    }
#pragma unroll
    for (int mt = 0; mt < 4; ++mt) {
#pragma unroll
        for (int r = 0; r < 4; ++r) {
            int R = m0 + wm + mt * 16 + quad * 4 + r;
#pragma unroll
            for (int nt = 0; nt < 4; ++nt) {
                int Cc = n0 + wn + nt * 16 + l15;
                Y[(size_t)R * cHID + Cc] = acc[mt][nt][r] + bias[Cc];
            }
        }
    }
}

// ---------------------------------------------------------------------------
// Landmark GEMM (fp32, exact path). Also emits f16 Klh for k1_mfma.
// ---------------------------------------------------------------------------
__global__ __launch_bounds__(256) void lgemm(
    const float* __restrict__ Xm, const float* __restrict__ mbar,
    const float* __restrict__ Wq, const float* __restrict__ bq,
    const float* __restrict__ Wk, const float* __restrict__ bk,
    float* __restrict__ Ql, float* __restrict__ Kl, _Float16* __restrict__ Klh)
{
    __shared__ __align__(16) float As[16][68];
    __shared__ __align__(16) float Bs[16][68];
    const int tid = threadIdx.x;
    const int wsel = blockIdx.z;
    const float* W    = wsel ? Wk : Wq;
    const float* bias = wsel ? bk : bq;
    float* Yl         = wsel ? Kl : Ql;
    const int c0 = blockIdx.x * 64, r0 = blockIdx.y * 64;
    const int tx = tid & 15, ty = tid >> 4;
    const int am = tid >> 2, ak = (tid & 3) * 4;
    const int bkk = tid >> 4, bn = (tid & 15) * 4;

    float acc[4][4] = {};
    for (int k0 = 0; k0 < cHID; k0 += 16) {
        float4 a4 = *reinterpret_cast<const float4*>(Xm + (size_t)(r0 + am) * cHID + k0 + ak);
        As[ak + 0][am] = a4.x; As[ak + 1][am] = a4.y; As[ak + 2][am] = a4.z; As[ak + 3][am] = a4.w;
        float4 b4 = *reinterpret_cast<const float4*>(W + (size_t)(k0 + bkk) * cD + c0 + bn);
        *reinterpret_cast<float4*>(&Bs[bkk][bn]) = b4;
        __syncthreads();
#pragma unroll
        for (int kk = 0; kk < 16; ++kk) {
            float4 av  = *reinterpret_cast<const float4*>(&As[kk][ty * 4]);
            float4 bv4 = *reinterpret_cast<const float4*>(&Bs[kk][tx * 4]);
            float a_[4] = {av.x, av.y, av.z, av.w};
            float b_[4] = {bv4.x, bv4.y, bv4.z, bv4.w};
#pragma unroll
            for (int i = 0; i < 4; ++i)
#pragma unroll
                for (int j = 0; j < 4; ++j) acc[i][j] += a_[i] * b_[j];
        }
        __syncthreads();
    }
#pragma unroll
    for (int i = 0; i < 4; ++i) {
        int r = r0 + ty * 4 + i;          // b*128 + l
        int b = r >> 7, l = r & 127;
        float mb = mbar[r];
#pragma unroll
        for (int j = 0; j < 4; ++j) {
            int c = c0 + tx * 4 + j;
            int h = c >> 6, d = c & 63;
            float val = (acc[i][j] + mb * bias[c]) * cSCALE;
            size_t idx = ((size_t)(b * cNH + h) * cNL + l) * cHD + d;
            Yl[idx] = val;
            if (wsel) Klh[idx] = (_Float16)val;
        }
    }
}

// ---------------------------------------------------------------------------
// k2 softmax chain (fp32-clean path)
// ---------------------------------------------------------------------------
__global__ __launch_bounds__(128) void k2_softmax(
    const float* __restrict__ Ql, const float* __restrict__ Kl, float* __restrict__ k2)
{
    __shared__ __align__(16) float qrow[64];
    __shared__ float red[128];
    int bh = blockIdx.x >> 7, i = blockIdx.x & 127;
    int j = threadIdx.x;
    if (j < 64) qrow[j] = Ql[(bh * cNL + i) * cHD + j];
    __syncthreads();
    const float4* q4  = reinterpret_cast<const float4*>(qrow);
    const float4* kl4 = reinterpret_cast<const float4*>(Kl + (bh * cNL + j) * cHD);
    float dot = 0.f;
#pragma unroll
    for (int u = 0; u < 16; ++u) {
        float4 a = q4[u], b = kl4[u];
        dot += a.x * b.x + a.y * b.y + a.z * b.z + a.w * b.w;
    }
    red[j] = dot; __syncthreads();
    for (int off = 64; off > 0; off >>= 1) { if (j < off) red[j] = fmaxf(red[j], red[j + off]); __syncthreads(); }
    float m = red[0]; __syncthreads();
    float e = expf(dot - m);
    red[j] = e; __syncthreads();
    for (int off = 64; off > 0; off >>= 1) { if (j < off) red[j] += red[j + off]; __syncthreads(); }
    k2[(bh * cNL + i) * cNL + j] = e / red[0];
}

__global__ __launch_bounds__(128) void colsum_max(const float* __restrict__ k2, int* __restrict__ cmax)
{
    __shared__ float red[128];
    int bh = blockIdx.x, j = threadIdx.x;
    float s = 0.f;
    for (int i = 0; i < cNL; ++i) s += k2[(bh * cNL + i) * cNL + j];
    red[j] = s; __syncthreads();
    for (int off = 64; off > 0; off >>= 1) { if (j < off) red[j] = fmaxf(red[j], red[j + off]); __syncthreads(); }
    if (j == 0) atomicMax(cmax, __float_as_int(red[0]));
}

__global__ __launch_bounds__(128) void v0_kernel(
    const float* __restrict__ k2, const int* __restrict__ cmax, float* __restrict__ V0)
{
    int bh = blockIdx.x >> 7, i = blockIdx.x & 127, j = threadIdx.x;
    float c = __int_as_float(*cmax);
    V0[(bh * cNL + i) * cNL + j] = k2[(bh * cNL + j) * cNL + i] / c;
}

// ---------------------------------------------------------------------------
// Batched 128x128: C = ds * (cs*A - A@B)
// ---------------------------------------------------------------------------
__global__ __launch_bounds__(256) void nys_matmul(
    const float* __restrict__ A, const float* __restrict__ Bm, float* __restrict__ C,
    float cs, float ds)
{
    __shared__ __align__(16) float As[16][68];
    __shared__ __align__(16) float Bs[16][68];
    const int tid = threadIdx.x;
    const int c0 = blockIdx.x * 64, r0 = blockIdx.y * 64;
    const int base = blockIdx.z * cNL * cNL;
    const int tx = tid & 15, ty = tid >> 4;
    const int am = tid >> 2, ak = (tid & 3) * 4;
    const int bkk = tid >> 4, bn = (tid & 15) * 4;

    float acc[4][4] = {};
    for (int k0 = 0; k0 < cNL; k0 += 16) {
        float4 a4 = *reinterpret_cast<const float4*>(A + base + (r0 + am) * cNL + k0 + ak);
        As[ak + 0][am] = a4.x; As[ak + 1][am] = a4.y; As[ak + 2][am] = a4.z; As[ak + 3][am] = a4.w;
        float4 b4 = *reinterpret_cast<const float4*>(Bm + base + (k0 + bkk) * cNL + c0 + bn);
        *reinterpret_cast<float4*>(&Bs[bkk][bn]) = b4;
        __syncthreads();
#pragma unroll
        for (int kk = 0; kk < 16; ++kk) {
            float4 av  = *reinterpret_cast<const float4*>(&As[kk][ty * 4]);
            float4 bv4 = *reinterpret_cast<const float4*>(&Bs[kk][tx * 4]);
            float a_[4] = {av.x, av.y, av.z, av.w};
            float b_[4] = {bv4.x, bv4.y, bv4.z, bv4.w};
#pragma unroll
            for (int i = 0; i < 4; ++i)
#pragma unroll
                for (int j = 0; j < 4; ++j) acc[i][j] += a_[i] * b_[j];
        }
        __syncthreads();
    }
#pragma unroll
    for (int i = 0; i < 4; ++i) {
        int r = r0 + ty * 4 + i;
#pragma unroll
        for (int j = 0; j < 4; ++j) {
            int c = c0 + tx * 4 + j;
            float av = A[base + r * cNL + c];
            C[base + r * cNL + c] = ds * (cs * av - acc[i][j]);
        }
    }
}

// ---------------------------------------------------------------------------
// ktrans: K[bh][s][d] fp32 -> KT[bh][d][s] fp16 (65-pad LDS transpose)
// ---------------------------------------------------------------------------
__global__ __launch_bounds__(256) void ktrans(const float* __restrict__ K, _Float16* __restrict__ KT)
{
    __shared__ float T[64 * 65];
    const int s0 = blockIdx.x * 64, bh = blockIdx.y;
    const int t = threadIdx.x;
    const float* kb = K + (size_t)bh * cS * cHD;
#pragma unroll
    for (int j = 0; j < 4; ++j) {
        int idx4 = t + j * 256;
        int row = idx4 >> 4, c4 = idx4 & 15;
        float4 v = *reinterpret_cast<const float4*>(kb + (size_t)(s0 + row) * cHD + c4 * 4);
        T[(c4 * 4 + 0) * 65 + row] = v.x; T[(c4 * 4 + 1) * 65 + row] = v.y;
        T[(c4 * 4 + 2) * 65 + row] = v.z; T[(c4 * 4 + 3) * 65 + row] = v.w;
    }
    __syncthreads();
    _Float16* kt = KT + (size_t)bh * cHD * cS;
#pragma unroll
    for (int j = 0; j < 4; ++j) {
        int idx4 = t + j * 256;
        int d = idx4 >> 4, s4 = idx4 & 15;
        union { _Float16 h[4]; ushort4 u; } p;
        p.h[0] = (_Float16)T[d * 65 + s4 * 4 + 0];
        p.h[1] = (_Float16)T[d * 65 + s4 * 4 + 1];
        p.h[2] = (_Float16)T[d * 65 + s4 * 4 + 2];
        p.h[3] = (_Float16)T[d * 65 + s4 * 4 + 3];
        *reinterpret_cast<ushort4*>(kt + (size_t)d * cS + s0 + s4 * 4) = p.u;
    }
}

// ---------------------------------------------------------------------------
// k3v split-S flash (unchanged from R4)
// ---------------------------------------------------------------------------
__global__ __launch_bounds__(256) void k3v_split(
    const float* __restrict__ Ql, const _Float16* __restrict__ KT, const float* __restrict__ V,
    const float* __restrict__ mask,
    float* __restrict__ Opart, float* __restrict__ mpart, float* __restrict__ spart)
{
    __shared__ __align__(16) float Kt[64][68];
    __shared__ __align__(16) float Vs[64][68];
    __shared__ __align__(16) float Ps[16][68];
    __shared__ __align__(16) float msk[64];
    const int l0 = blockIdx.x * 16, bh = blockIdx.y, z = blockIdx.z;
    const int s_base = z * 512;
    const int b = bh >> 4;
    const int t = threadIdx.x;
    const int lg = t >> 4, sq = t & 15;

    float qreg[64];
    {
        const float4* qp = reinterpret_cast<const float4*>(Ql + (size_t)(bh * cNL + l0 + lg) * cHD);
#pragma unroll
        for (int u4 = 0; u4 < 16; ++u4) {
            float4 q = qp[u4];
            qreg[u4 * 4 + 0] = q.x; qreg[u4 * 4 + 1] = q.y; qreg[u4 * 4 + 2] = q.z; qreg[u4 * 4 + 3] = q.w;
        }
    }

    float O0 = 0.f, O1 = 0.f, O2 = 0.f, O3 = 0.f;
    float mrun = -1e30f, srun = 0.f;

    const _Float16* ktg = KT + (size_t)bh * cHD * cS;
    const float* vbase = V + (size_t)bh * cS * cHD;

    f16x8 kh[2]; float4 vx[4]; float mv = 0.f;
#pragma unroll
    for (int j = 0; j < 2; ++j) {
        int idx8 = t + j * 256;
        int d = idx8 >> 3, s8 = idx8 & 7;
        kh[j] = *reinterpret_cast<const f16x8*>(ktg + (size_t)d * cS + s_base + s8 * 8);
    }
#pragma unroll
    for (int j = 0; j < 4; ++j) {
        int idx4 = t + j * 256;
        int row = idx4 >> 4, c4 = idx4 & 15;
        vx[j] = *reinterpret_cast<const float4*>(vbase + (size_t)(s_base + row) * cHD + c4 * 4);
    }
    if (t < 64) mv = mask[b * cS + s_base + t];

    for (int tile = 0; tile < 8; ++tile) {
        __syncthreads();
#pragma unroll
        for (int j = 0; j < 2; ++j) {
            int idx8 = t + j * 256;
            int d = idx8 >> 3, s8 = idx8 & 7;
            float4 lo = make_float4((float)kh[j][0], (float)kh[j][1], (float)kh[j][2], (float)kh[j][3]);
            float4 hi = make_float4((float)kh[j][4], (float)kh[j][5], (float)kh[j][6], (float)kh[j][7]);
            *reinterpret_cast<float4*>(&Kt[d][s8 * 8])     = lo;
            *reinterpret_cast<float4*>(&Kt[d][s8 * 8 + 4]) = hi;
        }
#pragma unroll
        for (int j = 0; j < 4; ++j) {
            int idx4 = t + j * 256;
            int row = idx4 >> 4, c4 = idx4 & 15;
            *reinterpret_cast<float4*>(&Vs[row][c4 * 4]) = vx[j];
        }
        if (t < 64) msk[t] = mv;
        if (tile < 7) {
            int s1 = s_base + (tile + 1) * 64;
#pragma unroll
            for (int j = 0; j < 2; ++j) {
                int idx8 = t + j * 256;
                int d = idx8 >> 3, s8 = idx8 & 7;
                kh[j] = *reinterpret_cast<const f16x8*>(ktg + (size_t)d * cS + s1 + s8 * 8);
            }
#pragma unroll
            for (int j = 0; j < 4; ++j) {
                int idx4 = t + j * 256;
                int row = idx4 >> 4, c4 = idx4 & 15;
                vx[j] = *reinterpret_cast<const float4*>(vbase + (size_t)(s1 + row) * cHD + c4 * 4);
            }
            if (t < 64) mv = mask[b * cS + s1 + t];
        }
        __syncthreads();
        float a0 = 0.f, a1 = 0.f, a2 = 0.f, a3 = 0.f;
#pragma unroll
        for (int u = 0; u < 64; ++u) {
            float4 k4 = *reinterpret_cast<const float4*>(&Kt[u][sq * 4]);
            float q = qreg[u];
            a0 += q * k4.x; a1 += q * k4.y; a2 += q * k4.z; a3 += q * k4.w;
        }
        float4 m4 = *reinterpret_cast<const float4*>(&msk[sq * 4]);
        a0 -= 1e9f * (1.0f - m4.x); a1 -= 1e9f * (1.0f - m4.y);
        a2 -= 1e9f * (1.0f - m4.z); a3 -= 1e9f * (1.0f - m4.w);
        float tmax = fmaxf(fmaxf(a0, a1), fmaxf(a2, a3));
#pragma unroll
        for (int w = 1; w < 16; w <<= 1) tmax = fmaxf(tmax, __shfl_xor(tmax, w, 16));
        float mnew = fmaxf(mrun, tmax);
        float alpha = __expf(mrun - mnew);
        float e0 = __expf(a0 - mnew), e1 = __expf(a1 - mnew);
        float e2 = __expf(a2 - mnew), e3 = __expf(a3 - mnew);
        float ts = e0 + e1 + e2 + e3;
#pragma unroll
        for (int w = 1; w < 16; w <<= 1) ts += __shfl_xor(ts, w, 16);
        srun = srun * alpha + ts;
        mrun = mnew;
        O0 *= alpha; O1 *= alpha; O2 *= alpha; O3 *= alpha;
        *reinterpret_cast<float4*>(&Ps[lg][sq * 4]) = make_float4(e0, e1, e2, e3);
        __syncthreads();
#pragma unroll
        for (int s = 0; s < 64; ++s) {
            float p = Ps[lg][s];
            float4 v4 = *reinterpret_cast<const float4*>(&Vs[s][sq * 4]);
            O0 += p * v4.x; O1 += p * v4.y; O2 += p * v4.z; O3 += p * v4.w;
        }
    }
    const int prow = (z * cBH + bh) * cNL + l0 + lg;
    *reinterpret_cast<float4*>(Opart + (size_t)prow * cHD + sq * 4) = make_float4(O0, O1, O2, O3);
    if (sq == 0) { mpart[prow] = mrun; spart[prow] = srun; }
}

// ---------------------------------------------------------------------------
// combine 8 chunk-partials
// ---------------------------------------------------------------------------
__global__ __launch_bounds__(256) void k3v_reduce(
    const float* __restrict__ Opart, const float* __restrict__ mpart,
    const float* __restrict__ spart, float* __restrict__ CV)
{
    const int t = threadIdx.x;
    const int row = blockIdx.x * 4 + (t >> 6);
    const int d = t & 63;
    float mstar = -1e30f;
#pragma unroll
    for (int z = 0; z < 8; ++z) mstar = fmaxf(mstar, mpart[z * 4096 + row]);
    float ssum = 0.f, acc = 0.f;
#pragma unroll
    for (int z = 0; z < 8; ++z) {
        float w = __expf(mpart[z * 4096 + row] - mstar);
        ssum += w * spart[z * 4096 + row];
        acc  += w * Opart[(size_t)(z * 4096 + row) * cHD + d];
    }
    CV[(size_t)row * cHD + d] = acc / ssum;
}

// W2T[bh][d][l] (f16) = (V6[bh] @ CV[bh])^T
__global__ __launch_bounds__(256) void w2_matmul(
    const float* __restrict__ V6, const float* __restrict__ CV, _Float16* __restrict__ W2T)
{
    __shared__ __align__(16) float CVs[128][64];
    const int bh = blockIdx.x, t = threadIdx.x;
    for (int k = 0; k < 32; ++k) { int idx = t + k * 256; CVs[idx >> 6][idx & 63] = CV[bh * 8192 + idx]; }
    __syncthreads();
    const int tx = t & 15, ty = t >> 4;
    float acc[8][4] = {};
    for (int k = 0; k < 128; ++k) {
        float4 b4 = *reinterpret_cast<const float4*>(&CVs[k][tx * 4]);
#pragma unroll
        for (int i = 0; i < 8; ++i) {
            float a = V6[(bh * cNL + ty * 8 + i) * cNL + k];
            acc[i][0] += a * b4.x; acc[i][1] += a * b4.y; acc[i][2] += a * b4.z; acc[i][3] += a * b4.w;
        }
    }
    _Float16* wt = W2T + (size_t)bh * cHD * cNL;
#pragma unroll
    for (int i = 0; i < 8; ++i)
#pragma unroll
        for (int j = 0; j < 4; ++j)
            wt[(size_t)(tx * 4 + j) * cNL + ty * 8 + i] = (_Float16)acc[i][j];
}

// ---------------------------------------------------------------------------
// k1_mfma: ctx[b][s][h*64+d] = softmax_l(Qh[bh][s].Klh[bh][l]) @ W2T[bh]
// grid (64 s-blocks, 32 bh), 4 waves; wave owns 16 s-rows.
// QK^T and PV on MFMA 16x16x32 f16; P round-trips LDS (C-layout -> A-layout).
// ---------------------------------------------------------------------------
__global__ __launch_bounds__(256) void k1_mfma(
    const _Float16* __restrict__ Qh, const _Float16* __restrict__ Klh,
    const _Float16* __restrict__ W2T, _Float16* __restrict__ ctxh)
{
    __shared__ __align__(16) _Float16 Qs[64 * 72];    // 64 rows, pad to 72 halfs
    __shared__ __align__(16) _Float16 Ps[64 * 136];   // 64 rows x 128, pad to 136
    const int s0 = blockIdx.x * 64, bh = blockIdx.y;
    const int b = bh >> 4, h = bh & 15;
    const int t = threadIdx.x;
    const int wave = t >> 6, lane = t & 63;
    const int quad = lane >> 4, l15 = lane & 15;

    // stage Q tile (64 x 64 halfs) with pad
    {
        const _Float16* qg = Qh + ((size_t)bh * cS + s0) * cHD;
#pragma unroll
        for (int i = 0; i < 2; ++i) {
            int idx = t + i * 256;               // 512 chunks of 8 halfs
            int row = idx >> 3, c8 = idx & 7;
            *reinterpret_cast<f16x8*>(&Qs[row * 72 + c8 * 8]) =
                *reinterpret_cast<const f16x8*>(qg + (size_t)row * cHD + c8 * 8);
        }
    }
    __syncthreads();

    // S = Q @ Kl^T : wave rows [wave*16, +16), 8 n-tiles of 16 landmarks
    const _Float16* klg = Klh + (size_t)bh * cNL * cHD;
    f32x4 accS[8];
#pragma unroll
    for (int nt = 0; nt < 8; ++nt) accS[nt] = (f32x4){0.f, 0.f, 0.f, 0.f};
#pragma unroll
    for (int k0 = 0; k0 < 2; ++k0) {
        f16x8 aq = *reinterpret_cast<const f16x8*>(&Qs[(wave * 16 + l15) * 72 + k0 * 32 + quad * 8]);
#pragma unroll
        for (int nt = 0; nt < 8; ++nt) {
            f16x8 bk = *reinterpret_cast<const f16x8*>(klg + (size_t)(nt * 16 + l15) * cHD + k0 * 32 + quad * 8);
            accS[nt] = __builtin_amdgcn_mfma_f32_16x16x32_f16(aq, bk, accS[nt], 0, 0, 0);
        }
    }

    // row softmax in C-layout: row = quad*4 + r (per wave), col = nt*16 + l15
    float rmax[4] = {-1e30f, -1e30f, -1e30f, -1e30f};
#pragma unroll
    for (int nt = 0; nt < 8; ++nt)
#pragma unroll
        for (int r = 0; r < 4; ++r) rmax[r] = fmaxf(rmax[r], accS[nt][r]);
#pragma unroll
    for (int r = 0; r < 4; ++r)
#pragma unroll
        for (int w = 1; w < 16; w <<= 1) rmax[r] = fmaxf(rmax[r], __shfl_xor(rmax[r], w, 16));
    float rsum[4] = {0.f, 0.f, 0.f, 0.f};
#pragma unroll
    for (int nt = 0; nt < 8; ++nt)
#pragma unroll
        for (int r = 0; r < 4; ++r) { accS[nt][r] = __expf(accS[nt][r] - rmax[r]); rsum[r] += accS[nt][r]; }
#pragma unroll
    for (int r = 0; r < 4; ++r) {
#pragma unroll
        for (int w = 1; w < 16; w <<= 1) rsum[r] += __shfl_xor(rsum[r], w, 16);
        rsum[r] = 1.0f / rsum[r];
    }
    // write normalized P (f16) to LDS in row-major [m][l]
#pragma unroll
    for (int nt = 0; nt < 8; ++nt)
#pragma unroll
        for (int r = 0; r < 4; ++r)
            Ps[(wave * 16 + quad * 4 + r) * 136 + nt * 16 + l15] = (_Float16)(accS[nt][r] * rsum[r]);
    __syncthreads();

    // ctx = P @ W2  (W2T rows are d, cols l)
    const _Float16* wtg = W2T + (size_t)bh * cHD * cNL;
    f32x4 accO[4];
#pragma unroll
    for (int nt = 0; nt < 4; ++nt) accO[nt] = (f32x4){0.f, 0.f, 0.f, 0.f};
#pragma unroll
    for (int k0 = 0; k0 < 4; ++k0) {
        f16x8 ap = *reinterpret_cast<const f16x8*>(&Ps[(wave * 16 + l15) * 136 + k0 * 32 + quad * 8]);
#pragma unroll
        for (int nt = 0; nt < 4; ++nt) {
            f16x8 bw = *reinterpret_cast<const f16x8*>(wtg + (size_t)(nt * 16 + l15) * cNL + k0 * 32 + quad * 8);
            accO[nt] = __builtin_amdgcn_mfma_f32_16x16x32_f16(ap, bw, accO[nt], 0, 0, 0);
        }
    }
#pragma unroll
    for (int nt = 0; nt < 4; ++nt)
#pragma unroll
        for (int r = 0; r < 4; ++r) {
            int s = s0 + wave * 16 + quad * 4 + r;
            int d = nt * 16 + l15;
            ctxh[((size_t)(b * cS) + s) * cD + h * cHD + d] = (_Float16)accO[nt][r];
        }
}

// ---------------------------------------------------------------------------
extern "C" void kernel_launch(void* const* d_in, const int* in_sizes, int n_in,
                              void* d_out, int out_size, void* d_ws, size_t ws_size,
                              hipStream_t stream)
{
    const float* X    = (const float*)d_in[0];
    const float* mask = (const float*)d_in[1];
    const float* Wq   = (const float*)d_in[2];
    const float* bq   = (const float*)d_in[3];
    const float* Wk   = (const float*)d_in[4];
    const float* bk   = (const float*)d_in[5];
    const float* Wv   = (const float*)d_in[6];
    const float* bv   = (const float*)d_in[7];
    const float* Wo   = (const float*)d_in[8];
    const float* bo   = (const float*)d_in[9];
    float* out = (float*)d_out;

    float* ws = (float*)d_ws;
    size_t off = 0;
    const size_t szQKV = (size_t)cBH * cS * cHD;      // 8388608 floats
    const size_t szL   = (size_t)cBH * cNL * cHD;     // 262144
    const size_t szM   = (size_t)cBH * cNL * cNL;     // 524288
    float* Q    = ws + off; off += szQKV;             // holds Qh (f16) now
    float* K    = ws + off; off += szQKV;
    float* V    = ws + off; off += szQKV;
    _Float16* Xh  = (_Float16*)(ws + off); off += szQKV / 2;
    _Float16* WqT = (_Float16*)(ws + off); off += 524288;
    _Float16* WkT = (_Float16*)(ws + off); off += 524288;
    _Float16* WvT = (_Float16*)(ws + off); off += 524288;
    _Float16* WoT = (_Float16*)(ws + off); off += 524288;
    float* Xm   = ws + off; off += (size_t)cB * cNL * cHID;
    float* mbar = ws + off; off += 256;
    float* Ql  = ws + off; off += szL;
    float* Kl  = ws + off; off += szL;
    float* k2  = ws + off; off += szM;
    float* Vb0 = ws + off; off += szM;
    float* Vb1 = ws + off; off += szM;
    float* Zb  = ws + off; off += szM;
    float* T2b = ws + off; off += szM;
    float* T3b = ws + off; off += szM;
    float* CV  = ws + off; off += szL;
    _Float16* Klh  = (_Float16*)(ws + off); off += szL / 2;   // f16 landmarks
    _Float16* W2Th = (_Float16*)(ws + off); off += szL / 2;   // f16 W2^T
    int*   cmax = (int*)(ws + off); off += 16;
    float* mpart = ws + off; off += 32768;
    float* spart = ws + off; off += 32768;
    _Float16* Qh = (_Float16*)Q;             // Q stored as f16
    _Float16* KT = (_Float16*)Xh;            // Xh dead after qkv_gemm_f16
    float* Opart = Vb1;                      // Vb1..T3b dead after nys loop
    _Float16* ctxh = (_Float16*)K;           // K dead after ktrans+k3v_split

    hipMemsetAsync(cmax, 0, sizeof(int), stream);

    cast_x<<<(int)(szQKV / 1024), 256, 0, stream>>>(X, Xh);
    wcast_t<<<dim3(32, 32, 4), 256, 0, stream>>>(Wq, Wk, Wv, Wo, WqT, WkT, WvT, WoT);
    xm_kernel<<<cB * cNL, 256, 0, stream>>>(X, mask, Xm, mbar);

    qkv_gemm_f16<<<dim3(cD / 128, (cB * cS) / 128, 3), 256, 0, stream>>>(
        Xh, mask, WqT, WkT, WvT, bq, bk, bv, Qh, K, V);
    ktrans<<<dim3(cS / 64, cBH), 256, 0, stream>>>(K, KT);
    lgemm<<<dim3(cD / 64, (cB * cNL) / 64, 2), 256, 0, stream>>>(Xm, mbar, Wq, bq, Wk, bk, Ql, Kl, Klh);

    k2_softmax<<<cBH * cNL, 128, 0, stream>>>(Ql, Kl, k2);
    colsum_max<<<cBH, 128, 0, stream>>>(k2, cmax);
    v0_kernel<<<cBH * cNL, 128, 0, stream>>>(k2, cmax, Vb0);

    float* Vc = Vb0; float* Vn = Vb1;
    for (int it = 0; it < 6; ++it) {
        nys_matmul<<<dim3(2, 2, cBH), 256, 0, stream>>>(k2, Vc, Zb, 0.f, -1.f);
        nys_matmul<<<dim3(2, 2, cBH), 256, 0, stream>>>(Zb, Zb, T2b, 7.f, 1.f);
        nys_matmul<<<dim3(2, 2, cBH), 256, 0, stream>>>(Zb, T2b, T3b, 15.f, 1.f);
        nys_matmul<<<dim3(2, 2, cBH), 256, 0, stream>>>(Vc, T3b, Vn, 13.f, 0.25f);
        float* tmp = Vc; Vc = Vn; Vn = tmp;
    }
    // Vc == Vb0 after 6 iters; Vb1..T3b reused as Opart

    k3v_split<<<dim3(cNL / 16, cBH, 8), 256, 0, stream>>>(Ql, KT, V, mask, Opart, mpart, spart);
    k3v_reduce<<<1024, 256, 0, stream>>>(Opart, mpart, spart, CV);
    w2_matmul<<<cBH, 256, 0, stream>>>(Vc, CV, W2Th);
    k1_mfma<<<dim3(cS / 64, cBH), 256, 0, stream>>>(Qh, Klh, W2Th, ctxh);
    out_gemm_f16<<<dim3(cHID / 128, (cB * cS) / 128), 256, 0, stream>>>(ctxh, WoT, bo, out);
}

// Round 6
// 608.953 us; speedup vs baseline: 4.6784x; 1.1951x over previous
//
#include <hip/hip_runtime.h>
#include <math.h>

// Problem constants
constexpr int cB = 2, cS = 4096, cHID = 1024, cNH = 16, cHD = 64, cNL = 128, cSEG = 32, cD = 1024, cBH = 32;
constexpr float cSCALE = 0.35355339059327373f;   // 1/sqrt(sqrt(64))

typedef _Float16 f16x8 __attribute__((ext_vector_type(8)));
typedef float f32x4 __attribute__((ext_vector_type(4)));

__device__ inline void gload_lds16(const void* g, void* l) {
    __builtin_amdgcn_global_load_lds(
        (const __attribute__((address_space(1))) void*)g,
        (__attribute__((address_space(3))) void*)l, 16, 0, 0);
}

// ---------------------------------------------------------------------------
// cast X fp32 -> fp16
// ---------------------------------------------------------------------------
__global__ __launch_bounds__(256) void cast_x(const float* __restrict__ X, _Float16* __restrict__ Xh)
{
    int i = (blockIdx.x * 256 + threadIdx.x) * 4;
    float4 v = *reinterpret_cast<const float4*>(X + i);
    union { _Float16 h[4]; ushort4 u; } p;
    p.h[0] = (_Float16)v.x; p.h[1] = (_Float16)v.y; p.h[2] = (_Float16)v.z; p.h[3] = (_Float16)v.w;
    *reinterpret_cast<ushort4*>(Xh + i) = p.u;
}

// ---------------------------------------------------------------------------
// transpose+cast W (K x N fp32) -> WT (N x K fp16)
// ---------------------------------------------------------------------------
__global__ __launch_bounds__(256) void wcast_t(
    const float* __restrict__ Wq, const float* __restrict__ Wk,
    const float* __restrict__ Wv, const float* __restrict__ Wo,
    _Float16* __restrict__ WqT, _Float16* __restrict__ WkT,
    _Float16* __restrict__ WvT, _Float16* __restrict__ WoT)
{
    __shared__ float tile[32][33];
    const int wsel = blockIdx.z;
    const float* W = (wsel == 0) ? Wq : (wsel == 1 ? Wk : (wsel == 2 ? Wv : Wo));
    _Float16* WT   = (wsel == 0) ? WqT : (wsel == 1 ? WkT : (wsel == 2 ? WvT : WoT));
    const int n0 = blockIdx.x * 32, k0 = blockIdx.y * 32;
    const int t = threadIdx.x;
    const int r = t >> 3, c = (t & 7) * 4;
    float4 v = *reinterpret_cast<const float4*>(W + (size_t)(k0 + r) * cD + n0 + c);
    tile[r][c] = v.x; tile[r][c + 1] = v.y; tile[r][c + 2] = v.z; tile[r][c + 3] = v.w;
    __syncthreads();
    union { _Float16 h[4]; ushort4 u; } p;
    p.h[0] = (_Float16)tile[c + 0][r]; p.h[1] = (_Float16)tile[c + 1][r];
    p.h[2] = (_Float16)tile[c + 2][r]; p.h[3] = (_Float16)tile[c + 3][r];
    *reinterpret_cast<ushort4*>(WT + (size_t)(n0 + r) * cHID + k0 + c) = p.u;
}

// ---------------------------------------------------------------------------
// Xm[b*128+l][:] = (1/32) sum_j mask*X ; mbar = mean mask  (fp32 landmark input)
// ---------------------------------------------------------------------------
__global__ __launch_bounds__(256) void xm_kernel(
    const float* __restrict__ X, const float* __restrict__ mask,
    float* __restrict__ Xm, float* __restrict__ mbar)
{
    const int bl = blockIdx.x;          // b*128 + l
    const int b = bl >> 7, l = bl & 127;
    const int c = threadIdx.x * 4;
    float4 a = {0.f, 0.f, 0.f, 0.f};
    float msum = 0.f;
    for (int j = 0; j < cSEG; ++j) {
        float m = mask[b * cS + l * cSEG + j];
        float4 x = *reinterpret_cast<const float4*>(X + ((size_t)(b * cS + l * cSEG + j)) * cHID + c);
        a.x += m * x.x; a.y += m * x.y; a.z += m * x.z; a.w += m * x.w;
        msum += m;
    }
    const float inv = 1.0f / cSEG;
    a.x *= inv; a.y *= inv; a.z *= inv; a.w *= inv;
    *reinterpret_cast<float4*>(Xm + (size_t)bl * cHID + c) = a;
    if (threadIdx.x == 0) mbar[bl] = msum * inv;
}

// ---------------------------------------------------------------------------
// f16 MFMA GEMM: QKV. Q,K,V all written f16 (k3v/k1 are the only consumers).
// ---------------------------------------------------------------------------
__global__ __launch_bounds__(256) void qkv_gemm_f16(
    const _Float16* __restrict__ Xh, const float* __restrict__ mask,
    const _Float16* __restrict__ WqT, const _Float16* __restrict__ WkT, const _Float16* __restrict__ WvT,
    const float* __restrict__ bq, const float* __restrict__ bk, const float* __restrict__ bv,
    _Float16* __restrict__ Qh, _Float16* __restrict__ Kh, _Float16* __restrict__ Vh)
{
    __shared__ __align__(16) _Float16 As[128 * 32];
    __shared__ __align__(16) _Float16 Bs[128 * 32];
    const int wsel = blockIdx.z;
    const _Float16* WT = (wsel == 0) ? WqT : (wsel == 1 ? WkT : WvT);
    const float* bias  = (wsel == 0) ? bq  : (wsel == 1 ? bk  : bv);
    _Float16* Y        = (wsel == 0) ? Qh  : (wsel == 1 ? Kh  : Vh);
    const int n0 = blockIdx.x * 128, m0 = blockIdx.y * 128;
    const int t = threadIdx.x;
    const int wave = t >> 6, lane = t & 63;
    const int wm = (wave >> 1) * 64, wn = (wave & 1) * 64;
    const int quad = lane >> 4, l15 = lane & 15;
    const int srow = wave * 32 + (lane >> 2);
    const int scol = (lane & 3) * 8;

    f32x4 acc[4][4];
#pragma unroll
    for (int i = 0; i < 4; ++i)
#pragma unroll
        for (int j = 0; j < 4; ++j) acc[i][j] = (f32x4){0.f, 0.f, 0.f, 0.f};

    for (int k0 = 0; k0 < cHID; k0 += 32) {
        const _Float16* aSrc = Xh + (size_t)(m0 + srow) * cHID + k0 + scol;
        const _Float16* bSrc = WT + (size_t)(n0 + srow) * cHID + k0 + scol;
        gload_lds16(aSrc,              &As[(wave * 32) * 32]);
        gload_lds16(aSrc + 16 * cHID,  &As[(wave * 32 + 16) * 32]);
        gload_lds16(bSrc,              &Bs[(wave * 32) * 32]);
        gload_lds16(bSrc + 16 * cHID,  &Bs[(wave * 32 + 16) * 32]);
        __syncthreads();
        f16x8 af[4], bf[4];
#pragma unroll
        for (int mt = 0; mt < 4; ++mt)
            af[mt] = *reinterpret_cast<const f16x8*>(&As[(wm + mt * 16 + l15) * 32 + quad * 8]);
#pragma unroll
        for (int nt = 0; nt < 4; ++nt)
            bf[nt] = *reinterpret_cast<const f16x8*>(&Bs[(wn + nt * 16 + l15) * 32 + quad * 8]);
#pragma unroll
        for (int mt = 0; mt < 4; ++mt)
#pragma unroll
            for (int nt = 0; nt < 4; ++nt)
                acc[mt][nt] = __builtin_amdgcn_mfma_f32_16x16x32_f16(af[mt], bf[nt], acc[mt][nt], 0, 0, 0);
        __syncthreads();
    }
#pragma unroll
    for (int mt = 0; mt < 4; ++mt) {
#pragma unroll
        for (int r = 0; r < 4; ++r) {
            int R = m0 + wm + mt * 16 + quad * 4 + r;
            int b = R >> 12, s = R & (cS - 1);
            float msc = (wsel < 2) ? mask[b * cS + s] * cSCALE : 1.0f;
#pragma unroll
            for (int nt = 0; nt < 4; ++nt) {
                int Cc = n0 + wn + nt * 16 + l15;
                int h = Cc >> 6, d = Cc & 63;
                float val = (acc[mt][nt][r] + bias[Cc]) * msc;
                Y[((size_t)(b * cNH + h) * cS + s) * cHD + d] = (_Float16)val;
            }
        }
    }
}

// ---------------------------------------------------------------------------
// f16 MFMA GEMM: out = ctxh @ Wo + bo
// ---------------------------------------------------------------------------
__global__ __launch_bounds__(256) void out_gemm_f16(
    const _Float16* __restrict__ Ah, const _Float16* __restrict__ WT,
    const float* __restrict__ bias, float* __restrict__ Y)
{
    __shared__ __align__(16) _Float16 As[128 * 32];
    __shared__ __align__(16) _Float16 Bs[128 * 32];
    const int n0 = blockIdx.x * 128, m0 = blockIdx.y * 128;
    const int t = threadIdx.x;
    const int wave = t >> 6, lane = t & 63;
    const int wm = (wave >> 1) * 64, wn = (wave & 1) * 64;
    const int quad = lane >> 4, l15 = lane & 15;
    const int srow = wave * 32 + (lane >> 2);
    const int scol = (lane & 3) * 8;

    f32x4 acc[4][4];
#pragma unroll
    for (int i = 0; i < 4; ++i)
#pragma unroll
        for (int j = 0; j < 4; ++j) acc[i][j] = (f32x4){0.f, 0.f, 0.f, 0.f};

    for (int k0 = 0; k0 < cD; k0 += 32) {
        const _Float16* aSrc = Ah + (size_t)(m0 + srow) * cD + k0 + scol;
        const _Float16* bSrc = WT + (size_t)(n0 + srow) * cD + k0 + scol;
        gload_lds16(aSrc,             &As[(wave * 32) * 32]);
        gload_lds16(aSrc + 16 * cD,   &As[(wave * 32 + 16) * 32]);
        gload_lds16(bSrc,             &Bs[(wave * 32) * 32]);
        gload_lds16(bSrc + 16 * cD,   &Bs[(wave * 32 + 16) * 32]);
        __syncthreads();
        f16x8 af[4], bf[4];
#pragma unroll
        for (int mt = 0; mt < 4; ++mt)
            af[mt] = *reinterpret_cast<const f16x8*>(&As[(wm + mt * 16 + l15) * 32 + quad * 8]);
#pragma unroll
        for (int nt = 0; nt < 4; ++nt)
            bf[nt] = *reinterpret_cast<const f16x8*>(&Bs[(wn + nt * 16 + l15) * 32 + quad * 8]);
#pragma unroll
        for (int mt = 0; mt < 4; ++mt)
#pragma unroll
            for (int nt = 0; nt < 4; ++nt)
                acc[mt][nt] = __builtin_amdgcn_mfma_f32_16x16x32_f16(af[mt], bf[nt], acc[mt][nt], 0, 0, 0);
        __syncthreads();
    }
#pragma unroll
    for (int mt = 0; mt < 4; ++mt) {
#pragma unroll
        for (int r = 0; r < 4; ++r) {
            int R = m0 + wm + mt * 16 + quad * 4 + r;
#pragma unroll
            for (int nt = 0; nt < 4; ++nt) {
                int Cc = n0 + wn + nt * 16 + l15;
                Y[(size_t)R * cHID + Cc] = acc[mt][nt][r] + bias[Cc];
            }
        }
    }
}

// ---------------------------------------------------------------------------
// Landmark GEMM (fp32, exact path). Emits f16 Qlh/Klh for MFMA consumers.
// ---------------------------------------------------------------------------
__global__ __launch_bounds__(256) void lgemm(
    const float* __restrict__ Xm, const float* __restrict__ mbar,
    const float* __restrict__ Wq, const float* __restrict__ bq,
    const float* __restrict__ Wk, const float* __restrict__ bk,
    float* __restrict__ Ql, float* __restrict__ Kl,
    _Float16* __restrict__ Qlh, _Float16* __restrict__ Klh)
{
    __shared__ __align__(16) float As[16][68];
    __shared__ __align__(16) float Bs[16][68];
    const int tid = threadIdx.x;
    const int wsel = blockIdx.z;
    const float* W    = wsel ? Wk : Wq;
    const float* bias = wsel ? bk : bq;
    float* Yl         = wsel ? Kl : Ql;
    _Float16* Ylh     = wsel ? Klh : Qlh;
    const int c0 = blockIdx.x * 64, r0 = blockIdx.y * 64;
    const int tx = tid & 15, ty = tid >> 4;
    const int am = tid >> 2, ak = (tid & 3) * 4;
    const int bkk = tid >> 4, bn = (tid & 15) * 4;

    float acc[4][4] = {};
    for (int k0 = 0; k0 < cHID; k0 += 16) {
        float4 a4 = *reinterpret_cast<const float4*>(Xm + (size_t)(r0 + am) * cHID + k0 + ak);
        As[ak + 0][am] = a4.x; As[ak + 1][am] = a4.y; As[ak + 2][am] = a4.z; As[ak + 3][am] = a4.w;
        float4 b4 = *reinterpret_cast<const float4*>(W + (size_t)(k0 + bkk) * cD + c0 + bn);
        *reinterpret_cast<float4*>(&Bs[bkk][bn]) = b4;
        __syncthreads();
#pragma unroll
        for (int kk = 0; kk < 16; ++kk) {
            float4 av  = *reinterpret_cast<const float4*>(&As[kk][ty * 4]);
            float4 bv4 = *reinterpret_cast<const float4*>(&Bs[kk][tx * 4]);
            float a_[4] = {av.x, av.y, av.z, av.w};
            float b_[4] = {bv4.x, bv4.y, bv4.z, bv4.w};
#pragma unroll
            for (int i = 0; i < 4; ++i)
#pragma unroll
                for (int j = 0; j < 4; ++j) acc[i][j] += a_[i] * b_[j];
        }
        __syncthreads();
    }
#pragma unroll
    for (int i = 0; i < 4; ++i) {
        int r = r0 + ty * 4 + i;          // b*128 + l
        int b = r >> 7, l = r & 127;
        float mb = mbar[r];
#pragma unroll
        for (int j = 0; j < 4; ++j) {
            int c = c0 + tx * 4 + j;
            int h = c >> 6, d = c & 63;
            float val = (acc[i][j] + mb * bias[c]) * cSCALE;
            size_t idx = ((size_t)(b * cNH + h) * cNL + l) * cHD + d;
            Yl[idx] = val;
            Ylh[idx] = (_Float16)val;
        }
    }
}

// ---------------------------------------------------------------------------
// k2 softmax chain (fp32-clean path)
// ---------------------------------------------------------------------------
__global__ __launch_bounds__(128) void k2_softmax(
    const float* __restrict__ Ql, const float* __restrict__ Kl, float* __restrict__ k2)
{
    __shared__ __align__(16) float qrow[64];
    __shared__ float red[128];
    int bh = blockIdx.x >> 7, i = blockIdx.x & 127;
    int j = threadIdx.x;
    if (j < 64) qrow[j] = Ql[(bh * cNL + i) * cHD + j];
    __syncthreads();
    const float4* q4  = reinterpret_cast<const float4*>(qrow);
    const float4* kl4 = reinterpret_cast<const float4*>(Kl + (bh * cNL + j) * cHD);
    float dot = 0.f;
#pragma unroll
    for (int u = 0; u < 16; ++u) {
        float4 a = q4[u], b = kl4[u];
        dot += a.x * b.x + a.y * b.y + a.z * b.z + a.w * b.w;
    }
    red[j] = dot; __syncthreads();
    for (int off = 64; off > 0; off >>= 1) { if (j < off) red[j] = fmaxf(red[j], red[j + off]); __syncthreads(); }
    float m = red[0]; __syncthreads();
    float e = expf(dot - m);
    red[j] = e; __syncthreads();
    for (int off = 64; off > 0; off >>= 1) { if (j < off) red[j] += red[j + off]; __syncthreads(); }
    k2[(bh * cNL + i) * cNL + j] = e / red[0];
}

__global__ __launch_bounds__(128) void colsum_max(const float* __restrict__ k2, int* __restrict__ cmax)
{
    __shared__ float red[128];
    int bh = blockIdx.x, j = threadIdx.x;
    float s = 0.f;
    for (int i = 0; i < cNL; ++i) s += k2[(bh * cNL + i) * cNL + j];
    red[j] = s; __syncthreads();
    for (int off = 64; off > 0; off >>= 1) { if (j < off) red[j] = fmaxf(red[j], red[j + off]); __syncthreads(); }
    if (j == 0) atomicMax(cmax, __float_as_int(red[0]));
}

__global__ __launch_bounds__(128) void v0_kernel(
    const float* __restrict__ k2, const int* __restrict__ cmax, float* __restrict__ V0)
{
    int bh = blockIdx.x >> 7, i = blockIdx.x & 127, j = threadIdx.x;
    float c = __int_as_float(*cmax);
    V0[(bh * cNL + i) * cNL + j] = k2[(bh * cNL + j) * cNL + i] / c;
}

// ---------------------------------------------------------------------------
// Batched 128x128: C = ds * (cs*A - A@B)
// ---------------------------------------------------------------------------
__global__ __launch_bounds__(256) void nys_matmul(
    const float* __restrict__ A, const float* __restrict__ Bm, float* __restrict__ C,
    float cs, float ds)
{
    __shared__ __align__(16) float As[16][68];
    __shared__ __align__(16) float Bs[16][68];
    const int tid = threadIdx.x;
    const int c0 = blockIdx.x * 64, r0 = blockIdx.y * 64;
    const int base = blockIdx.z * cNL * cNL;
    const int tx = tid & 15, ty = tid >> 4;
    const int am = tid >> 2, ak = (tid & 3) * 4;
    const int bkk = tid >> 4, bn = (tid & 15) * 4;

    float acc[4][4] = {};
    for (int k0 = 0; k0 < cNL; k0 += 16) {
        float4 a4 = *reinterpret_cast<const float4*>(A + base + (r0 + am) * cNL + k0 + ak);
        As[ak + 0][am] = a4.x; As[ak + 1][am] = a4.y; As[ak + 2][am] = a4.z; As[ak + 3][am] = a4.w;
        float4 b4 = *reinterpret_cast<const float4*>(Bm + base + (k0 + bkk) * cNL + c0 + bn);
        *reinterpret_cast<float4*>(&Bs[bkk][bn]) = b4;
        __syncthreads();
#pragma unroll
        for (int kk = 0; kk < 16; ++kk) {
            float4 av  = *reinterpret_cast<const float4*>(&As[kk][ty * 4]);
            float4 bv4 = *reinterpret_cast<const float4*>(&Bs[kk][tx * 4]);
            float a_[4] = {av.x, av.y, av.z, av.w};
            float b_[4] = {bv4.x, bv4.y, bv4.z, bv4.w};
#pragma unroll
            for (int i = 0; i < 4; ++i)
#pragma unroll
                for (int j = 0; j < 4; ++j) acc[i][j] += a_[i] * b_[j];
        }
        __syncthreads();
    }
#pragma unroll
    for (int i = 0; i < 4; ++i) {
        int r = r0 + ty * 4 + i;
#pragma unroll
        for (int j = 0; j < 4; ++j) {
            int c = c0 + tx * 4 + j;
            float av = A[base + r * cNL + c];
            C[base + r * cNL + c] = ds * (cs * av - acc[i][j]);
        }
    }
}

// ---------------------------------------------------------------------------
// vtrans: Vh[bh][s][d] f16 -> VTh[bh][d][s] f16 (64x64 LDS tiles)
// ---------------------------------------------------------------------------
__global__ __launch_bounds__(256) void vtrans(const _Float16* __restrict__ Vh, _Float16* __restrict__ VTh)
{
    __shared__ ushort T[64][72];
    const int s0 = blockIdx.x * 64, bh = blockIdx.y;
    const int t = threadIdx.x;
    const _Float16* vb = Vh + ((size_t)bh * cS + s0) * cHD;
#pragma unroll
    for (int i = 0; i < 2; ++i) {
        int idx = t + i * 256;
        int row = idx >> 3, c8 = idx & 7;
        f16x8 v = *reinterpret_cast<const f16x8*>(vb + (size_t)row * cHD + c8 * 8);
#pragma unroll
        for (int j = 0; j < 8; ++j) T[row][c8 * 8 + j] = ((ushort*)&v)[j];
    }
    __syncthreads();
    _Float16* vt = VTh + (size_t)bh * cHD * cS;
#pragma unroll
    for (int i = 0; i < 2; ++i) {
        int idx = t + i * 256;
        int d = idx >> 3, s8 = idx & 7;
        f16x8 o;
#pragma unroll
        for (int j = 0; j < 8; ++j) ((ushort*)&o)[j] = T[s8 * 8 + j][d];
        *reinterpret_cast<f16x8*>(vt + (size_t)d * cS + s0 + s8 * 8) = o;
    }
}

// ---------------------------------------------------------------------------
// k3v_mfma: flash-prefill over landmarks. grid (16 s-chunks, 32 bh), 4 waves.
// Wave owns 32 l-rows (2 m-tiles). S = Qlh@Kh^T (MFMA), online softmax in
// C-layout regs, P f16 -> wave-private LDS (no barriers), PV = P@VTh (MFMA).
// Emits per-chunk partials (O unnormalized, m, s).
// ---------------------------------------------------------------------------
__global__ __launch_bounds__(256) void k3v_mfma(
    const _Float16* __restrict__ Qlh, const _Float16* __restrict__ Kh,
    const _Float16* __restrict__ VTh, const float* __restrict__ mask,
    float* __restrict__ Opart, float* __restrict__ mpart, float* __restrict__ spart)
{
    __shared__ __align__(16) _Float16 Ps[128 * 72];   // wave-private row bands
    __shared__ float msk[256];
    const int z = blockIdx.x, bh = blockIdx.y;
    const int b = bh >> 4;
    const int sbase = z * 256;
    const int t = threadIdx.x;
    const int wave = t >> 6, lane = t & 63;
    const int quad = lane >> 4, l15 = lane & 15;

    msk[t] = mask[b * cS + sbase + t];

    // Ql A-fragments: rows wave*32 + mt*16 + l15, k = k0*32 + quad*8
    f16x8 aq[2][2];
    const _Float16* qlg = Qlh + (size_t)bh * cNL * cHD;
#pragma unroll
    for (int mt = 0; mt < 2; ++mt)
#pragma unroll
        for (int k0 = 0; k0 < 2; ++k0)
            aq[mt][k0] = *reinterpret_cast<const f16x8*>(
                qlg + (size_t)(wave * 32 + mt * 16 + l15) * cHD + k0 * 32 + quad * 8);

    float mrun[2][4], srun[2][4];
    f32x4 accO[2][4];
#pragma unroll
    for (int mt = 0; mt < 2; ++mt)
#pragma unroll
        for (int r = 0; r < 4; ++r) { mrun[mt][r] = -1e30f; srun[mt][r] = 0.f; }
#pragma unroll
    for (int mt = 0; mt < 2; ++mt)
#pragma unroll
        for (int dt = 0; dt < 4; ++dt) accO[mt][dt] = (f32x4){0.f, 0.f, 0.f, 0.f};

    __syncthreads();   // msk visible

    const _Float16* kg = Kh + (size_t)bh * cS * cHD;
    const _Float16* vg = VTh + (size_t)bh * cHD * cS;

    for (int step = 0; step < 4; ++step) {
        const int st = sbase + step * 64;
        // ---- S = Ql @ K^T (64 s-cols) ----
        f32x4 accS[2][4];
#pragma unroll
        for (int mt = 0; mt < 2; ++mt)
#pragma unroll
            for (int nt = 0; nt < 4; ++nt) accS[mt][nt] = (f32x4){0.f, 0.f, 0.f, 0.f};
#pragma unroll
        for (int k0 = 0; k0 < 2; ++k0)
#pragma unroll
            for (int nt = 0; nt < 4; ++nt) {
                f16x8 bk = *reinterpret_cast<const f16x8*>(
                    kg + (size_t)(st + nt * 16 + l15) * cHD + k0 * 32 + quad * 8);
#pragma unroll
                for (int mt = 0; mt < 2; ++mt)
                    accS[mt][nt] = __builtin_amdgcn_mfma_f32_16x16x32_f16(aq[mt][k0], bk, accS[mt][nt], 0, 0, 0);
            }
        // ---- mask + online softmax (C-layout: row=quad*4+r, col=nt*16+l15) ----
#pragma unroll
        for (int nt = 0; nt < 4; ++nt) {
            float pen = 1e9f * (1.0f - msk[step * 64 + nt * 16 + l15]);
#pragma unroll
            for (int mt = 0; mt < 2; ++mt)
#pragma unroll
                for (int r = 0; r < 4; ++r) accS[mt][nt][r] -= pen;
        }
#pragma unroll
        for (int mt = 0; mt < 2; ++mt) {
#pragma unroll
            for (int r = 0; r < 4; ++r) {
                float tmax = fmaxf(fmaxf(accS[mt][0][r], accS[mt][1][r]),
                                   fmaxf(accS[mt][2][r], accS[mt][3][r]));
#pragma unroll
                for (int w = 1; w < 16; w <<= 1) tmax = fmaxf(tmax, __shfl_xor(tmax, w, 16));
                float mnew = fmaxf(mrun[mt][r], tmax);
                float alpha = __expf(mrun[mt][r] - mnew);
                float ts = 0.f;
#pragma unroll
                for (int nt = 0; nt < 4; ++nt) {
                    float e = __expf(accS[mt][nt][r] - mnew);
                    accS[mt][nt][r] = e; ts += e;
                }
#pragma unroll
                for (int w = 1; w < 16; w <<= 1) ts += __shfl_xor(ts, w, 16);
                srun[mt][r] = srun[mt][r] * alpha + ts;
                mrun[mt][r] = mnew;
#pragma unroll
                for (int dt = 0; dt < 4; ++dt) accO[mt][dt][r] *= alpha;
            }
        }
        // ---- P (f16) -> wave-private LDS rows ----
#pragma unroll
        for (int mt = 0; mt < 2; ++mt)
#pragma unroll
            for (int nt = 0; nt < 4; ++nt)
#pragma unroll
                for (int r = 0; r < 4; ++r)
                    Ps[(wave * 32 + mt * 16 + quad * 4 + r) * 72 + nt * 16 + l15] =
                        (_Float16)accS[mt][nt][r];
        // ---- PV: O += P @ V ----
#pragma unroll
        for (int k0 = 0; k0 < 2; ++k0) {
            f16x8 ap[2];
#pragma unroll
            for (int mt = 0; mt < 2; ++mt)
                ap[mt] = *reinterpret_cast<const f16x8*>(
                    &Ps[(wave * 32 + mt * 16 + l15) * 72 + k0 * 32 + quad * 8]);
#pragma unroll
            for (int dt = 0; dt < 4; ++dt) {
                f16x8 bv = *reinterpret_cast<const f16x8*>(
                    vg + (size_t)(dt * 16 + l15) * cS + st + k0 * 32 + quad * 8);
#pragma unroll
                for (int mt = 0; mt < 2; ++mt)
                    accO[mt][dt] = __builtin_amdgcn_mfma_f32_16x16x32_f16(ap[mt], bv, accO[mt][dt], 0, 0, 0);
            }
        }
    }
    // ---- write partials ----
    const int rowbase = bh * cNL + wave * 32;
#pragma unroll
    for (int mt = 0; mt < 2; ++mt)
#pragma unroll
        for (int dt = 0; dt < 4; ++dt)
#pragma unroll
            for (int r = 0; r < 4; ++r)
                Opart[(size_t)(z * 4096 + rowbase + mt * 16 + quad * 4 + r) * cHD + dt * 16 + l15] =
                    accO[mt][dt][r];
    if (l15 == 0) {
#pragma unroll
        for (int mt = 0; mt < 2; ++mt)
#pragma unroll
            for (int r = 0; r < 4; ++r) {
                int prow = z * 4096 + rowbase + mt * 16 + quad * 4 + r;
                mpart[prow] = mrun[mt][r];
                spart[prow] = srun[mt][r];
            }
    }
}

// ---------------------------------------------------------------------------
// combine 16 chunk-partials
// ---------------------------------------------------------------------------
__global__ __launch_bounds__(256) void k3v_reduce(
    const float* __restrict__ Opart, const float* __restrict__ mpart,
    const float* __restrict__ spart, float* __restrict__ CV)
{
    const int t = threadIdx.x;
    const int row = blockIdx.x * 4 + (t >> 6);
    const int d = t & 63;
    float mstar = -1e30f;
#pragma unroll
    for (int z = 0; z < 16; ++z) mstar = fmaxf(mstar, mpart[z * 4096 + row]);
    float ssum = 0.f, acc = 0.f;
#pragma unroll
    for (int z = 0; z < 16; ++z) {
        float w = __expf(mpart[z * 4096 + row] - mstar);
        ssum += w * spart[z * 4096 + row];
        acc  += w * Opart[(size_t)(z * 4096 + row) * cHD + d];
    }
    CV[(size_t)row * cHD + d] = acc / ssum;
}

// W2T[bh][d][l] (f16) = (V6[bh] @ CV[bh])^T
__global__ __launch_bounds__(256) void w2_matmul(
    const float* __restrict__ V6, const float* __restrict__ CV, _Float16* __restrict__ W2T)
{
    __shared__ __align__(16) float CVs[128][64];
    const int bh = blockIdx.x, t = threadIdx.x;
    for (int k = 0; k < 32; ++k) { int idx = t + k * 256; CVs[idx >> 6][idx & 63] = CV[bh * 8192 + idx]; }
    __syncthreads();
    const int tx = t & 15, ty = t >> 4;
    float acc[8][4] = {};
    for (int k = 0; k < 128; ++k) {
        float4 b4 = *reinterpret_cast<const float4*>(&CVs[k][tx * 4]);
#pragma unroll
        for (int i = 0; i < 8; ++i) {
            float a = V6[(bh * cNL + ty * 8 + i) * cNL + k];
            acc[i][0] += a * b4.x; acc[i][1] += a * b4.y; acc[i][2] += a * b4.z; acc[i][3] += a * b4.w;
        }
    }
    _Float16* wt = W2T + (size_t)bh * cHD * cNL;
#pragma unroll
    for (int i = 0; i < 8; ++i)
#pragma unroll
        for (int j = 0; j < 4; ++j)
            wt[(size_t)(tx * 4 + j) * cNL + ty * 8 + i] = (_Float16)acc[i][j];
}

// ---------------------------------------------------------------------------
// k1_mfma (unchanged from R5)
// ---------------------------------------------------------------------------
__global__ __launch_bounds__(256) void k1_mfma(
    const _Float16* __restrict__ Qh, const _Float16* __restrict__ Klh,
    const _Float16* __restrict__ W2T, _Float16* __restrict__ ctxh)
{
    __shared__ __align__(16) _Float16 Qs[64 * 72];
    __shared__ __align__(16) _Float16 Ps[64 * 136];
    const int s0 = blockIdx.x * 64, bh = blockIdx.y;
    const int b = bh >> 4, h = bh & 15;
    const int t = threadIdx.x;
    const int wave = t >> 6, lane = t & 63;
    const int quad = lane >> 4, l15 = lane & 15;

    {
        const _Float16* qg = Qh + ((size_t)bh * cS + s0) * cHD;
#pragma unroll
        for (int i = 0; i < 2; ++i) {
            int idx = t + i * 256;
            int row = idx >> 3, c8 = idx & 7;
            *reinterpret_cast<f16x8*>(&Qs[row * 72 + c8 * 8]) =
                *reinterpret_cast<const f16x8*>(qg + (size_t)row * cHD + c8 * 8);
        }
    }
    __syncthreads();

    const _Float16* klg = Klh + (size_t)bh * cNL * cHD;
    f32x4 accS[8];
#pragma unroll
    for (int nt = 0; nt < 8; ++nt) accS[nt] = (f32x4){0.f, 0.f, 0.f, 0.f};
#pragma unroll
    for (int k0 = 0; k0 < 2; ++k0) {
        f16x8 aq = *reinterpret_cast<const f16x8*>(&Qs[(wave * 16 + l15) * 72 + k0 * 32 + quad * 8]);
#pragma unroll
        for (int nt = 0; nt < 8; ++nt) {
            f16x8 bk = *reinterpret_cast<const f16x8*>(klg + (size_t)(nt * 16 + l15) * cHD + k0 * 32 + quad * 8);
            accS[nt] = __builtin_amdgcn_mfma_f32_16x16x32_f16(aq, bk, accS[nt], 0, 0, 0);
        }
    }

    float rmax[4] = {-1e30f, -1e30f, -1e30f, -1e30f};
#pragma unroll
    for (int nt = 0; nt < 8; ++nt)
#pragma unroll
        for (int r = 0; r < 4; ++r) rmax[r] = fmaxf(rmax[r], accS[nt][r]);
#pragma unroll
    for (int r = 0; r < 4; ++r)
#pragma unroll
        for (int w = 1; w < 16; w <<= 1) rmax[r] = fmaxf(rmax[r], __shfl_xor(rmax[r], w, 16));
    float rsum[4] = {0.f, 0.f, 0.f, 0.f};
#pragma unroll
    for (int nt = 0; nt < 8; ++nt)
#pragma unroll
        for (int r = 0; r < 4; ++r) { accS[nt][r] = __expf(accS[nt][r] - rmax[r]); rsum[r] += accS[nt][r]; }
#pragma unroll
    for (int r = 0; r < 4; ++r) {
#pragma unroll
        for (int w = 1; w < 16; w <<= 1) rsum[r] += __shfl_xor(rsum[r], w, 16);
        rsum[r] = 1.0f / rsum[r];
    }
#pragma unroll
    for (int nt = 0; nt < 8; ++nt)
#pragma unroll
        for (int r = 0; r < 4; ++r)
            Ps[(wave * 16 + quad * 4 + r) * 136 + nt * 16 + l15] = (_Float16)(accS[nt][r] * rsum[r]);
    __syncthreads();

    const _Float16* wtg = W2T + (size_t)bh * cHD * cNL;
    f32x4 accO[4];
#pragma unroll
    for (int nt = 0; nt < 4; ++nt) accO[nt] = (f32x4){0.f, 0.f, 0.f, 0.f};
#pragma unroll
    for (int k0 = 0; k0 < 4; ++k0) {
        f16x8 ap = *reinterpret_cast<const f16x8*>(&Ps[(wave * 16 + l15) * 136 + k0 * 32 + quad * 8]);
#pragma unroll
        for (int nt = 0; nt < 4; ++nt) {
            f16x8 bw = *reinterpret_cast<const f16x8*>(wtg + (size_t)(nt * 16 + l15) * cNL + k0 * 32 + quad * 8);
            accO[nt] = __builtin_amdgcn_mfma_f32_16x16x32_f16(ap, bw, accO[nt], 0, 0, 0);
        }
    }
#pragma unroll
    for (int nt = 0; nt < 4; ++nt)
#pragma unroll
        for (int r = 0; r < 4; ++r) {
            int s = s0 + wave * 16 + quad * 4 + r;
            int d = nt * 16 + l15;
            ctxh[((size_t)(b * cS) + s) * cD + h * cHD + d] = (_Float16)accO[nt][r];
        }
}

// ---------------------------------------------------------------------------
extern "C" void kernel_launch(void* const* d_in, const int* in_sizes, int n_in,
                              void* d_out, int out_size, void* d_ws, size_t ws_size,
                              hipStream_t stream)
{
    const float* X    = (const float*)d_in[0];
    const float* mask = (const float*)d_in[1];
    const float* Wq   = (const float*)d_in[2];
    const float* bq   = (const float*)d_in[3];
    const float* Wk   = (const float*)d_in[4];
    const float* bk   = (const float*)d_in[5];
    const float* Wv   = (const float*)d_in[6];
    const float* bv   = (const float*)d_in[7];
    const float* Wo   = (const float*)d_in[8];
    const float* bo   = (const float*)d_in[9];
    float* out = (float*)d_out;

    float* ws = (float*)d_ws;
    size_t off = 0;
    const size_t szQKV = (size_t)cBH * cS * cHD;      // 8388608 floats
    const size_t szL   = (size_t)cBH * cNL * cHD;     // 262144
    const size_t szM   = (size_t)cBH * cNL * cNL;     // 524288
    float* Qr   = ws + off; off += szQKV;             // Qh f16 (1st half) | Opart f32 (2nd half)
    float* Kr   = ws + off; off += szQKV;             // Kh f16 (1st half) | ctxh f16 (2nd half)
    float* Vr   = ws + off; off += szQKV;             // Vh f16 (1st half) | VTh f16 (2nd half)
    _Float16* Xh  = (_Float16*)(ws + off); off += szQKV / 2;
    _Float16* WqT = (_Float16*)(ws + off); off += 524288;
    _Float16* WkT = (_Float16*)(ws + off); off += 524288;
    _Float16* WvT = (_Float16*)(ws + off); off += 524288;
    _Float16* WoT = (_Float16*)(ws + off); off += 524288;
    float* Xm   = ws + off; off += (size_t)cB * cNL * cHID;
    float* mbar = ws + off; off += 256;
    float* Ql  = ws + off; off += szL;
    float* Kl  = ws + off; off += szL;
    float* k2  = ws + off; off += szM;
    float* Vb0 = ws + off; off += szM;
    float* Vb1 = ws + off; off += szM;
    float* Zb  = ws + off; off += szM;
    float* T2b = ws + off; off += szM;
    float* T3b = ws + off; off += szM;
    float* CV  = ws + off; off += szL;
    _Float16* Qlh  = (_Float16*)(ws + off); off += szL / 2;
    _Float16* Klh  = (_Float16*)(ws + off); off += szL / 2;
    _Float16* W2Th = (_Float16*)(ws + off); off += szL / 2;
    int*   cmax = (int*)(ws + off); off += 16;
    float* mpart = ws + off; off += 65536;
    float* spart = ws + off; off += 65536;

    _Float16* Qh   = (_Float16*)Qr;
    float*    Opart = Qr + szQKV / 2;        // 2nd half of Q region (Qh untouched)
    _Float16* Kh   = (_Float16*)Kr;
    _Float16* ctxh = (_Float16*)(Kr + szQKV / 2);   // 2nd half of K region
    _Float16* Vh   = (_Float16*)Vr;
    _Float16* VTh  = (_Float16*)(Vr + szQKV / 2);   // 2nd half of V region

    hipMemsetAsync(cmax, 0, sizeof(int), stream);

    cast_x<<<(int)(szQKV / 1024), 256, 0, stream>>>(X, Xh);
    wcast_t<<<dim3(32, 32, 4), 256, 0, stream>>>(Wq, Wk, Wv, Wo, WqT, WkT, WvT, WoT);
    xm_kernel<<<cB * cNL, 256, 0, stream>>>(X, mask, Xm, mbar);

    qkv_gemm_f16<<<dim3(cD / 128, (cB * cS) / 128, 3), 256, 0, stream>>>(
        Xh, mask, WqT, WkT, WvT, bq, bk, bv, Qh, Kh, Vh);
    vtrans<<<dim3(cS / 64, cBH), 256, 0, stream>>>(Vh, VTh);
    lgemm<<<dim3(cD / 64, (cB * cNL) / 64, 2), 256, 0, stream>>>(Xm, mbar, Wq, bq, Wk, bk, Ql, Kl, Qlh, Klh);

    k2_softmax<<<cBH * cNL, 128, 0, stream>>>(Ql, Kl, k2);
    colsum_max<<<cBH, 128, 0, stream>>>(k2, cmax);
    v0_kernel<<<cBH * cNL, 128, 0, stream>>>(k2, cmax, Vb0);

    float* Vc = Vb0; float* Vn = Vb1;
    for (int it = 0; it < 6; ++it) {
        nys_matmul<<<dim3(2, 2, cBH), 256, 0, stream>>>(k2, Vc, Zb, 0.f, -1.f);
        nys_matmul<<<dim3(2, 2, cBH), 256, 0, stream>>>(Zb, Zb, T2b, 7.f, 1.f);
        nys_matmul<<<dim3(2, 2, cBH), 256, 0, stream>>>(Zb, T2b, T3b, 15.f, 1.f);
        nys_matmul<<<dim3(2, 2, cBH), 256, 0, stream>>>(Vc, T3b, Vn, 13.f, 0.25f);
        float* tmp = Vc; Vc = Vn; Vn = tmp;
    }
    // Vc == Vb0 after 6 iters

    k3v_mfma<<<dim3(16, cBH), 256, 0, stream>>>(Qlh, Kh, VTh, mask, Opart, mpart, spart);
    k3v_reduce<<<1024, 256, 0, stream>>>(Opart, mpart, spart, CV);
    w2_matmul<<<cBH, 256, 0, stream>>>(Vc, CV, W2Th);
    k1_mfma<<<dim3(cS / 64, cBH), 256, 0, stream>>>(Qh, Klh, W2Th, ctxh);
    out_gemm_f16<<<dim3(cHID / 128, (cB * cS) / 128), 256, 0, stream>>>(ctxh, WoT, bo, out);
}